// Round 1
// baseline (35608.023 us; speedup 1.0000x reference)
//
#include <hip/hip_runtime.h>

// R16: multi-query blocks for L2-reuse. R15 counters: VALUBusy 18%, Occupancy
// 9.4%, HBM ~0% -> L2-latency/BW-bound (each block streams full 2MB fit4 from
// L2 for ONE query; 32 GB total vs ~135 GB/s per-CU L2 BW). Fix: QB=3 queries
// per block share every fit4 load -> L2 traffic /3, compute density x3,
// kernel becomes VALU-bound (~850us phase-1 floor). Per-query key math,
// radix selection, fp64 re-key, and top-K are BIT-IDENTICAL to R15; phase 2
// loops over the block's 3 queries (block-uniform => barrier-safe).
// LDS: 3x16KB u16 keys (+s_cv overlaying query-0's dead keys) = ~53KB,
// 3 blocks/CU (157.5/160KB), matching the 3-waves/SIMD VGPR limit.

#define NQ 16384
#define NF 8192
#define D  64
#define TCAP 64
#define RANK 32
#define QB 3

typedef unsigned short u16;
typedef unsigned int u32;
typedef unsigned long long u64;

#define IDX_INVALID 0xFFFFFFFFu
#define NANF_BITS   0x7FC00000u
#define FLTMAX_BITS 0x7F7FFFFFu

__device__ __forceinline__ int f32_missing_bits(u32 b) {
    return ((b >> 23) & 0xFFu) == 0xFFu;      // NaN/inf => missing
}

// ---- prep: fit (row-major [NF,64]) -> fit4 (group-major [16][NF] float4) ----
__global__ __launch_bounds__(256) void prep_fit4(const float* __restrict__ fit,
                                                 float4* __restrict__ fit4) {
    int idx = blockIdx.x * 256 + threadIdx.x;     // 0 .. NF*16-1
    int g = idx / NF;                              // feature group 0..15
    int f = idx - g * NF;                          // donor
    const float4* src = (const float4*)(fit + (size_t)f * D);
    fit4[(size_t)g * NF + f] = src[g];             // scattered read, coalesced write
}

template <int USE4>
__global__ __launch_bounds__(256, 3) void knn_r16(
        const float* __restrict__ X,
        const float* __restrict__ fit,
        const float4* __restrict__ fit4,          // used iff USE4
        const int* __restrict__ pk,
        float* __restrict__ out) {
    __shared__ __align__(16) unsigned char s_pool[QB * NF * 2]; // u16 keys; q0 region overlays s_cv
    __shared__ u32   s_hist[256];
    __shared__ u32   s_blw[256];
    __shared__ u32   s_tie[256];
    __shared__ __align__(16) float s_xv[QB][D];
    __shared__ u64   s_xmask[QB];
    __shared__ u32   s_ci[TCAP];
    __shared__ double s_kd[TCAP];
    __shared__ u32   s_sel0, s_below0, s_sel1;

    u16*   s_k16 = (u16*)s_pool;
    float* s_cv  = (float*)s_pool;                 // 16KB, overlays query-0 keys (dead by then)

    const int tid = threadIdx.x;
    const int q0 = blockIdx.x * QB;

    // ---- load QB query rows + observed masks (wave qq handles query qq) ----
    if (tid < QB * 64) {
        int qq = tid >> 6, d = tid & 63;
        int q = q0 + qq; if (q >= NQ) q = NQ - 1;  // clamp (dup compute, store guarded)
        float xf = X[(size_t)q * D + d];
        int obs = !f32_missing_bits(__float_as_uint(xf));
        s_xv[qq][d] = obs ? xf : 0.f;
        u64 bal = __ballot(obs != 0);              // tid 0..63 == wave0 etc.
        if (d == 0) s_xmask[qq] = bal;
    }
    __syncthreads();

    u32 xlo[QB], xhi[QB];
    const float4* xv4[QB];
#pragma unroll
    for (int qq = 0; qq < QB; ++qq) {
        u64 xm = s_xmask[qq];
        xlo[qq] = (u32)xm; xhi[qq] = (u32)(xm >> 32);
        xv4[qq] = (const float4*)s_xv[qq];
    }
    const float4* fitc = (const float4*)fit;

    // ---- phase 1: fp32 keys for QB queries per fit4 load ----
#pragma unroll 1
    for (int i = 0; i < 32; ++i) {
        int f = tid + (i << 8);
        float ssd[QB]; int pr[QB];
#pragma unroll
        for (int qq = 0; qq < QB; ++qq) { ssd[qq] = 0.f; pr[qq] = 0; }
#pragma unroll
        for (int m = 0; m < 16; ++m) {
            float4 w = USE4 ? fit4[(size_t)m * NF + f]
                            : fitc[(size_t)f * 16 + m];
            float wv[4] = { w.x, w.y, w.z, w.w };
            float xw[QB][4];
            u32 mb[QB];
#pragma unroll
            for (int qq = 0; qq < QB; ++qq) {
                float4 xc = xv4[qq][m];            // LDS broadcast
                xw[qq][0] = xc.x; xw[qq][1] = xc.y; xw[qq][2] = xc.z; xw[qq][3] = xc.w;
                mb[qq] = (m < 8) ? (xlo[qq] >> ((m & 7) * 4))
                                 : (xhi[qq] >> ((m & 7) * 4));
            }
#pragma unroll
            for (int u = 0; u < 4; ++u) {
                int vobs = f32_missing_bits(__float_as_uint(wv[u])) ^ 1; // shared
#pragma unroll
                for (int qq = 0; qq < QB; ++qq) {
                    int ok = (int)((mb[qq] >> u) & 1u) & vobs;
                    float t = ok ? wv[u] : xw[qq][u];
                    float dm = xw[qq][u] - t;      // = ok ? x - v : 0
                    ssd[qq] = fmaf(dm, dm, ssd[qq]);
                    pr[qq] += ok;
                }
            }
        }
#pragma unroll
        for (int qq = 0; qq < QB; ++qq) {
            float kk = (pr[qq] > 0) ? (ssd[qq] / (float)pr[qq])
                                    : __uint_as_float(FLTMAX_BITS);
            s_k16[qq * NF + f] = (u16)(__float_as_uint(kk) >> 16);
        }
    }
    __syncthreads();

    int K = *pk;
    if (K < 1 || K > 64) {                 // robustness if scalar arrived as float
        float kf = __int_as_float(K);
        K = (kf >= 1.f && kf <= 64.f) ? (int)kf : 5;
    }
    if (K > TCAP) K = TCAP;

    // ---- phase 2: per-query selection + imputation (identical math to R15) ----
    for (int qq = 0; qq < QB; ++qq) {
        const int q = q0 + qq;
        if (q >= NQ) continue;                     // block-uniform, barrier-safe
        const u16* kq = s_k16 + (size_t)qq * NF;
        const u32 xmlo = xlo[qq], xmhi = xhi[qq];

        // -- 2a: exact rank-32 u16 threshold, 2 byte passes --
        s_hist[tid] = 0;
        __syncthreads();
        for (int i = 0; i < 32; ++i) {
            u32 k16 = (u32)kq[tid + (i << 8)];
            atomicAdd(&s_hist[k16 >> 8], 1u);
        }
        __syncthreads();
        if (tid == 0) {
            u32 run = 0, below = 0, sel = 255;
            for (int b = 0; b < 256; ++b) {
                u32 c = s_hist[b];
                if (run + c >= (u32)RANK) { sel = (u32)b; below = run; break; }
                run += c;
            }
            s_sel0 = sel; s_below0 = below;
        }
        __syncthreads();
        const u32 sel0 = s_sel0;
        const u32 need1 = (u32)RANK - s_below0;
        __syncthreads();
        s_hist[tid] = 0;
        __syncthreads();
        for (int i = 0; i < 32; ++i) {
            u32 k16 = (u32)kq[tid + (i << 8)];
            if ((k16 >> 8) == sel0) atomicAdd(&s_hist[k16 & 0xFFu], 1u);
        }
        __syncthreads();
        if (tid == 0) {
            u32 run = 0, sel = 255;
            for (int b = 0; b < 256; ++b) {
                u32 c = s_hist[b];
                if (run + c >= need1) { sel = (u32)b; break; }
                run += c;
            }
            s_sel1 = sel;
        }
        __syncthreads();
        const u32 thr16 = (sel0 << 8) | s_sel1;

        // -- 2a': collection bitmasks (below + ties, cap TCAP) --
        {
            u32 bb = 0, tb = 0;
            for (int i = 0; i < 32; ++i) {
                u32 k16 = (u32)kq[tid + (i << 8)];
                bb |= (k16 < thr16)  ? (1u << i) : 0u;
                tb |= (k16 == thr16) ? (1u << i) : 0u;
            }
            s_blw[tid] = bb; s_tie[tid] = tb;
        }
        __syncthreads();
        if (tid == 0) {
            int n = 0;
            for (int t = 0; t < 256 && n < TCAP; ++t) {
                u32 w = s_blw[t];
                while (w && n < TCAP) {
                    int i = __ffs(w) - 1; w &= w - 1;
                    s_ci[n++] = (u32)(i * 256 + t);   // below-count <= 31 always
                }
            }
            u32 tf[TCAP]; int nt = 0;
            for (int t = 0; t < 256 && nt < TCAP; ++t) {
                u32 w = s_tie[t];
                while (w && nt < TCAP) {
                    int i = __ffs(w) - 1; w &= w - 1;
                    tf[nt++] = (u32)(i * 256 + t);
                }
            }
            int cap = TCAP - n;
            if (nt <= cap) {
                for (int r = 0; r < nt; ++r) s_ci[n++] = tf[r];
            } else {
                for (int j = 0; j < cap; ++j) {       // prefer smallest donor idx
                    int bp = -1; u32 bi = IDX_INVALID;
                    for (int r = 0; r < nt; ++r)
                        if (tf[r] < bi) { bi = tf[r]; bp = r; }
                    tf[bp] = IDX_INVALID;
                    s_ci[n++] = bi;
                }
            }
            for (; n < TCAP; ++n) s_ci[n] = IDX_INVALID;
        }
        __syncthreads();

        // -- 2c: stage candidate values (overlays query-0 keys — dead now) --
#pragma unroll
        for (int t = 0; t < (TCAP * 64) / 256; ++t) {   // 16 iters
            int idx = tid + t * 256;
            int r = idx >> 6, d2 = idx & 63;
            u32 ci = s_ci[r];
            s_cv[idx] = (ci != IDX_INVALID) ? fit[(size_t)ci * D + d2]
                                            : __uint_as_float(NANF_BITS);
        }

        // -- 2b: exact fp64 re-key of the candidates --
        if (tid < TCAP) {
            u32 ci = s_ci[tid];
            double kd = 1.0e300;
            if (ci != IDX_INVALID) {
                const float* row = fit + (size_t)ci * D;
                double ss = 0.0; int pr2 = 0;
                for (int j = 0; j < D; ++j) {
                    float yf = row[j];
                    int vmiss = f32_missing_bits(__float_as_uint(yf));
                    u32 xbit = (j < 32) ? ((xmlo >> j) & 1u) : ((xmhi >> (j - 32)) & 1u);
                    int ok = (int)xbit & (vmiss ^ 1);
                    double dd = ok ? ((double)s_xv[qq][j] - (double)yf) : 0.0;
                    ss = fma(dd, dd, ss);
                    pr2 += ok;
                }
                kd = (pr2 > 0) ? (ss / (double)pr2) : 1.0e300;
            }
            s_kd[tid] = kd;
        }
        __syncthreads();

        // -- 2d: per-column imputation (64 threads) --
        if (tid < 64) {
            const int d = tid;
            u32 xobs = (d < 32) ? ((xmlo >> d) & 1u) : ((xmhi >> (d - 32)) & 1u);
            float res;
            if (xobs) {
                res = s_xv[qq][d];
            } else {
                u64 used = 0; float sum = 0.f; int cnt = 0;
                for (int s = 0; s < K; ++s) {
                    int best = -1; double bk = 0.0; u32 bi = 0;
                    for (int r = 0; r < TCAP; ++r) {
                        if ((used >> r) & 1ull) continue;
                        u32 ci = s_ci[r];
                        if (ci == IDX_INVALID) continue;
                        float v = s_cv[r * 64 + d];
                        if (f32_missing_bits(__float_as_uint(v))) continue;
                        double kd = s_kd[r];
                        if (kd >= 1.0e300) continue;
                        if (best < 0 || kd < bk || (kd == bk && ci < bi)) {
                            best = r; bk = kd; bi = ci;
                        }
                    }
                    if (best < 0) break;
                    used |= 1ull << best;
                    sum += s_cv[best * 64 + d];
                    cnt++;
                }
                if (cnt > 0) {
                    res = sum / (float)cnt;
                } else {
                    float cs = 0.f; int cc = 0;        // essentially-never fallback
                    for (int f = 0; f < NF; ++f) {
                        float yf = fit[(size_t)f * D + d];
                        if (!f32_missing_bits(__float_as_uint(yf))) { cs += yf; cc++; }
                    }
                    res = cc > 0 ? cs / (float)cc : 0.f;
                }
                u32 rb = __float_as_uint(res);
                if (((rb >> 23) & 0xFFu) == 0xFFu) res = 0.f;   // integer guard
            }
            out[(size_t)q * D + d] = res;
        }
        // next qq: >=4 barriers before s_ci/s_cv reuse => 2d hazard-free
    }
}

// ---- launch ------------------------------------------------------------------
extern "C" void kernel_launch(void* const* d_in, const int* in_sizes, int n_in,
                              void* d_out, int out_size, void* d_ws, size_t ws_size,
                              hipStream_t stream) {
    const void* pX = d_in[0];
    const void* pF = (n_in > 1) ? d_in[1] : d_in[0];
    const void* pK = (n_in > 2) ? d_in[2] : d_in[0];
    for (int i = 0; i < n_in; ++i) {
        if (in_sizes[i] == NQ * D)      pX = d_in[i];
        else if (in_sizes[i] == NF * D) pF = d_in[i];
        else if (in_sizes[i] == 1)      pK = d_in[i];
    }
    const float* X   = (const float*)pX;
    const float* fit = (const float*)pF;
    const int*   pk  = (const int*)pK;
    float* out = (float*)d_out;

    const int grid = (NQ + QB - 1) / QB;           // 5462 blocks
    const size_t need = (size_t)NF * D * sizeof(float);   // 2 MB
    if (ws_size >= need) {
        float4* fit4 = (float4*)d_ws;
        prep_fit4<<<(NF * 16) / 256, 256, 0, stream>>>(fit, fit4);
        knn_r16<1><<<grid, 256, 0, stream>>>(X, fit, fit4, pk, out);
    } else {
        knn_r16<0><<<grid, 256, 0, stream>>>(X, fit, nullptr, pk, out);
    }
}

// Round 3
// 19612.193 us; speedup vs baseline: 1.8156x; 1.8156x over previous
//
#include <hip/hip_runtime.h>

// R17b: resubmit of R17 (container failed twice — infra, not kernel).
// QB=3 L2-reuse, spill-proof. R16's regression (35.6ms, WRITE_SIZE 6MB ->
// 15.5GB, FETCH 18MB -> 40GB, VALUBusy 3.9%) was register-spill scratch traffic:
// the per-query ARRAYS (xw[QB][4], mb[QB], ssd[QB]) in the hot loop defeated
// SROA -> local memory. R17 keeps the reuse idea (3 queries share every fit4
// load => L2 traffic /3) but phase 1 is fully scalarized via macro expansion:
// zero arrays, ~45 live VGPRs, nothing to spill. Phase 2 reads masks from LDS
// (runtime qq stays array-free) and is bit-identical to the proven R15 math:
// 2-pass exact u16 radix + bitmask collection + fp64 re-key + exact top-K.
// LDS: 3x16KB u16 keys (s_cv overlays query-0's dead keys) = ~53KB, 3 blk/CU.

#define NQ 16384
#define NF 8192
#define D  64
#define TCAP 64
#define RANK 32
#define QB 3

typedef unsigned short u16;
typedef unsigned int u32;
typedef unsigned long long u64;

#define IDX_INVALID 0xFFFFFFFFu
#define NANF_BITS   0x7FC00000u
#define FLTMAX_BITS 0x7F7FFFFFu

__device__ __forceinline__ int f32_missing_bits(u32 b) {
    return ((b >> 23) & 0xFFu) == 0xFFu;      // NaN/inf => missing
}

// ---- prep: fit (row-major [NF,64]) -> fit4 (group-major [16][NF] float4) ----
__global__ __launch_bounds__(256) void prep_fit4(const float* __restrict__ fit,
                                                 float4* __restrict__ fit4) {
    int idx = blockIdx.x * 256 + threadIdx.x;     // 0 .. NF*16-1
    int g = idx / NF;                              // feature group 0..15
    int f = idx - g * NF;                          // donor
    const float4* src = (const float4*)(fit + (size_t)f * D);
    fit4[(size_t)g * NF + f] = src[g];             // scattered read, coalesced write
}

template <int USE4>
__global__ __launch_bounds__(256) void knn_r17(
        const float* __restrict__ X,
        const float* __restrict__ fit,
        const float4* __restrict__ fit4,          // used iff USE4
        const int* __restrict__ pk,
        float* __restrict__ out) {
    __shared__ __align__(16) unsigned char s_pool[QB * NF * 2]; // 48KB u16 keys; q0 region overlays s_cv
    __shared__ u32   s_hist[256];
    __shared__ u32   s_blw[256];
    __shared__ u32   s_tie[256];
    __shared__ __align__(16) float s_xv[QB][D];
    __shared__ u64   s_xmask[QB];
    __shared__ u32   s_ci[TCAP];
    __shared__ double s_kd[TCAP];
    __shared__ u32   s_sel0, s_below0, s_sel1;

    u16*   s_k16 = (u16*)s_pool;
    float* s_cv  = (float*)s_pool;                 // 16KB, overlays query-0 keys (dead by then)

    const int tid = threadIdx.x;
    const int q0 = blockIdx.x * QB;

    // ---- load QB query rows + observed masks (wave qq handles query qq) ----
    if (tid < QB * 64) {
        int qq = tid >> 6, d = tid & 63;
        int q = q0 + qq; if (q >= NQ) q = NQ - 1;  // clamp (dup compute, store guarded)
        float xf = X[(size_t)q * D + d];
        int obs = !f32_missing_bits(__float_as_uint(xf));
        s_xv[qq][d] = obs ? xf : 0.f;
        u64 bal = __ballot(obs != 0);              // waves 0..2 fully active
        if (d == 0) s_xmask[qq] = bal;
    }
    __syncthreads();

    // ---- phase 1: fp32 keys for QB queries per fit4 load — fully scalarized ----
    {
        const u32 xlo0 = (u32)s_xmask[0], xhi0 = (u32)(s_xmask[0] >> 32);
        const u32 xlo1 = (u32)s_xmask[1], xhi1 = (u32)(s_xmask[1] >> 32);
        const u32 xlo2 = (u32)s_xmask[2], xhi2 = (u32)(s_xmask[2] >> 32);
        const float4* xqa = (const float4*)s_xv[0];
        const float4* xqb = (const float4*)s_xv[1];
        const float4* xqc = (const float4*)s_xv[2];
        const float4* fitc = (const float4*)fit;

#pragma unroll 1
        for (int i = 0; i < 32; ++i) {
            int f = tid + (i << 8);
            float ssd0 = 0.f, ssd1 = 0.f, ssd2 = 0.f;
            int pr0 = 0, pr1 = 0, pr2 = 0;
#pragma unroll
            for (int m = 0; m < 16; ++m) {
                float4 w  = USE4 ? fit4[(size_t)m * NF + f]
                                 : fitc[(size_t)f * 16 + m];
                float4 x0 = xqa[m];                // LDS broadcast reads
                float4 x1 = xqb[m];
                float4 x2 = xqc[m];
                u32 mb0 = (m < 8) ? (xlo0 >> ((m & 7) * 4)) : (xhi0 >> ((m & 7) * 4));
                u32 mb1 = (m < 8) ? (xlo1 >> ((m & 7) * 4)) : (xhi1 >> ((m & 7) * 4));
                u32 mb2 = (m < 8) ? (xlo2 >> ((m & 7) * 4)) : (xhi2 >> ((m & 7) * 4));
#define R17_ACC(U, WC, XA, XB, XC) {                                           \
                int vobs = f32_missing_bits(__float_as_uint(WC)) ^ 1;          \
                int ok0 = (int)((mb0 >> (U)) & 1u) & vobs;                     \
                float t0 = ok0 ? (WC) : (XA);                                  \
                float e0 = (XA) - t0;                                          \
                ssd0 = fmaf(e0, e0, ssd0); pr0 += ok0;                         \
                int ok1 = (int)((mb1 >> (U)) & 1u) & vobs;                     \
                float t1 = ok1 ? (WC) : (XB);                                  \
                float e1 = (XB) - t1;                                          \
                ssd1 = fmaf(e1, e1, ssd1); pr1 += ok1;                         \
                int ok2 = (int)((mb2 >> (U)) & 1u) & vobs;                     \
                float t2 = ok2 ? (WC) : (XC);                                  \
                float e2 = (XC) - t2;                                          \
                ssd2 = fmaf(e2, e2, ssd2); pr2 += ok2; }
                R17_ACC(0, w.x, x0.x, x1.x, x2.x)
                R17_ACC(1, w.y, x0.y, x1.y, x2.y)
                R17_ACC(2, w.z, x0.z, x1.z, x2.z)
                R17_ACC(3, w.w, x0.w, x1.w, x2.w)
#undef R17_ACC
            }
            float k0 = (pr0 > 0) ? (ssd0 / (float)pr0) : __uint_as_float(FLTMAX_BITS);
            float k1 = (pr1 > 0) ? (ssd1 / (float)pr1) : __uint_as_float(FLTMAX_BITS);
            float k2 = (pr2 > 0) ? (ssd2 / (float)pr2) : __uint_as_float(FLTMAX_BITS);
            s_k16[0 * NF + f] = (u16)(__float_as_uint(k0) >> 16);
            s_k16[1 * NF + f] = (u16)(__float_as_uint(k1) >> 16);
            s_k16[2 * NF + f] = (u16)(__float_as_uint(k2) >> 16);
        }
    }
    __syncthreads();

    int K = *pk;
    if (K < 1 || K > 64) {                 // robustness if scalar arrived as float
        float kf = __int_as_float(K);
        K = (kf >= 1.f && kf <= 64.f) ? (int)kf : 5;
    }
    if (K > TCAP) K = TCAP;

    // ---- phase 2: per-query selection + imputation (identical math to R15) ----
#pragma unroll 1
    for (int qq = 0; qq < QB; ++qq) {
        const int q = q0 + qq;
        if (q >= NQ) continue;                     // block-uniform, barrier-safe
        const u16* kq = s_k16 + (size_t)qq * NF;
        const u64 xm = s_xmask[qq];
        const u32 xmlo = (u32)xm, xmhi = (u32)(xm >> 32);

        // -- 2a: exact rank-32 u16 threshold, 2 byte passes --
        s_hist[tid] = 0;
        __syncthreads();
        for (int i = 0; i < 32; ++i) {
            u32 k16 = (u32)kq[tid + (i << 8)];
            atomicAdd(&s_hist[k16 >> 8], 1u);
        }
        __syncthreads();
        if (tid == 0) {
            u32 run = 0, below = 0, sel = 255;
            for (int b = 0; b < 256; ++b) {
                u32 c = s_hist[b];
                if (run + c >= (u32)RANK) { sel = (u32)b; below = run; break; }
                run += c;
            }
            s_sel0 = sel; s_below0 = below;
        }
        __syncthreads();
        const u32 sel0 = s_sel0;
        const u32 need1 = (u32)RANK - s_below0;
        __syncthreads();
        s_hist[tid] = 0;
        __syncthreads();
        for (int i = 0; i < 32; ++i) {
            u32 k16 = (u32)kq[tid + (i << 8)];
            if ((k16 >> 8) == sel0) atomicAdd(&s_hist[k16 & 0xFFu], 1u);
        }
        __syncthreads();
        if (tid == 0) {
            u32 run = 0, sel = 255;
            for (int b = 0; b < 256; ++b) {
                u32 c = s_hist[b];
                if (run + c >= need1) { sel = (u32)b; break; }
                run += c;
            }
            s_sel1 = sel;
        }
        __syncthreads();
        const u32 thr16 = (sel0 << 8) | s_sel1;

        // -- 2a': collection bitmasks (below + ties, cap TCAP) --
        {
            u32 bb = 0, tb = 0;
            for (int i = 0; i < 32; ++i) {
                u32 k16 = (u32)kq[tid + (i << 8)];
                bb |= (k16 < thr16)  ? (1u << i) : 0u;
                tb |= (k16 == thr16) ? (1u << i) : 0u;
            }
            s_blw[tid] = bb; s_tie[tid] = tb;
        }
        __syncthreads();
        if (tid == 0) {
            int n = 0;
            for (int t = 0; t < 256 && n < TCAP; ++t) {
                u32 w = s_blw[t];
                while (w && n < TCAP) {
                    int i = __ffs(w) - 1; w &= w - 1;
                    s_ci[n++] = (u32)(i * 256 + t);   // below-count <= 31 always
                }
            }
            u32 tf[TCAP]; int nt = 0;
            for (int t = 0; t < 256 && nt < TCAP; ++t) {
                u32 w = s_tie[t];
                while (w && nt < TCAP) {
                    int i = __ffs(w) - 1; w &= w - 1;
                    tf[nt++] = (u32)(i * 256 + t);
                }
            }
            int cap = TCAP - n;
            if (nt <= cap) {
                for (int r = 0; r < nt; ++r) s_ci[n++] = tf[r];
            } else {
                for (int j = 0; j < cap; ++j) {       // prefer smallest donor idx
                    int bp = -1; u32 bi = IDX_INVALID;
                    for (int r = 0; r < nt; ++r)
                        if (tf[r] < bi) { bi = tf[r]; bp = r; }
                    tf[bp] = IDX_INVALID;
                    s_ci[n++] = bi;
                }
            }
            for (; n < TCAP; ++n) s_ci[n] = IDX_INVALID;
        }
        __syncthreads();

        // -- 2c: stage candidate values (overlays query-0 keys — dead now) --
#pragma unroll
        for (int t = 0; t < (TCAP * 64) / 256; ++t) {   // 16 iters
            int idx = tid + t * 256;
            int r = idx >> 6, d2 = idx & 63;
            u32 ci = s_ci[r];
            s_cv[idx] = (ci != IDX_INVALID) ? fit[(size_t)ci * D + d2]
                                            : __uint_as_float(NANF_BITS);
        }

        // -- 2b: exact fp64 re-key of the candidates --
        if (tid < TCAP) {
            u32 ci = s_ci[tid];
            double kd = 1.0e300;
            if (ci != IDX_INVALID) {
                const float* row = fit + (size_t)ci * D;
                double ss = 0.0; int pr2 = 0;
                for (int j = 0; j < D; ++j) {
                    float yf = row[j];
                    int vmiss = f32_missing_bits(__float_as_uint(yf));
                    u32 xbit = (j < 32) ? ((xmlo >> j) & 1u) : ((xmhi >> (j - 32)) & 1u);
                    int ok = (int)xbit & (vmiss ^ 1);
                    double dd = ok ? ((double)s_xv[qq][j] - (double)yf) : 0.0;
                    ss = fma(dd, dd, ss);
                    pr2 += ok;
                }
                kd = (pr2 > 0) ? (ss / (double)pr2) : 1.0e300;
            }
            s_kd[tid] = kd;
        }
        __syncthreads();

        // -- 2d: per-column imputation (64 threads) --
        if (tid < 64) {
            const int d = tid;
            u32 xobs = (d < 32) ? ((xmlo >> d) & 1u) : ((xmhi >> (d - 32)) & 1u);
            float res;
            if (xobs) {
                res = s_xv[qq][d];
            } else {
                u64 used = 0; float sum = 0.f; int cnt = 0;
                for (int s = 0; s < K; ++s) {
                    int best = -1; double bk = 0.0; u32 bi = 0;
                    for (int r = 0; r < TCAP; ++r) {
                        if ((used >> r) & 1ull) continue;
                        u32 ci = s_ci[r];
                        if (ci == IDX_INVALID) continue;
                        float v = s_cv[r * 64 + d];
                        if (f32_missing_bits(__float_as_uint(v))) continue;
                        double kd = s_kd[r];
                        if (kd >= 1.0e300) continue;
                        if (best < 0 || kd < bk || (kd == bk && ci < bi)) {
                            best = r; bk = kd; bi = ci;
                        }
                    }
                    if (best < 0) break;
                    used |= 1ull << best;
                    sum += s_cv[best * 64 + d];
                    cnt++;
                }
                if (cnt > 0) {
                    res = sum / (float)cnt;
                } else {
                    float cs = 0.f; int cc = 0;        // essentially-never fallback
                    for (int f = 0; f < NF; ++f) {
                        float yf = fit[(size_t)f * D + d];
                        if (!f32_missing_bits(__float_as_uint(yf))) { cs += yf; cc++; }
                    }
                    res = cc > 0 ? cs / (float)cc : 0.f;
                }
                u32 rb = __float_as_uint(res);
                if (((rb >> 23) & 0xFFu) == 0xFFu) res = 0.f;   // integer guard
            }
            out[(size_t)q * D + d] = res;
        }
        // next qq: >=4 barriers before s_ci/s_cv reuse => 2d hazard-free
    }
}

// ---- launch ------------------------------------------------------------------
extern "C" void kernel_launch(void* const* d_in, const int* in_sizes, int n_in,
                              void* d_out, int out_size, void* d_ws, size_t ws_size,
                              hipStream_t stream) {
    const void* pX = d_in[0];
    const void* pF = (n_in > 1) ? d_in[1] : d_in[0];
    const void* pK = (n_in > 2) ? d_in[2] : d_in[0];
    for (int i = 0; i < n_in; ++i) {
        if (in_sizes[i] == NQ * D)      pX = d_in[i];
        else if (in_sizes[i] == NF * D) pF = d_in[i];
        else if (in_sizes[i] == 1)      pK = d_in[i];
    }
    const float* X   = (const float*)pX;
    const float* fit = (const float*)pF;
    const int*   pk  = (const int*)pK;
    float* out = (float*)d_out;

    const int grid = (NQ + QB - 1) / QB;           // 5462 blocks
    const size_t need = (size_t)NF * D * sizeof(float);   // 2 MB
    if (ws_size >= need) {
        float4* fit4 = (float4*)d_ws;
        prep_fit4<<<(NF * 16) / 256, 256, 0, stream>>>(fit, fit4);
        knn_r17<1><<<grid, 256, 0, stream>>>(X, fit, fit4, pk, out);
    } else {
        knn_r17<0><<<grid, 256, 0, stream>>>(X, fit, nullptr, pk, out);
    }
}

// Round 4
// 7819.205 us; speedup vs baseline: 4.5539x; 2.5082x over previous
//
#include <hip/hip_runtime.h>

// R18: MFMA phase-1. R16/R17 both died of register pressure: Q queries x 64
// f32 of query data cannot live in VGPRs (R17: LICM hoisted 192 regs of
// loop-invariant LDS loads -> VGPR 256 + 2GB spill stores). Fix the ALGORITHM:
// ssd/pres are GEMMs (reference's own decomposition):
//   ssd  = obsY.XX + YY.obsX + Yc.(-2Xc)   (K=64 each, bf16 in / f32 acc)
//   pres = obsY.obsX
// Donor-side fragments precomputed in ws (3MB, frag-layout-major, coalesced
// 16B/lane loads); query-side frags built once into 24 VGPRs. 8 MFMAs per
// 16-donor tile. bf16 key noise (sigma~0.05 abs) << rank-5..32 gap (~10) and
// << existing u16 truncation (~0.5): candidate collection unchanged in
// character; final values still from EXACT fp64 re-key + exact top-K
// (proven R15 phase 2, verbatim, looped over QB=8 queries/block).
// LDS: 8 x 8208 u16 keys (padded rows) = 128.2KB + misc ~137KB, 1 block/CU
// (>64KB static LDS ok on gfx950 per m201 128KB precedent).
// Fallback (ws < 3MB): proven R15 row-major kernel.

#define NQ 16384
#define NF 8192
#define D  64
#define TCAP 64
#define RANK 32
#define QB 8
#define PADW 8208      // u16 key-row stride (8192 + 16 pad -> rows offset 8 banks)
#define NTILES 512     // NF/16

typedef unsigned short u16;
typedef unsigned int u32;
typedef unsigned long long u64;
typedef __attribute__((ext_vector_type(8))) short bf16x8;
typedef __attribute__((ext_vector_type(4))) float f32x4;

#define IDX_INVALID 0xFFFFFFFFu
#define NANF_BITS   0x7FC00000u
#define FLTMAX_BITS 0x7F7FFFFFu

__device__ __forceinline__ int f32_missing_bits(u32 b) {
    return ((b >> 23) & 0xFFu) == 0xFFu;      // NaN/inf => missing
}
__device__ __forceinline__ u16 bf16_rne(float f) {
    u32 b = __float_as_uint(f);
    return (u16)((b + 0x7FFFu + ((b >> 16) & 1u)) >> 16);
}

// ---- prep: donor-side MFMA A-fragments into ws ------------------------------
// Layout (uint4 units): idx = ((t*3 + sel)*2 + kk)*64 + lane
//   sel 0: obsY (1.0/0.0), sel 1: v^2, sel 2: v   (bf16, missing -> 0)
//   lane's 8 elems: donor = t*16 + (lane&15), feature = kk*32 + (lane>>4)*8 + e
__global__ __launch_bounds__(256) void prep_frags(const float* __restrict__ fit,
                                                  uint4* __restrict__ frags) {
    int idx  = blockIdx.x * 256 + threadIdx.x;    // 0 .. NTILES*384-1
    int lane = idx & 63;
    int kk   = (idx >> 6) & 1;
    int sel  = (idx >> 7) % 3;
    int t    = (idx >> 7) / 3;
    int donor = t * 16 + (lane & 15);
    int j0 = kk * 32 + ((lane >> 4) & 3) * 8;
    const float* row = fit + (size_t)donor * D + j0;
    u32 w[4];
#pragma unroll
    for (int p = 0; p < 4; ++p) {
        u16 h0, h1;
        {
            float v = row[p * 2];
            int miss = f32_missing_bits(__float_as_uint(v));
            float vc = miss ? 0.f : v;
            float val = (sel == 0) ? (miss ? 0.f : 1.f) : (sel == 1) ? vc * vc : vc;
            h0 = bf16_rne(val);
        }
        {
            float v = row[p * 2 + 1];
            int miss = f32_missing_bits(__float_as_uint(v));
            float vc = miss ? 0.f : v;
            float val = (sel == 0) ? (miss ? 0.f : 1.f) : (sel == 1) ? vc * vc : vc;
            h1 = bf16_rne(val);
        }
        w[p] = (u32)h0 | ((u32)h1 << 16);
    }
    frags[idx] = make_uint4(w[0], w[1], w[2], w[3]);
}

#define MF(A, B, C) __builtin_amdgcn_mfma_f32_16x16x32_bf16(                  \
        __builtin_bit_cast(bf16x8, (A)), (B), (C), 0, 0, 0)

#define LOADT(T, A0, A1, A2, A3, A4, A5) {                                    \
        size_t bo = (size_t)(T) * 384 + lane;                                 \
        A0 = frags[bo];       A1 = frags[bo + 64];                            \
        A2 = frags[bo + 128]; A3 = frags[bo + 192];                           \
        A4 = frags[bo + 256]; A5 = frags[bo + 320]; }

__global__ __launch_bounds__(256) void knn_mfma(
        const float* __restrict__ X,
        const float* __restrict__ fit,
        const uint4* __restrict__ frags,
        const int* __restrict__ pk,
        float* __restrict__ out) {
    __shared__ __align__(16) u16 s_k16[QB * PADW];   // 131,328 B
    __shared__ u32   s_hist[256];
    __shared__ u32   s_blw[256];
    __shared__ u32   s_tie[256];
    __shared__ __align__(16) float s_xv[QB][D];
    __shared__ u64   s_xmask[QB];
    __shared__ u32   s_ci[TCAP];
    __shared__ double s_kd[TCAP];
    __shared__ u32   s_sel0, s_below0, s_sel1;

    float* s_cv = (float*)s_k16;   // 16,384 B staging overlays query-0 key row
                                   // (16,416 B; dead after qq=0 collection)
    const int tid = threadIdx.x;
    const int q0 = blockIdx.x * QB;

    // ---- load QB=8 query rows + observed masks (wave-ballot per query) ----
#pragma unroll
    for (int rr = 0; rr < 2; ++rr) {
        int qq = rr * 4 + (tid >> 6);
        int d  = tid & 63;
        float xf = X[(size_t)(q0 + qq) * D + d];
        int obs = !f32_missing_bits(__float_as_uint(xf));
        s_xv[qq][d] = obs ? xf : 0.f;
        u64 bal = __ballot(obs != 0);
        if (d == 0) s_xmask[qq] = bal;
    }
    __syncthreads();

    // ---- build query-side B fragments (once; 24 VGPRs total) ----
    const int lane = tid & 63;
    const int qcol = lane & 15;          // MFMA B col / D col = query
    const int krow = (lane >> 4) & 3;    // k-group
    bf16x8 bXX0 = (bf16x8)(short)0, bXX1 = (bf16x8)(short)0;
    bf16x8 bOX0 = (bf16x8)(short)0, bOX1 = (bf16x8)(short)0;
    bf16x8 bM0  = (bf16x8)(short)0, bM1  = (bf16x8)(short)0;
    if (qcol < QB) {
        const float* xr = s_xv[qcol];
        u64 xm = s_xmask[qcol];
#pragma unroll
        for (int e = 0; e < 8; ++e) {
            {
                int j = krow * 8 + e;                   // kk = 0 (features 0..31)
                float x = xr[j];
                bXX0[e] = (short)bf16_rne(x * x);
                bOX0[e] = (short)(((xm >> j) & 1ull) ? 0x3F80 : 0);
                bM0[e]  = (short)bf16_rne(-2.f * x);
            }
            {
                int j = 32 + krow * 8 + e;              // kk = 1 (features 32..63)
                float x = xr[j];
                bXX1[e] = (short)bf16_rne(x * x);
                bOX1[e] = (short)(((xm >> j) & 1ull) ? 0x3F80 : 0);
                bM1[e]  = (short)bf16_rne(-2.f * x);
            }
        }
    }

    // ---- phase 1: MFMA over 128 donor tiles per wave, reg double-buffered ----
    {
        const int wv = tid >> 6;
        int t = wv * 128;
        uint4 c0, c1, c2, c3, c4, c5;
        uint4 n0 = {}, n1 = {}, n2 = {}, n3 = {}, n4 = {}, n5 = {};
        LOADT(t, c0, c1, c2, c3, c4, c5);
#pragma unroll 1
        for (int tt = 0; tt < 128; ++tt) {
            bool hasn = (tt + 1 < 128);
            if (hasn) LOADT(t + 1, n0, n1, n2, n3, n4, n5);
            f32x4 accS = {0.f, 0.f, 0.f, 0.f};
            f32x4 accP = {0.f, 0.f, 0.f, 0.f};
            accS = MF(c0, bXX0, accS);   // obsY . x^2
            accS = MF(c1, bXX1, accS);
            accS = MF(c2, bOX0, accS);   // v^2 . obsX
            accS = MF(c3, bOX1, accS);
            accS = MF(c4, bM0,  accS);   // v . (-2x)
            accS = MF(c5, bM1,  accS);
            accP = MF(c0, bOX0, accP);   // obsY . obsX
            accP = MF(c1, bOX1, accP);
            if (qcol < QB) {
                // D row = (lane>>4)*4 + r = donor-in-tile; col = lane&15 = query
#define MKKEY(r) ((accP[r] > 0.5f)                                            \
                    ? __float_as_uint(__fdividef(fmaxf(accS[r], 0.f), accP[r]))\
                    : FLTMAX_BITS)
                u32 b0 = MKKEY(0), b1 = MKKEY(1), b2 = MKKEY(2), b3 = MKKEY(3);
#undef MKKEY
                u32 lo = (b0 >> 16) | (b1 & 0xFFFF0000u);
                u32 hi = (b2 >> 16) | (b3 & 0xFFFF0000u);
                u32 off = (u32)qcol * PADW + (u32)t * 16 + (u32)krow * 4;
                *(uint2*)(&s_k16[off]) = make_uint2(lo, hi);
            }
            if (hasn) { c0 = n0; c1 = n1; c2 = n2; c3 = n3; c4 = n4; c5 = n5; }
            ++t;
        }
    }
    __syncthreads();

    int K = *pk;
    if (K < 1 || K > 64) {                 // robustness if scalar arrived as float
        float kf = __int_as_float(K);
        K = (kf >= 1.f && kf <= 64.f) ? (int)kf : 5;
    }
    if (K > TCAP) K = TCAP;

    // ---- phase 2: proven R15 selection + imputation, per query ----
#pragma unroll 1
    for (int qq = 0; qq < QB; ++qq) {
        const int q = q0 + qq;
        const u16* kq = s_k16 + (size_t)qq * PADW;
        const u64 xm = s_xmask[qq];
        const u32 xmlo = (u32)xm, xmhi = (u32)(xm >> 32);

        // -- 2a: exact rank-32 u16 threshold, 2 byte passes --
        s_hist[tid] = 0;
        __syncthreads();
        for (int i = 0; i < 32; ++i) {
            u32 k16 = (u32)kq[tid + (i << 8)];
            atomicAdd(&s_hist[k16 >> 8], 1u);
        }
        __syncthreads();
        if (tid == 0) {
            u32 run = 0, below = 0, sel = 255;
            for (int b = 0; b < 256; ++b) {
                u32 c = s_hist[b];
                if (run + c >= (u32)RANK) { sel = (u32)b; below = run; break; }
                run += c;
            }
            s_sel0 = sel; s_below0 = below;
        }
        __syncthreads();
        const u32 sel0 = s_sel0;
        const u32 need1 = (u32)RANK - s_below0;
        __syncthreads();
        s_hist[tid] = 0;
        __syncthreads();
        for (int i = 0; i < 32; ++i) {
            u32 k16 = (u32)kq[tid + (i << 8)];
            if ((k16 >> 8) == sel0) atomicAdd(&s_hist[k16 & 0xFFu], 1u);
        }
        __syncthreads();
        if (tid == 0) {
            u32 run = 0, sel = 255;
            for (int b = 0; b < 256; ++b) {
                u32 c = s_hist[b];
                if (run + c >= need1) { sel = (u32)b; break; }
                run += c;
            }
            s_sel1 = sel;
        }
        __syncthreads();
        const u32 thr16 = (sel0 << 8) | s_sel1;

        // -- 2a': collection bitmasks (below + ties, cap TCAP) --
        {
            u32 bb = 0, tb = 0;
            for (int i = 0; i < 32; ++i) {
                u32 k16 = (u32)kq[tid + (i << 8)];
                bb |= (k16 < thr16)  ? (1u << i) : 0u;
                tb |= (k16 == thr16) ? (1u << i) : 0u;
            }
            s_blw[tid] = bb; s_tie[tid] = tb;
        }
        __syncthreads();
        if (tid == 0) {
            int n = 0;
            for (int t = 0; t < 256 && n < TCAP; ++t) {
                u32 w = s_blw[t];
                while (w && n < TCAP) {
                    int i = __ffs(w) - 1; w &= w - 1;
                    s_ci[n++] = (u32)(i * 256 + t);   // below-count <= 31 always
                }
            }
            u32 tf[TCAP]; int nt = 0;
            for (int t = 0; t < 256 && nt < TCAP; ++t) {
                u32 w = s_tie[t];
                while (w && nt < TCAP) {
                    int i = __ffs(w) - 1; w &= w - 1;
                    tf[nt++] = (u32)(i * 256 + t);
                }
            }
            int cap = TCAP - n;
            if (nt <= cap) {
                for (int r = 0; r < nt; ++r) s_ci[n++] = tf[r];
            } else {
                for (int j = 0; j < cap; ++j) {       // prefer smallest donor idx
                    int bp = -1; u32 bi = IDX_INVALID;
                    for (int r = 0; r < nt; ++r)
                        if (tf[r] < bi) { bi = tf[r]; bp = r; }
                    tf[bp] = IDX_INVALID;
                    s_ci[n++] = bi;
                }
            }
            for (; n < TCAP; ++n) s_ci[n] = IDX_INVALID;
        }
        __syncthreads();

        // -- 2c: stage candidate values (overlays query-0 key row — dead now) --
#pragma unroll
        for (int t = 0; t < (TCAP * 64) / 256; ++t) {   // 16 iters
            int idx = tid + t * 256;
            int r = idx >> 6, d2 = idx & 63;
            u32 ci = s_ci[r];
            s_cv[idx] = (ci != IDX_INVALID) ? fit[(size_t)ci * D + d2]
                                            : __uint_as_float(NANF_BITS);
        }

        // -- 2b: exact fp64 re-key of the candidates --
        if (tid < TCAP) {
            u32 ci = s_ci[tid];
            double kd = 1.0e300;
            if (ci != IDX_INVALID) {
                const float* row = fit + (size_t)ci * D;
                double ss = 0.0; int pr2 = 0;
                for (int j = 0; j < D; ++j) {
                    float yf = row[j];
                    int vmiss = f32_missing_bits(__float_as_uint(yf));
                    u32 xbit = (j < 32) ? ((xmlo >> j) & 1u) : ((xmhi >> (j - 32)) & 1u);
                    int ok = (int)xbit & (vmiss ^ 1);
                    double dd = ok ? ((double)s_xv[qq][j] - (double)yf) : 0.0;
                    ss = fma(dd, dd, ss);
                    pr2 += ok;
                }
                kd = (pr2 > 0) ? (ss / (double)pr2) : 1.0e300;
            }
            s_kd[tid] = kd;
        }
        __syncthreads();

        // -- 2d: per-column imputation (64 threads) --
        if (tid < 64) {
            const int d = tid;
            u32 xobs = (d < 32) ? ((xmlo >> d) & 1u) : ((xmhi >> (d - 32)) & 1u);
            float res;
            if (xobs) {
                res = s_xv[qq][d];
            } else {
                u64 used = 0; float sum = 0.f; int cnt = 0;
                for (int s = 0; s < K; ++s) {
                    int best = -1; double bk = 0.0; u32 bi = 0;
                    for (int r = 0; r < TCAP; ++r) {
                        if ((used >> r) & 1ull) continue;
                        u32 ci = s_ci[r];
                        if (ci == IDX_INVALID) continue;
                        float v = s_cv[r * 64 + d];
                        if (f32_missing_bits(__float_as_uint(v))) continue;
                        double kd = s_kd[r];
                        if (kd >= 1.0e300) continue;
                        if (best < 0 || kd < bk || (kd == bk && ci < bi)) {
                            best = r; bk = kd; bi = ci;
                        }
                    }
                    if (best < 0) break;
                    used |= 1ull << best;
                    sum += s_cv[best * 64 + d];
                    cnt++;
                }
                if (cnt > 0) {
                    res = sum / (float)cnt;
                } else {
                    float cs = 0.f; int cc = 0;        // essentially-never fallback
                    for (int f = 0; f < NF; ++f) {
                        float yf = fit[(size_t)f * D + d];
                        if (!f32_missing_bits(__float_as_uint(yf))) { cs += yf; cc++; }
                    }
                    res = cc > 0 ? cs / (float)cc : 0.f;
                }
                u32 rb = __float_as_uint(res);
                if (((rb >> 23) & 0xFFu) == 0xFFu) res = 0.f;   // integer guard
            }
            out[(size_t)q * D + d] = res;
        }
        // next qq: >=4 barriers before s_ci/s_cv/s_kd reuse => 2d hazard-free
    }
}

// ---- fallback: proven R15 kernel, row-major path (1 query/block) ------------
__global__ __launch_bounds__(256) void knn_fb(
        const float* __restrict__ X,
        const float* __restrict__ fit,
        const int* __restrict__ pk,
        float* __restrict__ out) {
    __shared__ __align__(16) unsigned char s_pool[16384];
    __shared__ u32   s_hist[256];
    __shared__ u32   s_blw[256];
    __shared__ u32   s_tie[256];
    __shared__ __align__(16) float s_xv[D];
    __shared__ u64   s_xmask;
    __shared__ u32   s_ci[TCAP];
    __shared__ double s_kd[TCAP];
    __shared__ u32   s_sel0, s_below0, s_sel1;

    u16*   s_k16 = (u16*)s_pool;
    float* s_cv  = (float*)s_pool;
    const int tid = threadIdx.x;
    const int q = blockIdx.x;

    if (tid < 64) {
        float xf = X[(size_t)q * D + tid];
        int obs = !f32_missing_bits(__float_as_uint(xf));
        s_xv[tid] = obs ? xf : 0.f;
        u64 bal = __ballot(obs != 0);
        if (tid == 0) s_xmask = bal;
    }
    __syncthreads();

    const u64 xm = s_xmask;
    const u32 xmlo = (u32)xm, xmhi = (u32)(xm >> 32);
    const float4* xv4 = (const float4*)s_xv;
    const float4* fitc = (const float4*)fit;

    for (int i = 0; i < 32; ++i) {
        int f = tid + (i << 8);
        const float4* rp = fitc + (size_t)f * 16;
        float ssd = 0.f; int pres = 0;
#pragma unroll
        for (int m = 0; m < 16; ++m) {
            float4 w = rp[m];
            float4 xc = xv4[m];
            u32 mb = (m < 8) ? (xmlo >> ((m & 7) * 4)) : (xmhi >> ((m & 7) * 4));
            float wv[4] = { w.x, w.y, w.z, w.w };
            float xw[4] = { xc.x, xc.y, xc.z, xc.w };
#pragma unroll
            for (int u = 0; u < 4; ++u) {
                int ok = (int)((mb >> u) & 1u)
                       & (f32_missing_bits(__float_as_uint(wv[u])) ^ 1);
                float t = ok ? wv[u] : xw[u];
                float dm = xw[u] - t;
                ssd = fmaf(dm, dm, ssd);
                pres += ok;
            }
        }
        float kk = (pres > 0) ? (ssd / (float)pres) : __uint_as_float(FLTMAX_BITS);
        s_k16[f] = (u16)(__float_as_uint(kk) >> 16);
    }
    __syncthreads();

    int K = *pk;
    if (K < 1 || K > 64) {
        float kf = __int_as_float(K);
        K = (kf >= 1.f && kf <= 64.f) ? (int)kf : 5;
    }
    if (K > TCAP) K = TCAP;

    s_hist[tid] = 0;
    __syncthreads();
    for (int i = 0; i < 32; ++i) {
        u32 k16 = (u32)s_k16[tid + (i << 8)];
        atomicAdd(&s_hist[k16 >> 8], 1u);
    }
    __syncthreads();
    if (tid == 0) {
        u32 run = 0, below = 0, sel = 255;
        for (int b = 0; b < 256; ++b) {
            u32 c = s_hist[b];
            if (run + c >= (u32)RANK) { sel = (u32)b; below = run; break; }
            run += c;
        }
        s_sel0 = sel; s_below0 = below;
    }
    __syncthreads();
    const u32 sel0 = s_sel0;
    const u32 need1 = (u32)RANK - s_below0;
    __syncthreads();
    s_hist[tid] = 0;
    __syncthreads();
    for (int i = 0; i < 32; ++i) {
        u32 k16 = (u32)s_k16[tid + (i << 8)];
        if ((k16 >> 8) == sel0) atomicAdd(&s_hist[k16 & 0xFFu], 1u);
    }
    __syncthreads();
    if (tid == 0) {
        u32 run = 0, sel = 255;
        for (int b = 0; b < 256; ++b) {
            u32 c = s_hist[b];
            if (run + c >= need1) { sel = (u32)b; break; }
            run += c;
        }
        s_sel1 = sel;
    }
    __syncthreads();
    const u32 thr16 = (sel0 << 8) | s_sel1;

    {
        u32 bb = 0, tb = 0;
        for (int i = 0; i < 32; ++i) {
            u32 k16 = (u32)s_k16[tid + (i << 8)];
            bb |= (k16 < thr16)  ? (1u << i) : 0u;
            tb |= (k16 == thr16) ? (1u << i) : 0u;
        }
        s_blw[tid] = bb; s_tie[tid] = tb;
    }
    __syncthreads();
    if (tid == 0) {
        int n = 0;
        for (int t = 0; t < 256 && n < TCAP; ++t) {
            u32 w = s_blw[t];
            while (w && n < TCAP) {
                int i = __ffs(w) - 1; w &= w - 1;
                s_ci[n++] = (u32)(i * 256 + t);
            }
        }
        u32 tf[TCAP]; int nt = 0;
        for (int t = 0; t < 256 && nt < TCAP; ++t) {
            u32 w = s_tie[t];
            while (w && nt < TCAP) {
                int i = __ffs(w) - 1; w &= w - 1;
                tf[nt++] = (u32)(i * 256 + t);
            }
        }
        int cap = TCAP - n;
        if (nt <= cap) {
            for (int r = 0; r < nt; ++r) s_ci[n++] = tf[r];
        } else {
            for (int j = 0; j < cap; ++j) {
                int bp = -1; u32 bi = IDX_INVALID;
                for (int r = 0; r < nt; ++r)
                    if (tf[r] < bi) { bi = tf[r]; bp = r; }
                tf[bp] = IDX_INVALID;
                s_ci[n++] = bi;
            }
        }
        for (; n < TCAP; ++n) s_ci[n] = IDX_INVALID;
    }
    __syncthreads();

#pragma unroll
    for (int t = 0; t < (TCAP * 64) / 256; ++t) {
        int idx = tid + t * 256;
        int r = idx >> 6, d2 = idx & 63;
        u32 ci = s_ci[r];
        s_cv[idx] = (ci != IDX_INVALID) ? fit[(size_t)ci * D + d2]
                                        : __uint_as_float(NANF_BITS);
    }

    if (tid < TCAP) {
        u32 ci = s_ci[tid];
        double kd = 1.0e300;
        if (ci != IDX_INVALID) {
            const float* row = fit + (size_t)ci * D;
            double ss = 0.0; int pr = 0;
            for (int j = 0; j < D; ++j) {
                float yf = row[j];
                int vmiss = f32_missing_bits(__float_as_uint(yf));
                u32 xbit = (j < 32) ? ((xmlo >> j) & 1u) : ((xmhi >> (j - 32)) & 1u);
                int ok = (int)xbit & (vmiss ^ 1);
                double dd = ok ? ((double)s_xv[j] - (double)yf) : 0.0;
                ss = fma(dd, dd, ss);
                pr += ok;
            }
            kd = (pr > 0) ? (ss / (double)pr) : 1.0e300;
        }
        s_kd[tid] = kd;
    }
    __syncthreads();

    if (tid < 64) {
        const int d = tid;
        u32 xobs = (d < 32) ? ((xmlo >> d) & 1u) : ((xmhi >> (d - 32)) & 1u);
        float res;
        if (xobs) {
            res = s_xv[d];
        } else {
            u64 used = 0; float sum = 0.f; int cnt = 0;
            for (int s = 0; s < K; ++s) {
                int best = -1; double bk = 0.0; u32 bi = 0;
                for (int r = 0; r < TCAP; ++r) {
                    if ((used >> r) & 1ull) continue;
                    u32 ci = s_ci[r];
                    if (ci == IDX_INVALID) continue;
                    float v = s_cv[r * 64 + d];
                    if (f32_missing_bits(__float_as_uint(v))) continue;
                    double kd = s_kd[r];
                    if (kd >= 1.0e300) continue;
                    if (best < 0 || kd < bk || (kd == bk && ci < bi)) {
                        best = r; bk = kd; bi = ci;
                    }
                }
                if (best < 0) break;
                used |= 1ull << best;
                sum += s_cv[best * 64 + d];
                cnt++;
            }
            if (cnt > 0) {
                res = sum / (float)cnt;
            } else {
                float cs = 0.f; int cc = 0;
                for (int f = 0; f < NF; ++f) {
                    float yf = fit[(size_t)f * D + d];
                    if (!f32_missing_bits(__float_as_uint(yf))) { cs += yf; cc++; }
                }
                res = cc > 0 ? cs / (float)cc : 0.f;
            }
            u32 rb = __float_as_uint(res);
            if (((rb >> 23) & 0xFFu) == 0xFFu) res = 0.f;
        }
        out[(size_t)q * D + d] = res;
    }
}

// ---- launch ------------------------------------------------------------------
extern "C" void kernel_launch(void* const* d_in, const int* in_sizes, int n_in,
                              void* d_out, int out_size, void* d_ws, size_t ws_size,
                              hipStream_t stream) {
    const void* pX = d_in[0];
    const void* pF = (n_in > 1) ? d_in[1] : d_in[0];
    const void* pK = (n_in > 2) ? d_in[2] : d_in[0];
    for (int i = 0; i < n_in; ++i) {
        if (in_sizes[i] == NQ * D)      pX = d_in[i];
        else if (in_sizes[i] == NF * D) pF = d_in[i];
        else if (in_sizes[i] == 1)      pK = d_in[i];
    }
    const float* X   = (const float*)pX;
    const float* fit = (const float*)pF;
    const int*   pk  = (const int*)pK;
    float* out = (float*)d_out;

    const size_t need = (size_t)NTILES * 384 * 16;   // 3 MB of fragments
    if (ws_size >= need) {
        uint4* frags = (uint4*)d_ws;
        prep_frags<<<(NTILES * 384) / 256, 256, 0, stream>>>(fit, frags);
        knn_mfma<<<NQ / QB, 256, 0, stream>>>(X, fit, frags, pk, out);
    } else {
        knn_fb<<<NQ, 256, 0, stream>>>(X, fit, pk, out);
    }
}

// Round 5
// 2112.032 us; speedup vs baseline: 16.8596x; 3.7022x over previous
//
#include <hip/hip_runtime.h>

// R19: wave-parallel phase 2. R18 counters (MfmaUtil 0.7, VALUBusy 5, dur
// 7.8ms) show phase 1 (MFMA ~2us + 175us L2) is ~3% of runtime; the rest is
// phase 2's serial machinery: same-address LDS atomic histogram (keys
// concentrate in 1-2 exponent bins), 4x 256-iter tid==0 dependent-LDS scans
// per query, and 64-of-256-thread epilogues, x8 queries sequential.
// (SQ_LDS_BANK_CONFLICT 9.2e7 invariant across R15-R18 = phase-2 fingerprint.)
// R19: each wave owns one query (2 rounds x 4 waves, zero block barriers
// after phase 1):
//   threshold: 16-step binary search for the 32nd-smallest u16 key
//     (count<=mid via 64 u32 reads/lane + shfl_xor reduce; same thr16 value
//     as the radix version by construction);
//   collection: per-wave atomic append (candidate SET is order-independent:
//     below<32 always all collected; ties appended only if total<=64, else
//     rare lane-0 ascending scan = "all below + smallest-idx ties" exactly);
//   staging into the query's own dead key row, XOR-swizzled (j^(r&31)) so
//     2b row-scans and 2d column-scans are both bank-conflict-free;
//   fp64 re-key reads staged values (bit-identical to global re-read);
//   2d exact top-K unchanged, now 4 waves concurrently.
// Phase 1 (MFMA GEMM keys) byte-identical to proven R18.

#define NQ 16384
#define NF 8192
#define D  64
#define TCAP 64
#define RANK 32
#define QB 8
#define PADW 8208      // u16 key-row stride; 16416B rows, float-aligned
#define NTILES 512     // NF/16

typedef unsigned short u16;
typedef unsigned int u32;
typedef unsigned long long u64;
typedef __attribute__((ext_vector_type(8))) short bf16x8;
typedef __attribute__((ext_vector_type(4))) float f32x4;

#define IDX_INVALID 0xFFFFFFFFu
#define NANF_BITS   0x7FC00000u
#define FLTMAX_BITS 0x7F7FFFFFu

__device__ __forceinline__ int f32_missing_bits(u32 b) {
    return ((b >> 23) & 0xFFu) == 0xFFu;      // NaN/inf => missing
}
__device__ __forceinline__ u16 bf16_rne(float f) {
    u32 b = __float_as_uint(f);
    return (u16)((b + 0x7FFFu + ((b >> 16) & 1u)) >> 16);
}

// ---- prep: donor-side MFMA A-fragments into ws (unchanged from R18) ---------
__global__ __launch_bounds__(256) void prep_frags(const float* __restrict__ fit,
                                                  uint4* __restrict__ frags) {
    int idx  = blockIdx.x * 256 + threadIdx.x;    // 0 .. NTILES*384-1
    int lane = idx & 63;
    int kk   = (idx >> 6) & 1;
    int sel  = (idx >> 7) % 3;
    int t    = (idx >> 7) / 3;
    int donor = t * 16 + (lane & 15);
    int j0 = kk * 32 + ((lane >> 4) & 3) * 8;
    const float* row = fit + (size_t)donor * D + j0;
    u32 w[4];
#pragma unroll
    for (int p = 0; p < 4; ++p) {
        u16 h0, h1;
        {
            float v = row[p * 2];
            int miss = f32_missing_bits(__float_as_uint(v));
            float vc = miss ? 0.f : v;
            float val = (sel == 0) ? (miss ? 0.f : 1.f) : (sel == 1) ? vc * vc : vc;
            h0 = bf16_rne(val);
        }
        {
            float v = row[p * 2 + 1];
            int miss = f32_missing_bits(__float_as_uint(v));
            float vc = miss ? 0.f : v;
            float val = (sel == 0) ? (miss ? 0.f : 1.f) : (sel == 1) ? vc * vc : vc;
            h1 = bf16_rne(val);
        }
        w[p] = (u32)h0 | ((u32)h1 << 16);
    }
    frags[idx] = make_uint4(w[0], w[1], w[2], w[3]);
}

#define MF(A, B, C) __builtin_amdgcn_mfma_f32_16x16x32_bf16(                  \
        __builtin_bit_cast(bf16x8, (A)), (B), (C), 0, 0, 0)

#define LOADT(T, A0, A1, A2, A3, A4, A5) {                                    \
        size_t bo = (size_t)(T) * 384 + lane;                                 \
        A0 = frags[bo];       A1 = frags[bo + 64];                            \
        A2 = frags[bo + 128]; A3 = frags[bo + 192];                           \
        A4 = frags[bo + 256]; A5 = frags[bo + 320]; }

__global__ __launch_bounds__(256) void knn_mfma(
        const float* __restrict__ X,
        const float* __restrict__ fit,
        const uint4* __restrict__ frags,
        const int* __restrict__ pk,
        float* __restrict__ out) {
    __shared__ __align__(16) u16 s_k16[QB * PADW];   // 131,328 B
    __shared__ __align__(16) float s_xv[QB][D];      // 2 KB
    __shared__ u64    s_xmask[QB];
    __shared__ u32    s_ci[4][TCAP];                 // per-wave
    __shared__ double s_kd[4][TCAP];                 // per-wave
    __shared__ u32    s_cnt[4];                      // per-wave append counter

    const int tid = threadIdx.x;
    const int q0 = blockIdx.x * QB;

    // ---- load QB=8 query rows + observed masks (wave-ballot per query) ----
#pragma unroll
    for (int rr = 0; rr < 2; ++rr) {
        int qq = rr * 4 + (tid >> 6);
        int d  = tid & 63;
        float xf = X[(size_t)(q0 + qq) * D + d];
        int obs = !f32_missing_bits(__float_as_uint(xf));
        s_xv[qq][d] = obs ? xf : 0.f;
        u64 bal = __ballot(obs != 0);
        if (d == 0) s_xmask[qq] = bal;
    }
    __syncthreads();

    // ---- build query-side B fragments (once; 24 VGPRs) ----
    const int lane = tid & 63;
    const int qcol = lane & 15;          // MFMA B col / D col = query
    const int krow = (lane >> 4) & 3;    // k-group
    bf16x8 bXX0 = (bf16x8)(short)0, bXX1 = (bf16x8)(short)0;
    bf16x8 bOX0 = (bf16x8)(short)0, bOX1 = (bf16x8)(short)0;
    bf16x8 bM0  = (bf16x8)(short)0, bM1  = (bf16x8)(short)0;
    if (qcol < QB) {
        const float* xr = s_xv[qcol];
        u64 xm = s_xmask[qcol];
#pragma unroll
        for (int e = 0; e < 8; ++e) {
            {
                int j = krow * 8 + e;                   // features 0..31
                float x = xr[j];
                bXX0[e] = (short)bf16_rne(x * x);
                bOX0[e] = (short)(((xm >> j) & 1ull) ? 0x3F80 : 0);
                bM0[e]  = (short)bf16_rne(-2.f * x);
            }
            {
                int j = 32 + krow * 8 + e;              // features 32..63
                float x = xr[j];
                bXX1[e] = (short)bf16_rne(x * x);
                bOX1[e] = (short)(((xm >> j) & 1ull) ? 0x3F80 : 0);
                bM1[e]  = (short)bf16_rne(-2.f * x);
            }
        }
    }

    // ---- phase 1: MFMA over 128 donor tiles per wave (unchanged R18) ----
    {
        const int wv = tid >> 6;
        int t = wv * 128;
        uint4 c0, c1, c2, c3, c4, c5;
        uint4 n0 = {}, n1 = {}, n2 = {}, n3 = {}, n4 = {}, n5 = {};
        LOADT(t, c0, c1, c2, c3, c4, c5);
#pragma unroll 1
        for (int tt = 0; tt < 128; ++tt) {
            bool hasn = (tt + 1 < 128);
            if (hasn) LOADT(t + 1, n0, n1, n2, n3, n4, n5);
            f32x4 accS = {0.f, 0.f, 0.f, 0.f};
            f32x4 accP = {0.f, 0.f, 0.f, 0.f};
            accS = MF(c0, bXX0, accS);   // obsY . x^2
            accS = MF(c1, bXX1, accS);
            accS = MF(c2, bOX0, accS);   // v^2 . obsX
            accS = MF(c3, bOX1, accS);
            accS = MF(c4, bM0,  accS);   // v . (-2x)
            accS = MF(c5, bM1,  accS);
            accP = MF(c0, bOX0, accP);   // obsY . obsX
            accP = MF(c1, bOX1, accP);
            if (qcol < QB) {
#define MKKEY(r) ((accP[r] > 0.5f)                                            \
                    ? __float_as_uint(__fdividef(fmaxf(accS[r], 0.f), accP[r]))\
                    : FLTMAX_BITS)
                u32 b0 = MKKEY(0), b1 = MKKEY(1), b2 = MKKEY(2), b3 = MKKEY(3);
#undef MKKEY
                u32 lo = (b0 >> 16) | (b1 & 0xFFFF0000u);
                u32 hi = (b2 >> 16) | (b3 & 0xFFFF0000u);
                u32 off = (u32)qcol * PADW + (u32)t * 16 + (u32)krow * 4;
                *(uint2*)(&s_k16[off]) = make_uint2(lo, hi);
            }
            if (hasn) { c0 = n0; c1 = n1; c2 = n2; c3 = n3; c4 = n4; c5 = n5; }
            ++t;
        }
    }
    __syncthreads();    // keys complete; no further block barriers

    int K = *pk;
    if (K < 1 || K > 64) {                 // robustness if scalar arrived as float
        float kf = __int_as_float(K);
        K = (kf >= 1.f && kf <= 64.f) ? (int)kf : 5;
    }
    if (K > TCAP) K = TCAP;

    // ---- phase 2: each wave owns one query; 2 rounds; no block barriers ----
    const int wv = tid >> 6;
#pragma unroll 1
    for (int rr = 0; rr < 2; ++rr) {
        const int qq = wv + rr * 4;
        const int q = q0 + qq;
        u16* kq = s_k16 + (size_t)qq * PADW;
        const u32* kq32 = (const u32*)kq;            // 4096 u32 = 8192 keys
        const u64 xm = s_xmask[qq];
        const u32 xmlo = (u32)xm, xmhi = (u32)(xm >> 32);

        // -- 2a: 32nd-smallest u16 key via binary search (== radix thr16) --
        u32 blo = 0, bhi = 65535;
#pragma unroll 1
        while (blo < bhi) {
            u32 mid = (blo + bhi) >> 1;
            int c = 0;
#pragma unroll 8
            for (int i = 0; i < 64; ++i) {
                u32 w2 = kq32[lane + (i << 6)];
                c += ((w2 & 0xFFFFu) <= mid) + ((w2 >> 16) <= mid);
            }
#pragma unroll
            for (int o = 32; o; o >>= 1) c += __shfl_xor(c, o, 64);
            if ((u32)c >= (u32)RANK) bhi = mid; else blo = mid + 1;
        }
        const u32 thr16 = blo;

        // -- 2a': collection. Count below/ties; set is order-independent. --
        if (lane == 0) s_cnt[wv] = 0;                // in-wave LDS order: ok
        int nb = 0, nt2 = 0;
#pragma unroll 8
        for (int i = 0; i < 64; ++i) {
            u32 w2 = kq32[lane + (i << 6)];
            u32 k0 = w2 & 0xFFFFu, k1 = w2 >> 16;
            nb  += (k0 < thr16)  + (k1 < thr16);
            nt2 += (k0 == thr16) + (k1 == thr16);
        }
        int tb = nb, tt2 = nt2;
#pragma unroll
        for (int o = 32; o; o >>= 1) {
            tb  += __shfl_xor(tb, o, 64);
            tt2 += __shfl_xor(tt2, o, 64);
        }
        const int nTot = tb + tt2;                   // >= RANK
        if (nTot <= TCAP) {
            // parallel append (all below + ALL ties fit: same set as R15)
#pragma unroll 4
            for (int i = 0; i < 64; ++i) {
                u32 w2 = kq32[lane + (i << 6)];
                u32 k0 = w2 & 0xFFFFu, k1 = w2 >> 16;
                int f0 = (lane + (i << 6)) * 2;
                if (k0 <= thr16) { u32 p = atomicAdd(&s_cnt[wv], 1u); s_ci[wv][p] = (u32)f0; }
                if (k1 <= thr16) { u32 p = atomicAdd(&s_cnt[wv], 1u); s_ci[wv][p] = (u32)(f0 + 1); }
            }
            if (lane >= nTot) s_ci[wv][lane] = IDX_INVALID;   // pad tail
        } else {
            // rare: overflow -> all below, then ties ascending (smallest idx)
            if (lane == 0) {
                int n = 0;
                for (int f = 0; f < NF; ++f)
                    if ((u32)kq[f] < thr16) s_ci[wv][n++] = (u32)f;
                for (int f = 0; f < NF && n < TCAP; ++f)
                    if ((u32)kq[f] == thr16) s_ci[wv][n++] = (u32)f;
                for (; n < TCAP; ++n) s_ci[wv][n] = IDX_INVALID;
            }
        }

        // -- 2c: stage candidates into this query's DEAD key row, swizzled --
        float* cv = (float*)kq;                      // 16,384B of 16,416B row
        u32 myci = s_ci[wv][lane];                   // candidate r = lane
#pragma unroll 8
        for (int r = 0; r < TCAP; ++r) {
            u32 ci = __shfl((int)myci, r, 64);       // broadcast, no LDS dep
            float v = (ci != IDX_INVALID) ? fit[(size_t)ci * D + lane]
                                          : __uint_as_float(NANF_BITS);
            cv[(r << 6) + (lane ^ (r & 31))] = v;    // conflict-free writes
        }

        // -- 2b: exact fp64 re-key from staged values (bit-identical) --
        {
            double ss = 0.0; int pr2 = 0;
#pragma unroll 8
            for (int j = 0; j < D; ++j) {
                float yf = cv[(lane << 6) + (j ^ (lane & 31))];
                int vmiss = f32_missing_bits(__float_as_uint(yf));
                u32 xbit = (j < 32) ? ((xmlo >> j) & 1u) : ((xmhi >> (j - 32)) & 1u);
                int ok = (int)xbit & (vmiss ^ 1);
                double dd = ok ? ((double)s_xv[qq][j] - (double)yf) : 0.0;
                ss = fma(dd, dd, ss);
                pr2 += ok;
            }
            double kd = (myci != IDX_INVALID && pr2 > 0) ? (ss / (double)pr2)
                                                         : 1.0e300;
            s_kd[wv][lane] = kd;
        }

        // -- 2d: per-column exact top-K imputation (all 64 lanes = columns) --
        {
            const int d = lane;
            u32 xobs = (d < 32) ? ((xmlo >> d) & 1u) : ((xmhi >> (d - 32)) & 1u);
            float res;
            if (xobs) {
                res = s_xv[qq][d];
            } else {
                u64 used = 0; float sum = 0.f; int cnt = 0;
                for (int s = 0; s < K; ++s) {
                    int best = -1; double bk = 0.0; u32 bi = 0;
                    for (int r = 0; r < TCAP; ++r) {
                        if ((used >> r) & 1ull) continue;
                        u32 ci = s_ci[wv][r];
                        if (ci == IDX_INVALID) continue;
                        float v = cv[(r << 6) + (d ^ (r & 31))];
                        if (f32_missing_bits(__float_as_uint(v))) continue;
                        double kd = s_kd[wv][r];
                        if (kd >= 1.0e300) continue;
                        if (best < 0 || kd < bk || (kd == bk && ci < bi)) {
                            best = r; bk = kd; bi = ci;
                        }
                    }
                    if (best < 0) break;
                    used |= 1ull << best;
                    sum += cv[(best << 6) + (d ^ (best & 31))];
                    cnt++;
                }
                if (cnt > 0) {
                    res = sum / (float)cnt;
                } else {
                    float cs = 0.f; int cc = 0;        // essentially-never fallback
                    for (int f = 0; f < NF; ++f) {
                        float yf = fit[(size_t)f * D + d];
                        if (!f32_missing_bits(__float_as_uint(yf))) { cs += yf; cc++; }
                    }
                    res = cc > 0 ? cs / (float)cc : 0.f;
                }
                u32 rb = __float_as_uint(res);
                if (((rb >> 23) & 0xFFu) == 0xFFu) res = 0.f;   // integer guard
            }
            out[(size_t)q * D + d] = res;
        }
        // round rr+1 uses a different key row; all state per-wave => no sync
    }
}

// ---- fallback: proven R15 kernel, row-major path (1 query/block) ------------
__global__ __launch_bounds__(256) void knn_fb(
        const float* __restrict__ X,
        const float* __restrict__ fit,
        const int* __restrict__ pk,
        float* __restrict__ out) {
    __shared__ __align__(16) unsigned char s_pool[16384];
    __shared__ u32   s_hist[256];
    __shared__ u32   s_blw[256];
    __shared__ u32   s_tie[256];
    __shared__ __align__(16) float s_xv[D];
    __shared__ u64   s_xmask;
    __shared__ u32   s_ci[TCAP];
    __shared__ double s_kd[TCAP];
    __shared__ u32   s_sel0, s_below0, s_sel1;

    u16*   s_k16 = (u16*)s_pool;
    float* s_cv  = (float*)s_pool;
    const int tid = threadIdx.x;
    const int q = blockIdx.x;

    if (tid < 64) {
        float xf = X[(size_t)q * D + tid];
        int obs = !f32_missing_bits(__float_as_uint(xf));
        s_xv[tid] = obs ? xf : 0.f;
        u64 bal = __ballot(obs != 0);
        if (tid == 0) s_xmask = bal;
    }
    __syncthreads();

    const u64 xm = s_xmask;
    const u32 xmlo = (u32)xm, xmhi = (u32)(xm >> 32);
    const float4* xv4 = (const float4*)s_xv;
    const float4* fitc = (const float4*)fit;

    for (int i = 0; i < 32; ++i) {
        int f = tid + (i << 8);
        const float4* rp = fitc + (size_t)f * 16;
        float ssd = 0.f; int pres = 0;
#pragma unroll
        for (int m = 0; m < 16; ++m) {
            float4 w = rp[m];
            float4 xc = xv4[m];
            u32 mb = (m < 8) ? (xmlo >> ((m & 7) * 4)) : (xmhi >> ((m & 7) * 4));
            float wv[4] = { w.x, w.y, w.z, w.w };
            float xw[4] = { xc.x, xc.y, xc.z, xc.w };
#pragma unroll
            for (int u = 0; u < 4; ++u) {
                int ok = (int)((mb >> u) & 1u)
                       & (f32_missing_bits(__float_as_uint(wv[u])) ^ 1);
                float t = ok ? wv[u] : xw[u];
                float dm = xw[u] - t;
                ssd = fmaf(dm, dm, ssd);
                pres += ok;
            }
        }
        float kk = (pres > 0) ? (ssd / (float)pres) : __uint_as_float(FLTMAX_BITS);
        s_k16[f] = (u16)(__float_as_uint(kk) >> 16);
    }
    __syncthreads();

    int K = *pk;
    if (K < 1 || K > 64) {
        float kf = __int_as_float(K);
        K = (kf >= 1.f && kf <= 64.f) ? (int)kf : 5;
    }
    if (K > TCAP) K = TCAP;

    s_hist[tid] = 0;
    __syncthreads();
    for (int i = 0; i < 32; ++i) {
        u32 k16 = (u32)s_k16[tid + (i << 8)];
        atomicAdd(&s_hist[k16 >> 8], 1u);
    }
    __syncthreads();
    if (tid == 0) {
        u32 run = 0, below = 0, sel = 255;
        for (int b = 0; b < 256; ++b) {
            u32 c = s_hist[b];
            if (run + c >= (u32)RANK) { sel = (u32)b; below = run; break; }
            run += c;
        }
        s_sel0 = sel; s_below0 = below;
    }
    __syncthreads();
    const u32 sel0 = s_sel0;
    const u32 need1 = (u32)RANK - s_below0;
    __syncthreads();
    s_hist[tid] = 0;
    __syncthreads();
    for (int i = 0; i < 32; ++i) {
        u32 k16 = (u32)s_k16[tid + (i << 8)];
        if ((k16 >> 8) == sel0) atomicAdd(&s_hist[k16 & 0xFFu], 1u);
    }
    __syncthreads();
    if (tid == 0) {
        u32 run = 0, sel = 255;
        for (int b = 0; b < 256; ++b) {
            u32 c = s_hist[b];
            if (run + c >= need1) { sel = (u32)b; break; }
            run += c;
        }
        s_sel1 = sel;
    }
    __syncthreads();
    const u32 thr16 = (sel0 << 8) | s_sel1;

    {
        u32 bb = 0, tb = 0;
        for (int i = 0; i < 32; ++i) {
            u32 k16 = (u32)s_k16[tid + (i << 8)];
            bb |= (k16 < thr16)  ? (1u << i) : 0u;
            tb |= (k16 == thr16) ? (1u << i) : 0u;
        }
        s_blw[tid] = bb; s_tie[tid] = tb;
    }
    __syncthreads();
    if (tid == 0) {
        int n = 0;
        for (int t = 0; t < 256 && n < TCAP; ++t) {
            u32 w = s_blw[t];
            while (w && n < TCAP) {
                int i = __ffs(w) - 1; w &= w - 1;
                s_ci[n++] = (u32)(i * 256 + t);
            }
        }
        u32 tf[TCAP]; int nt = 0;
        for (int t = 0; t < 256 && nt < TCAP; ++t) {
            u32 w = s_tie[t];
            while (w && nt < TCAP) {
                int i = __ffs(w) - 1; w &= w - 1;
                tf[nt++] = (u32)(i * 256 + t);
            }
        }
        int cap = TCAP - n;
        if (nt <= cap) {
            for (int r = 0; r < nt; ++r) s_ci[n++] = tf[r];
        } else {
            for (int j = 0; j < cap; ++j) {
                int bp = -1; u32 bi = IDX_INVALID;
                for (int r = 0; r < nt; ++r)
                    if (tf[r] < bi) { bi = tf[r]; bp = r; }
                tf[bp] = IDX_INVALID;
                s_ci[n++] = bi;
            }
        }
        for (; n < TCAP; ++n) s_ci[n] = IDX_INVALID;
    }
    __syncthreads();

#pragma unroll
    for (int t = 0; t < (TCAP * 64) / 256; ++t) {
        int idx = tid + t * 256;
        int r = idx >> 6, d2 = idx & 63;
        u32 ci = s_ci[r];
        s_cv[idx] = (ci != IDX_INVALID) ? fit[(size_t)ci * D + d2]
                                        : __uint_as_float(NANF_BITS);
    }

    if (tid < TCAP) {
        u32 ci = s_ci[tid];
        double kd = 1.0e300;
        if (ci != IDX_INVALID) {
            const float* row = fit + (size_t)ci * D;
            double ss = 0.0; int pr = 0;
            for (int j = 0; j < D; ++j) {
                float yf = row[j];
                int vmiss = f32_missing_bits(__float_as_uint(yf));
                u32 xbit = (j < 32) ? ((xmlo >> j) & 1u) : ((xmhi >> (j - 32)) & 1u);
                int ok = (int)xbit & (vmiss ^ 1);
                double dd = ok ? ((double)s_xv[j] - (double)yf) : 0.0;
                ss = fma(dd, dd, ss);
                pr += ok;
            }
            kd = (pr > 0) ? (ss / (double)pr) : 1.0e300;
        }
        s_kd[tid] = kd;
    }
    __syncthreads();

    if (tid < 64) {
        const int d = tid;
        u32 xobs = (d < 32) ? ((xmlo >> d) & 1u) : ((xmhi >> (d - 32)) & 1u);
        float res;
        if (xobs) {
            res = s_xv[d];
        } else {
            u64 used = 0; float sum = 0.f; int cnt = 0;
            for (int s = 0; s < K; ++s) {
                int best = -1; double bk = 0.0; u32 bi = 0;
                for (int r = 0; r < TCAP; ++r) {
                    if ((used >> r) & 1ull) continue;
                    u32 ci = s_ci[r];
                    if (ci == IDX_INVALID) continue;
                    float v = s_cv[r * 64 + d];
                    if (f32_missing_bits(__float_as_uint(v))) continue;
                    double kd = s_kd[r];
                    if (kd >= 1.0e300) continue;
                    if (best < 0 || kd < bk || (kd == bk && ci < bi)) {
                        best = r; bk = kd; bi = ci;
                    }
                }
                if (best < 0) break;
                used |= 1ull << best;
                sum += s_cv[best * 64 + d];
                cnt++;
            }
            if (cnt > 0) {
                res = sum / (float)cnt;
            } else {
                float cs = 0.f; int cc = 0;
                for (int f = 0; f < NF; ++f) {
                    float yf = fit[(size_t)f * D + d];
                    if (!f32_missing_bits(__float_as_uint(yf))) { cs += yf; cc++; }
                }
                res = cc > 0 ? cs / (float)cc : 0.f;
            }
            u32 rb = __float_as_uint(res);
            if (((rb >> 23) & 0xFFu) == 0xFFu) res = 0.f;
        }
        out[(size_t)q * D + d] = res;
    }
}

// ---- launch ------------------------------------------------------------------
extern "C" void kernel_launch(void* const* d_in, const int* in_sizes, int n_in,
                              void* d_out, int out_size, void* d_ws, size_t ws_size,
                              hipStream_t stream) {
    const void* pX = d_in[0];
    const void* pF = (n_in > 1) ? d_in[1] : d_in[0];
    const void* pK = (n_in > 2) ? d_in[2] : d_in[0];
    for (int i = 0; i < n_in; ++i) {
        if (in_sizes[i] == NQ * D)      pX = d_in[i];
        else if (in_sizes[i] == NF * D) pF = d_in[i];
        else if (in_sizes[i] == 1)      pK = d_in[i];
    }
    const float* X   = (const float*)pX;
    const float* fit = (const float*)pF;
    const int*   pk  = (const int*)pK;
    float* out = (float*)d_out;

    const size_t need = (size_t)NTILES * 384 * 16;   // 3 MB of fragments
    if (ws_size >= need) {
        uint4* frags = (uint4*)d_ws;
        prep_frags<<<(NTILES * 384) / 256, 256, 0, stream>>>(fit, frags);
        knn_mfma<<<NQ / QB, 256, 0, stream>>>(X, fit, frags, pk, out);
    } else {
        knn_fb<<<NQ, 256, 0, stream>>>(X, fit, pk, out);
    }
}

// Round 6
// 1116.226 us; speedup vs baseline: 31.9004x; 1.8921x over previous
//
#include <hip/hip_runtime.h>

// R20: two-kernel split. R19 (2112us) counters: MfmaUtil 2.6, VALUBusy 22.6,
// Occupancy 12% -> phase 2 is latency-bound at 1 block/CU (136KB LDS pins 4
// waves/CU). Decouple: kernel A = MFMA keys with QB=16 (full B-frag width,
// frag L2 traffic halved) -> u16 keys to workspace (chunked; 256MB full-size).
// Kernel B = selection, ONE WAVE per block, ~17.5KB LDS (key row overlaid by
// cv staging) -> ~9 blocks/CU (=28% occupancy, 2.25x waves). Phase-2 code is
// R19's proven machinery verbatim; binary search seeded with [min, max-of-
// lane-minima] bracket (valid: 64 lane-minima <= hi0 => count(<=hi0)>=64>=32)
// -> ~10 steps instead of 16. Keys bit-identical (MFMA cols independent, same
// MKKEY); thr + candidate-set semantics identical => same output as R19.
// Fallbacks: ws >= 3MB+32MB two-kernel chunked; >=3MB R19 kernel; else R15.

#define NQ 16384
#define NF 8192
#define D  64
#define TCAP 64
#define RANK 32
#define QB 8            // R19 fallback kernel
#define QA 16           // kernel-A queries per block
#define PADW 8208
#define NTILES 512      // NF/16
#define FRAG_BYTES ((size_t)NTILES * 384 * 16)   // 3 MB

typedef unsigned short u16;
typedef unsigned int u32;
typedef unsigned long long u64;
typedef __attribute__((ext_vector_type(8))) short bf16x8;
typedef __attribute__((ext_vector_type(4))) float f32x4;

#define IDX_INVALID 0xFFFFFFFFu
#define NANF_BITS   0x7FC00000u
#define FLTMAX_BITS 0x7F7FFFFFu

__device__ __forceinline__ int f32_missing_bits(u32 b) {
    return ((b >> 23) & 0xFFu) == 0xFFu;      // NaN/inf => missing
}
__device__ __forceinline__ u16 bf16_rne(float f) {
    u32 b = __float_as_uint(f);
    return (u16)((b + 0x7FFFu + ((b >> 16) & 1u)) >> 16);
}

// ---- prep: donor-side MFMA A-fragments into ws (unchanged, proven) ----------
__global__ __launch_bounds__(256) void prep_frags(const float* __restrict__ fit,
                                                  uint4* __restrict__ frags) {
    int idx  = blockIdx.x * 256 + threadIdx.x;    // 0 .. NTILES*384-1
    int lane = idx & 63;
    int kk   = (idx >> 6) & 1;
    int sel  = (idx >> 7) % 3;
    int t    = (idx >> 7) / 3;
    int donor = t * 16 + (lane & 15);
    int j0 = kk * 32 + ((lane >> 4) & 3) * 8;
    const float* row = fit + (size_t)donor * D + j0;
    u32 w[4];
#pragma unroll
    for (int p = 0; p < 4; ++p) {
        u16 h0, h1;
        {
            float v = row[p * 2];
            int miss = f32_missing_bits(__float_as_uint(v));
            float vc = miss ? 0.f : v;
            float val = (sel == 0) ? (miss ? 0.f : 1.f) : (sel == 1) ? vc * vc : vc;
            h0 = bf16_rne(val);
        }
        {
            float v = row[p * 2 + 1];
            int miss = f32_missing_bits(__float_as_uint(v));
            float vc = miss ? 0.f : v;
            float val = (sel == 0) ? (miss ? 0.f : 1.f) : (sel == 1) ? vc * vc : vc;
            h1 = bf16_rne(val);
        }
        w[p] = (u32)h0 | ((u32)h1 << 16);
    }
    frags[idx] = make_uint4(w[0], w[1], w[2], w[3]);
}

#define MF(A, B, C) __builtin_amdgcn_mfma_f32_16x16x32_bf16(                  \
        __builtin_bit_cast(bf16x8, (A)), (B), (C), 0, 0, 0)

#define LOADT(T, A0, A1, A2, A3, A4, A5) {                                    \
        size_t bo = (size_t)(T) * 384 + lane;                                 \
        A0 = frags[bo];       A1 = frags[bo + 64];                            \
        A2 = frags[bo + 128]; A3 = frags[bo + 192];                           \
        A4 = frags[bo + 256]; A5 = frags[bo + 320]; }

// ---- kernel A: QB=16 MFMA keys -> global workspace --------------------------
__global__ __launch_bounds__(256) void knn_keys(
        const float* __restrict__ X,
        const uint4* __restrict__ frags,
        u16* __restrict__ keys,                   // [chunkQ][NF]
        const int* __restrict__ pk,               // unused; uniform signature
        int cq0) {
    __shared__ __align__(16) float s_xv[QA][D];
    __shared__ u64 s_xmask[QA];

    const int tid = threadIdx.x;
    const int qb0 = blockIdx.x * QA;              // local query base

#pragma unroll
    for (int rr = 0; rr < 4; ++rr) {
        int qq = rr * 4 + (tid >> 6);
        int d  = tid & 63;
        float xf = X[(size_t)(cq0 + qb0 + qq) * D + d];
        int obs = !f32_missing_bits(__float_as_uint(xf));
        s_xv[qq][d] = obs ? xf : 0.f;
        u64 bal = __ballot(obs != 0);
        if (d == 0) s_xmask[qq] = bal;
    }
    __syncthreads();

    const int lane = tid & 63;
    const int qcol = lane & 15;                   // all 16 columns used
    const int krow = (lane >> 4) & 3;
    bf16x8 bXX0, bXX1, bOX0, bOX1, bM0, bM1;
    {
        const float* xr = s_xv[qcol];
        u64 xm = s_xmask[qcol];
#pragma unroll
        for (int e = 0; e < 8; ++e) {
            {
                int j = krow * 8 + e;
                float x = xr[j];
                bXX0[e] = (short)bf16_rne(x * x);
                bOX0[e] = (short)(((xm >> j) & 1ull) ? 0x3F80 : 0);
                bM0[e]  = (short)bf16_rne(-2.f * x);
            }
            {
                int j = 32 + krow * 8 + e;
                float x = xr[j];
                bXX1[e] = (short)bf16_rne(x * x);
                bOX1[e] = (short)(((xm >> j) & 1ull) ? 0x3F80 : 0);
                bM1[e]  = (short)bf16_rne(-2.f * x);
            }
        }
    }

    const int wv = tid >> 6;
    int t = wv * 128;
    uint4 c0, c1, c2, c3, c4, c5;
    uint4 n0 = {}, n1 = {}, n2 = {}, n3 = {}, n4 = {}, n5 = {};
    LOADT(t, c0, c1, c2, c3, c4, c5);
#pragma unroll 1
    for (int tt = 0; tt < 128; ++tt) {
        bool hasn = (tt + 1 < 128);
        if (hasn) LOADT(t + 1, n0, n1, n2, n3, n4, n5);
        f32x4 accS = {0.f, 0.f, 0.f, 0.f};
        f32x4 accP = {0.f, 0.f, 0.f, 0.f};
        accS = MF(c0, bXX0, accS);   // obsY . x^2
        accS = MF(c1, bXX1, accS);
        accS = MF(c2, bOX0, accS);   // v^2 . obsX
        accS = MF(c3, bOX1, accS);
        accS = MF(c4, bM0,  accS);   // v . (-2x)
        accS = MF(c5, bM1,  accS);
        accP = MF(c0, bOX0, accP);   // obsY . obsX
        accP = MF(c1, bOX1, accP);
#define MKKEY(r) ((accP[r] > 0.5f)                                            \
                    ? __float_as_uint(__fdividef(fmaxf(accS[r], 0.f), accP[r]))\
                    : FLTMAX_BITS)
        u32 b0 = MKKEY(0), b1 = MKKEY(1), b2 = MKKEY(2), b3 = MKKEY(3);
#undef MKKEY
        u32 lo = (b0 >> 16) | (b1 & 0xFFFF0000u);
        u32 hi = (b2 >> 16) | (b3 & 0xFFFF0000u);
        size_t off = (size_t)(qb0 + qcol) * NF + (size_t)t * 16 + krow * 4;
        *(uint2*)(keys + off) = make_uint2(lo, hi);
        if (hasn) { c0 = n0; c1 = n1; c2 = n2; c3 = n3; c4 = n4; c5 = n5; }
        ++t;
    }
}

// ---- kernel B: one wave per query; small LDS; R19 phase-2 machinery ---------
__global__ __launch_bounds__(64) void knn_sel(
        const float* __restrict__ X,
        const float* __restrict__ fit,
        const u16* __restrict__ keys,             // [chunkQ][NF]
        const int* __restrict__ pk,
        float* __restrict__ out,
        int cq0) {
    __shared__ __align__(16) u16 s_keys[NF];      // 16 KB; cv overlays later
    __shared__ __align__(16) float s_xv[D];
    __shared__ u32    s_ci[TCAP];
    __shared__ double s_kd[TCAP];
    __shared__ u32    s_cnt;

    const int lane = threadIdx.x;
    const int ql = blockIdx.x;                    // local query
    const int q  = cq0 + ql;                      // global query

    // ---- query row + mask ----
    float xf = X[(size_t)q * D + lane];
    int obs = !f32_missing_bits(__float_as_uint(xf));
    s_xv[lane] = obs ? xf : 0.f;
    const u64 xm = __ballot(obs != 0);
    const u32 xmlo = (u32)xm, xmhi = (u32)(xm >> 32);

    // ---- stage keys coalesced; track per-lane min ----
    u32 mymin = 0xFFFFu;
    {
        const uint4* kg = (const uint4*)(keys + (size_t)ql * NF);
        uint4* sk4 = (uint4*)s_keys;
#pragma unroll
        for (int i = 0; i < 16; ++i) {
            uint4 w = kg[lane + (i << 6)];
            sk4[lane + (i << 6)] = w;
#define MIN16S(W) { u32 a_ = (W) & 0xFFFFu, b_ = (W) >> 16;                    \
                    mymin = a_ < mymin ? a_ : mymin;                           \
                    mymin = b_ < mymin ? b_ : mymin; }
            MIN16S(w.x) MIN16S(w.y) MIN16S(w.z) MIN16S(w.w)
#undef MIN16S
        }
    }
    u32 lo0 = mymin, hi0 = mymin;                 // bracket: [min, max-of-lane-mins]
#pragma unroll
    for (int o = 32; o; o >>= 1) {
        u32 a = (u32)__shfl_xor((int)lo0, o, 64); lo0 = a < lo0 ? a : lo0;
        u32 b = (u32)__shfl_xor((int)hi0, o, 64); hi0 = b > hi0 ? b : hi0;
    }

    int K = *pk;
    if (K < 1 || K > 64) {                 // robustness if scalar arrived as float
        float kf = __int_as_float(K);
        K = (kf >= 1.f && kf <= 64.f) ? (int)kf : 5;
    }
    if (K > TCAP) K = TCAP;

    const u32* kq32 = (const u32*)s_keys;

    // -- 2a: 32nd-smallest u16 key via bracketed binary search --
    u32 blo = lo0, bhi = hi0;
#pragma unroll 1
    while (blo < bhi) {
        u32 mid = (blo + bhi) >> 1;
        int c = 0;
#pragma unroll 8
        for (int i = 0; i < 64; ++i) {
            u32 w2 = kq32[lane + (i << 6)];
            c += ((w2 & 0xFFFFu) <= mid) + ((w2 >> 16) <= mid);
        }
#pragma unroll
        for (int o = 32; o; o >>= 1) c += __shfl_xor(c, o, 64);
        if ((u32)c >= (u32)RANK) bhi = mid; else blo = mid + 1;
    }
    const u32 thr16 = blo;

    // -- 2a': collection (R19 semantics: set is order-independent) --
    if (lane == 0) s_cnt = 0;
    int nb = 0, nt2 = 0;
#pragma unroll 8
    for (int i = 0; i < 64; ++i) {
        u32 w2 = kq32[lane + (i << 6)];
        u32 k0 = w2 & 0xFFFFu, k1 = w2 >> 16;
        nb  += (k0 < thr16)  + (k1 < thr16);
        nt2 += (k0 == thr16) + (k1 == thr16);
    }
    int tb = nb, tt2 = nt2;
#pragma unroll
    for (int o = 32; o; o >>= 1) {
        tb  += __shfl_xor(tb, o, 64);
        tt2 += __shfl_xor(tt2, o, 64);
    }
    const int nTot = tb + tt2;                    // >= RANK
    if (nTot <= TCAP) {
#pragma unroll 4
        for (int i = 0; i < 64; ++i) {
            u32 w2 = kq32[lane + (i << 6)];
            u32 k0 = w2 & 0xFFFFu, k1 = w2 >> 16;
            int f0 = (lane + (i << 6)) * 2;
            if (k0 <= thr16) { u32 p = atomicAdd(&s_cnt, 1u); s_ci[p] = (u32)f0; }
            if (k1 <= thr16) { u32 p = atomicAdd(&s_cnt, 1u); s_ci[p] = (u32)(f0 + 1); }
        }
        if (lane >= nTot) s_ci[lane] = IDX_INVALID;
    } else {
        // rare overflow: all below, then ties ascending (smallest donor idx)
        if (lane == 0) {
            int n = 0;
            for (int f = 0; f < NF; ++f)
                if ((u32)s_keys[f] < thr16) s_ci[n++] = (u32)f;
            for (int f = 0; f < NF && n < TCAP; ++f)
                if ((u32)s_keys[f] == thr16) s_ci[n++] = (u32)f;
            for (; n < TCAP; ++n) s_ci[n] = IDX_INVALID;
        }
    }

    // -- 2c: stage candidates into dead key LDS, XOR-swizzled --
    float* cv = (float*)s_keys;
    u32 myci = s_ci[lane];
#pragma unroll 8
    for (int r = 0; r < TCAP; ++r) {
        u32 ci = __shfl((int)myci, r, 64);
        float v = (ci != IDX_INVALID) ? fit[(size_t)ci * D + lane]
                                      : __uint_as_float(NANF_BITS);
        cv[(r << 6) + (lane ^ (r & 31))] = v;
    }

    // -- 2b: exact fp64 re-key from staged values --
    {
        double ss = 0.0; int pr2 = 0;
#pragma unroll 8
        for (int j = 0; j < D; ++j) {
            float yf = cv[(lane << 6) + (j ^ (lane & 31))];
            int vmiss = f32_missing_bits(__float_as_uint(yf));
            u32 xbit = (j < 32) ? ((xmlo >> j) & 1u) : ((xmhi >> (j - 32)) & 1u);
            int ok = (int)xbit & (vmiss ^ 1);
            double dd = ok ? ((double)s_xv[j] - (double)yf) : 0.0;
            ss = fma(dd, dd, ss);
            pr2 += ok;
        }
        double kd = (myci != IDX_INVALID && pr2 > 0) ? (ss / (double)pr2)
                                                     : 1.0e300;
        s_kd[lane] = kd;
    }

    // -- 2d: per-column exact top-K imputation --
    {
        const int d = lane;
        u32 xobs = (d < 32) ? ((xmlo >> d) & 1u) : ((xmhi >> (d - 32)) & 1u);
        float res;
        if (xobs) {
            res = s_xv[d];
        } else {
            u64 used = 0; float sum = 0.f; int cnt = 0;
            for (int s = 0; s < K; ++s) {
                int best = -1; double bk = 0.0; u32 bi = 0;
                for (int r = 0; r < TCAP; ++r) {
                    if ((used >> r) & 1ull) continue;
                    u32 ci = s_ci[r];
                    if (ci == IDX_INVALID) continue;
                    float v = cv[(r << 6) + (d ^ (r & 31))];
                    if (f32_missing_bits(__float_as_uint(v))) continue;
                    double kd = s_kd[r];
                    if (kd >= 1.0e300) continue;
                    if (best < 0 || kd < bk || (kd == bk && ci < bi)) {
                        best = r; bk = kd; bi = ci;
                    }
                }
                if (best < 0) break;
                used |= 1ull << best;
                sum += cv[(best << 6) + (d ^ (best & 31))];
                cnt++;
            }
            if (cnt > 0) {
                res = sum / (float)cnt;
            } else {
                float cs = 0.f; int cc = 0;            // essentially-never fallback
                for (int f = 0; f < NF; ++f) {
                    float yf = fit[(size_t)f * D + d];
                    if (!f32_missing_bits(__float_as_uint(yf))) { cs += yf; cc++; }
                }
                res = cc > 0 ? cs / (float)cc : 0.f;
            }
            u32 rb = __float_as_uint(res);
            if (((rb >> 23) & 0xFFu) == 0xFFu) res = 0.f;   // integer guard
        }
        out[(size_t)q * D + d] = res;
    }
}

// ---- mid fallback: proven R19 single-kernel (verbatim) ----------------------
__global__ __launch_bounds__(256) void knn_mfma(
        const float* __restrict__ X,
        const float* __restrict__ fit,
        const uint4* __restrict__ frags,
        const int* __restrict__ pk,
        float* __restrict__ out) {
    __shared__ __align__(16) u16 s_k16[QB * PADW];
    __shared__ __align__(16) float s_xv[QB][D];
    __shared__ u64    s_xmask[QB];
    __shared__ u32    s_ci[4][TCAP];
    __shared__ double s_kd[4][TCAP];
    __shared__ u32    s_cnt[4];

    const int tid = threadIdx.x;
    const int q0 = blockIdx.x * QB;

#pragma unroll
    for (int rr = 0; rr < 2; ++rr) {
        int qq = rr * 4 + (tid >> 6);
        int d  = tid & 63;
        float xf = X[(size_t)(q0 + qq) * D + d];
        int obs = !f32_missing_bits(__float_as_uint(xf));
        s_xv[qq][d] = obs ? xf : 0.f;
        u64 bal = __ballot(obs != 0);
        if (d == 0) s_xmask[qq] = bal;
    }
    __syncthreads();

    const int lane = tid & 63;
    const int qcol = lane & 15;
    const int krow = (lane >> 4) & 3;
    bf16x8 bXX0 = (bf16x8)(short)0, bXX1 = (bf16x8)(short)0;
    bf16x8 bOX0 = (bf16x8)(short)0, bOX1 = (bf16x8)(short)0;
    bf16x8 bM0  = (bf16x8)(short)0, bM1  = (bf16x8)(short)0;
    if (qcol < QB) {
        const float* xr = s_xv[qcol];
        u64 xm = s_xmask[qcol];
#pragma unroll
        for (int e = 0; e < 8; ++e) {
            {
                int j = krow * 8 + e;
                float x = xr[j];
                bXX0[e] = (short)bf16_rne(x * x);
                bOX0[e] = (short)(((xm >> j) & 1ull) ? 0x3F80 : 0);
                bM0[e]  = (short)bf16_rne(-2.f * x);
            }
            {
                int j = 32 + krow * 8 + e;
                float x = xr[j];
                bXX1[e] = (short)bf16_rne(x * x);
                bOX1[e] = (short)(((xm >> j) & 1ull) ? 0x3F80 : 0);
                bM1[e]  = (short)bf16_rne(-2.f * x);
            }
        }
    }

    {
        const int wv = tid >> 6;
        int t = wv * 128;
        uint4 c0, c1, c2, c3, c4, c5;
        uint4 n0 = {}, n1 = {}, n2 = {}, n3 = {}, n4 = {}, n5 = {};
        LOADT(t, c0, c1, c2, c3, c4, c5);
#pragma unroll 1
        for (int tt = 0; tt < 128; ++tt) {
            bool hasn = (tt + 1 < 128);
            if (hasn) LOADT(t + 1, n0, n1, n2, n3, n4, n5);
            f32x4 accS = {0.f, 0.f, 0.f, 0.f};
            f32x4 accP = {0.f, 0.f, 0.f, 0.f};
            accS = MF(c0, bXX0, accS);
            accS = MF(c1, bXX1, accS);
            accS = MF(c2, bOX0, accS);
            accS = MF(c3, bOX1, accS);
            accS = MF(c4, bM0,  accS);
            accS = MF(c5, bM1,  accS);
            accP = MF(c0, bOX0, accP);
            accP = MF(c1, bOX1, accP);
            if (qcol < QB) {
#define MKKEY(r) ((accP[r] > 0.5f)                                            \
                    ? __float_as_uint(__fdividef(fmaxf(accS[r], 0.f), accP[r]))\
                    : FLTMAX_BITS)
                u32 b0 = MKKEY(0), b1 = MKKEY(1), b2 = MKKEY(2), b3 = MKKEY(3);
#undef MKKEY
                u32 lo = (b0 >> 16) | (b1 & 0xFFFF0000u);
                u32 hi = (b2 >> 16) | (b3 & 0xFFFF0000u);
                u32 off = (u32)qcol * PADW + (u32)t * 16 + (u32)krow * 4;
                *(uint2*)(&s_k16[off]) = make_uint2(lo, hi);
            }
            if (hasn) { c0 = n0; c1 = n1; c2 = n2; c3 = n3; c4 = n4; c5 = n5; }
            ++t;
        }
    }
    __syncthreads();

    int K = *pk;
    if (K < 1 || K > 64) {
        float kf = __int_as_float(K);
        K = (kf >= 1.f && kf <= 64.f) ? (int)kf : 5;
    }
    if (K > TCAP) K = TCAP;

    const int wv = tid >> 6;
#pragma unroll 1
    for (int rr = 0; rr < 2; ++rr) {
        const int qq = wv + rr * 4;
        const int q = q0 + qq;
        u16* kq = s_k16 + (size_t)qq * PADW;
        const u32* kq32 = (const u32*)kq;
        const u64 xm = s_xmask[qq];
        const u32 xmlo = (u32)xm, xmhi = (u32)(xm >> 32);

        u32 blo = 0, bhi = 65535;
#pragma unroll 1
        while (blo < bhi) {
            u32 mid = (blo + bhi) >> 1;
            int c = 0;
#pragma unroll 8
            for (int i = 0; i < 64; ++i) {
                u32 w2 = kq32[lane + (i << 6)];
                c += ((w2 & 0xFFFFu) <= mid) + ((w2 >> 16) <= mid);
            }
#pragma unroll
            for (int o = 32; o; o >>= 1) c += __shfl_xor(c, o, 64);
            if ((u32)c >= (u32)RANK) bhi = mid; else blo = mid + 1;
        }
        const u32 thr16 = blo;

        if (lane == 0) s_cnt[wv] = 0;
        int nb = 0, nt2 = 0;
#pragma unroll 8
        for (int i = 0; i < 64; ++i) {
            u32 w2 = kq32[lane + (i << 6)];
            u32 k0 = w2 & 0xFFFFu, k1 = w2 >> 16;
            nb  += (k0 < thr16)  + (k1 < thr16);
            nt2 += (k0 == thr16) + (k1 == thr16);
        }
        int tb = nb, tt2 = nt2;
#pragma unroll
        for (int o = 32; o; o >>= 1) {
            tb  += __shfl_xor(tb, o, 64);
            tt2 += __shfl_xor(tt2, o, 64);
        }
        const int nTot = tb + tt2;
        if (nTot <= TCAP) {
#pragma unroll 4
            for (int i = 0; i < 64; ++i) {
                u32 w2 = kq32[lane + (i << 6)];
                u32 k0 = w2 & 0xFFFFu, k1 = w2 >> 16;
                int f0 = (lane + (i << 6)) * 2;
                if (k0 <= thr16) { u32 p = atomicAdd(&s_cnt[wv], 1u); s_ci[wv][p] = (u32)f0; }
                if (k1 <= thr16) { u32 p = atomicAdd(&s_cnt[wv], 1u); s_ci[wv][p] = (u32)(f0 + 1); }
            }
            if (lane >= nTot) s_ci[wv][lane] = IDX_INVALID;
        } else {
            if (lane == 0) {
                int n = 0;
                for (int f = 0; f < NF; ++f)
                    if ((u32)kq[f] < thr16) s_ci[wv][n++] = (u32)f;
                for (int f = 0; f < NF && n < TCAP; ++f)
                    if ((u32)kq[f] == thr16) s_ci[wv][n++] = (u32)f;
                for (; n < TCAP; ++n) s_ci[wv][n] = IDX_INVALID;
            }
        }

        float* cv = (float*)kq;
        u32 myci = s_ci[wv][lane];
#pragma unroll 8
        for (int r = 0; r < TCAP; ++r) {
            u32 ci = __shfl((int)myci, r, 64);
            float v = (ci != IDX_INVALID) ? fit[(size_t)ci * D + lane]
                                          : __uint_as_float(NANF_BITS);
            cv[(r << 6) + (lane ^ (r & 31))] = v;
        }

        {
            double ss = 0.0; int pr2 = 0;
#pragma unroll 8
            for (int j = 0; j < D; ++j) {
                float yf = cv[(lane << 6) + (j ^ (lane & 31))];
                int vmiss = f32_missing_bits(__float_as_uint(yf));
                u32 xbit = (j < 32) ? ((xmlo >> j) & 1u) : ((xmhi >> (j - 32)) & 1u);
                int ok = (int)xbit & (vmiss ^ 1);
                double dd = ok ? ((double)s_xv[qq][j] - (double)yf) : 0.0;
                ss = fma(dd, dd, ss);
                pr2 += ok;
            }
            double kd = (myci != IDX_INVALID && pr2 > 0) ? (ss / (double)pr2)
                                                         : 1.0e300;
            s_kd[wv][lane] = kd;
        }

        {
            const int d = lane;
            u32 xobs = (d < 32) ? ((xmlo >> d) & 1u) : ((xmhi >> (d - 32)) & 1u);
            float res;
            if (xobs) {
                res = s_xv[qq][d];
            } else {
                u64 used = 0; float sum = 0.f; int cnt = 0;
                for (int s = 0; s < K; ++s) {
                    int best = -1; double bk = 0.0; u32 bi = 0;
                    for (int r = 0; r < TCAP; ++r) {
                        if ((used >> r) & 1ull) continue;
                        u32 ci = s_ci[wv][r];
                        if (ci == IDX_INVALID) continue;
                        float v = cv[(r << 6) + (d ^ (r & 31))];
                        if (f32_missing_bits(__float_as_uint(v))) continue;
                        double kd = s_kd[wv][r];
                        if (kd >= 1.0e300) continue;
                        if (best < 0 || kd < bk || (kd == bk && ci < bi)) {
                            best = r; bk = kd; bi = ci;
                        }
                    }
                    if (best < 0) break;
                    used |= 1ull << best;
                    sum += cv[(best << 6) + (d ^ (best & 31))];
                    cnt++;
                }
                if (cnt > 0) {
                    res = sum / (float)cnt;
                } else {
                    float cs = 0.f; int cc = 0;
                    for (int f = 0; f < NF; ++f) {
                        float yf = fit[(size_t)f * D + d];
                        if (!f32_missing_bits(__float_as_uint(yf))) { cs += yf; cc++; }
                    }
                    res = cc > 0 ? cs / (float)cc : 0.f;
                }
                u32 rb = __float_as_uint(res);
                if (((rb >> 23) & 0xFFu) == 0xFFu) res = 0.f;
            }
            out[(size_t)q * D + d] = res;
        }
    }
}

// ---- last fallback: proven R15 kernel ---------------------------------------
__global__ __launch_bounds__(256) void knn_fb(
        const float* __restrict__ X,
        const float* __restrict__ fit,
        const int* __restrict__ pk,
        float* __restrict__ out) {
    __shared__ __align__(16) unsigned char s_pool[16384];
    __shared__ u32   s_hist[256];
    __shared__ u32   s_blw[256];
    __shared__ u32   s_tie[256];
    __shared__ __align__(16) float s_xv[D];
    __shared__ u64   s_xmask;
    __shared__ u32   s_ci[TCAP];
    __shared__ double s_kd[TCAP];
    __shared__ u32   s_sel0, s_below0, s_sel1;

    u16*   s_k16 = (u16*)s_pool;
    float* s_cv  = (float*)s_pool;
    const int tid = threadIdx.x;
    const int q = blockIdx.x;

    if (tid < 64) {
        float xf = X[(size_t)q * D + tid];
        int obs = !f32_missing_bits(__float_as_uint(xf));
        s_xv[tid] = obs ? xf : 0.f;
        u64 bal = __ballot(obs != 0);
        if (tid == 0) s_xmask = bal;
    }
    __syncthreads();

    const u64 xm = s_xmask;
    const u32 xmlo = (u32)xm, xmhi = (u32)(xm >> 32);
    const float4* xv4 = (const float4*)s_xv;
    const float4* fitc = (const float4*)fit;

    for (int i = 0; i < 32; ++i) {
        int f = tid + (i << 8);
        const float4* rp = fitc + (size_t)f * 16;
        float ssd = 0.f; int pres = 0;
#pragma unroll
        for (int m = 0; m < 16; ++m) {
            float4 w = rp[m];
            float4 xc = xv4[m];
            u32 mb = (m < 8) ? (xmlo >> ((m & 7) * 4)) : (xmhi >> ((m & 7) * 4));
            float wv[4] = { w.x, w.y, w.z, w.w };
            float xw[4] = { xc.x, xc.y, xc.z, xc.w };
#pragma unroll
            for (int u = 0; u < 4; ++u) {
                int ok = (int)((mb >> u) & 1u)
                       & (f32_missing_bits(__float_as_uint(wv[u])) ^ 1);
                float t = ok ? wv[u] : xw[u];
                float dm = xw[u] - t;
                ssd = fmaf(dm, dm, ssd);
                pres += ok;
            }
        }
        float kk = (pres > 0) ? (ssd / (float)pres) : __uint_as_float(FLTMAX_BITS);
        s_k16[f] = (u16)(__float_as_uint(kk) >> 16);
    }
    __syncthreads();

    int K = *pk;
    if (K < 1 || K > 64) {
        float kf = __int_as_float(K);
        K = (kf >= 1.f && kf <= 64.f) ? (int)kf : 5;
    }
    if (K > TCAP) K = TCAP;

    s_hist[tid] = 0;
    __syncthreads();
    for (int i = 0; i < 32; ++i) {
        u32 k16 = (u32)s_k16[tid + (i << 8)];
        atomicAdd(&s_hist[k16 >> 8], 1u);
    }
    __syncthreads();
    if (tid == 0) {
        u32 run = 0, below = 0, sel = 255;
        for (int b = 0; b < 256; ++b) {
            u32 c = s_hist[b];
            if (run + c >= (u32)RANK) { sel = (u32)b; below = run; break; }
            run += c;
        }
        s_sel0 = sel; s_below0 = below;
    }
    __syncthreads();
    const u32 sel0 = s_sel0;
    const u32 need1 = (u32)RANK - s_below0;
    __syncthreads();
    s_hist[tid] = 0;
    __syncthreads();
    for (int i = 0; i < 32; ++i) {
        u32 k16 = (u32)s_k16[tid + (i << 8)];
        if ((k16 >> 8) == sel0) atomicAdd(&s_hist[k16 & 0xFFu], 1u);
    }
    __syncthreads();
    if (tid == 0) {
        u32 run = 0, sel = 255;
        for (int b = 0; b < 256; ++b) {
            u32 c = s_hist[b];
            if (run + c >= need1) { sel = (u32)b; break; }
            run += c;
        }
        s_sel1 = sel;
    }
    __syncthreads();
    const u32 thr16 = (sel0 << 8) | s_sel1;

    {
        u32 bb = 0, tb = 0;
        for (int i = 0; i < 32; ++i) {
            u32 k16 = (u32)s_k16[tid + (i << 8)];
            bb |= (k16 < thr16)  ? (1u << i) : 0u;
            tb |= (k16 == thr16) ? (1u << i) : 0u;
        }
        s_blw[tid] = bb; s_tie[tid] = tb;
    }
    __syncthreads();
    if (tid == 0) {
        int n = 0;
        for (int t = 0; t < 256 && n < TCAP; ++t) {
            u32 w = s_blw[t];
            while (w && n < TCAP) {
                int i = __ffs(w) - 1; w &= w - 1;
                s_ci[n++] = (u32)(i * 256 + t);
            }
        }
        u32 tf[TCAP]; int nt = 0;
        for (int t = 0; t < 256 && nt < TCAP; ++t) {
            u32 w = s_tie[t];
            while (w && nt < TCAP) {
                int i = __ffs(w) - 1; w &= w - 1;
                tf[nt++] = (u32)(i * 256 + t);
            }
        }
        int cap = TCAP - n;
        if (nt <= cap) {
            for (int r = 0; r < nt; ++r) s_ci[n++] = tf[r];
        } else {
            for (int j = 0; j < cap; ++j) {
                int bp = -1; u32 bi = IDX_INVALID;
                for (int r = 0; r < nt; ++r)
                    if (tf[r] < bi) { bi = tf[r]; bp = r; }
                tf[bp] = IDX_INVALID;
                s_ci[n++] = bi;
            }
        }
        for (; n < TCAP; ++n) s_ci[n] = IDX_INVALID;
    }
    __syncthreads();

#pragma unroll
    for (int t = 0; t < (TCAP * 64) / 256; ++t) {
        int idx = tid + t * 256;
        int r = idx >> 6, d2 = idx & 63;
        u32 ci = s_ci[r];
        s_cv[idx] = (ci != IDX_INVALID) ? fit[(size_t)ci * D + d2]
                                        : __uint_as_float(NANF_BITS);
    }

    if (tid < TCAP) {
        u32 ci = s_ci[tid];
        double kd = 1.0e300;
        if (ci != IDX_INVALID) {
            const float* row = fit + (size_t)ci * D;
            double ss = 0.0; int pr = 0;
            for (int j = 0; j < D; ++j) {
                float yf = row[j];
                int vmiss = f32_missing_bits(__float_as_uint(yf));
                u32 xbit = (j < 32) ? ((xmlo >> j) & 1u) : ((xmhi >> (j - 32)) & 1u);
                int ok = (int)xbit & (vmiss ^ 1);
                double dd = ok ? ((double)s_xv[j] - (double)yf) : 0.0;
                ss = fma(dd, dd, ss);
                pr += ok;
            }
            kd = (pr > 0) ? (ss / (double)pr) : 1.0e300;
        }
        s_kd[tid] = kd;
    }
    __syncthreads();

    if (tid < 64) {
        const int d = tid;
        u32 xobs = (d < 32) ? ((xmlo >> d) & 1u) : ((xmhi >> (d - 32)) & 1u);
        float res;
        if (xobs) {
            res = s_xv[d];
        } else {
            u64 used = 0; float sum = 0.f; int cnt = 0;
            for (int s = 0; s < K; ++s) {
                int best = -1; double bk = 0.0; u32 bi = 0;
                for (int r = 0; r < TCAP; ++r) {
                    if ((used >> r) & 1ull) continue;
                    u32 ci = s_ci[r];
                    if (ci == IDX_INVALID) continue;
                    float v = s_cv[r * 64 + d];
                    if (f32_missing_bits(__float_as_uint(v))) continue;
                    double kd = s_kd[r];
                    if (kd >= 1.0e300) continue;
                    if (best < 0 || kd < bk || (kd == bk && ci < bi)) {
                        best = r; bk = kd; bi = ci;
                    }
                }
                if (best < 0) break;
                used |= 1ull << best;
                sum += s_cv[best * 64 + d];
                cnt++;
            }
            if (cnt > 0) {
                res = sum / (float)cnt;
            } else {
                float cs = 0.f; int cc = 0;
                for (int f = 0; f < NF; ++f) {
                    float yf = fit[(size_t)f * D + d];
                    if (!f32_missing_bits(__float_as_uint(yf))) { cs += yf; cc++; }
                }
                res = cc > 0 ? cs / (float)cc : 0.f;
            }
            u32 rb = __float_as_uint(res);
            if (((rb >> 23) & 0xFFu) == 0xFFu) res = 0.f;
        }
        out[(size_t)q * D + d] = res;
    }
}

// ---- launch ------------------------------------------------------------------
extern "C" void kernel_launch(void* const* d_in, const int* in_sizes, int n_in,
                              void* d_out, int out_size, void* d_ws, size_t ws_size,
                              hipStream_t stream) {
    const void* pX = d_in[0];
    const void* pF = (n_in > 1) ? d_in[1] : d_in[0];
    const void* pK = (n_in > 2) ? d_in[2] : d_in[0];
    for (int i = 0; i < n_in; ++i) {
        if (in_sizes[i] == NQ * D)      pX = d_in[i];
        else if (in_sizes[i] == NF * D) pF = d_in[i];
        else if (in_sizes[i] == 1)      pK = d_in[i];
    }
    const float* X   = (const float*)pX;
    const float* fit = (const float*)pF;
    const int*   pk  = (const int*)pK;
    float* out = (float*)d_out;

    const size_t perQ = (size_t)NF * sizeof(u16);          // 16 KB per query
    if (ws_size >= FRAG_BYTES + 2048 * perQ) {
        // two-kernel path, chunked to fit workspace
        uint4* frags = (uint4*)d_ws;
        u16*   keys  = (u16*)((char*)d_ws + FRAG_BYTES);
        size_t avail = ws_size - FRAG_BYTES;
        int chunkQ = (int)(avail / perQ);
        if (chunkQ > NQ) chunkQ = NQ;
        chunkQ &= ~15;                                      // multiple of QA
        prep_frags<<<(NTILES * 384) / 256, 256, 0, stream>>>(fit, frags);
        for (int cq0 = 0; cq0 < NQ; cq0 += chunkQ) {
            int cur = NQ - cq0 < chunkQ ? NQ - cq0 : chunkQ;
            knn_keys<<<cur / QA, 256, 0, stream>>>(X, frags, keys, pk, cq0);
            knn_sel<<<cur, 64, 0, stream>>>(X, fit, keys, pk, out, cq0);
        }
    } else if (ws_size >= FRAG_BYTES) {
        uint4* frags = (uint4*)d_ws;
        prep_frags<<<(NTILES * 384) / 256, 256, 0, stream>>>(fit, frags);
        knn_mfma<<<NQ / QB, 256, 0, stream>>>(X, fit, frags, pk, out);
    } else {
        knn_fb<<<NQ, 256, 0, stream>>>(X, fit, pk, out);
    }
}

// Round 7
// 639.324 us; speedup vs baseline: 55.6964x; 1.7459x over previous
//
#include <hip/hip_runtime.h>

// R21: register-keys + rank-sort selection + QA=32 keys kernel.
// R20 (1116us): knn_sel 650us (occ 24.5%, VALU 32%) + knn_keys ~460us.
// knn_sel fixes: (1) keys live in 16 statically-indexed uint4 regs/lane --
//   binary search & collection count from regs (kills ~770 LDS reads/query,
//   drops s_keys 16KB -> 9 blocks/CU); (2) after fp64 re-key, rank candidates
//   by #smaller (kd,ci,lane) via 64-shfl loop -> s_ord; top-K walks sorted
//   order taking first K column-valid donors (exchange argument: identical
//   picks as iterative min; kd->ci tie matches; invalids sort last) --
//   ~320 divergent iters -> ~8. knn_keys: QA=32 via two MFMA column-sets per
//   A-frag load -> frag L2 traffic 3GB -> 1.5GB, 2x MFMA density.
// Selection semantics (thr16 = exact 32nd-smallest u16 key; candidates =
// below + ties capped at 64 with smallest-idx preference; exact fp64 re-key;
// exact top-K) unchanged from proven R19/R20 => identical output.
// Fallbacks: ws>=3MB+32MB two-kernel chunked; >=3MB R19 kernel; else R15.

#define NQ 16384
#define NF 8192
#define D  64
#define TCAP 64
#define RANK 32
#define QB 8            // R19 fallback kernel
#define QA 32           // kernel-A queries per block (two 16-col MFMA sets)
#define PADW 8208
#define NTILES 512      // NF/16
#define FRAG_BYTES ((size_t)NTILES * 384 * 16)   // 3 MB

typedef unsigned short u16;
typedef unsigned int u32;
typedef unsigned long long u64;
typedef __attribute__((ext_vector_type(8))) short bf16x8;
typedef __attribute__((ext_vector_type(4))) float f32x4;

#define IDX_INVALID 0xFFFFFFFFu
#define NANF_BITS   0x7FC00000u
#define FLTMAX_BITS 0x7F7FFFFFu

__device__ __forceinline__ int f32_missing_bits(u32 b) {
    return ((b >> 23) & 0xFFu) == 0xFFu;      // NaN/inf => missing
}
__device__ __forceinline__ u16 bf16_rne(float f) {
    u32 b = __float_as_uint(f);
    return (u16)((b + 0x7FFFu + ((b >> 16) & 1u)) >> 16);
}

// ---- prep: donor-side MFMA A-fragments into ws (unchanged, proven) ----------
__global__ __launch_bounds__(256) void prep_frags(const float* __restrict__ fit,
                                                  uint4* __restrict__ frags) {
    int idx  = blockIdx.x * 256 + threadIdx.x;    // 0 .. NTILES*384-1
    int lane = idx & 63;
    int kk   = (idx >> 6) & 1;
    int sel  = (idx >> 7) % 3;
    int t    = (idx >> 7) / 3;
    int donor = t * 16 + (lane & 15);
    int j0 = kk * 32 + ((lane >> 4) & 3) * 8;
    const float* row = fit + (size_t)donor * D + j0;
    u32 w[4];
#pragma unroll
    for (int p = 0; p < 4; ++p) {
        u16 h0, h1;
        {
            float v = row[p * 2];
            int miss = f32_missing_bits(__float_as_uint(v));
            float vc = miss ? 0.f : v;
            float val = (sel == 0) ? (miss ? 0.f : 1.f) : (sel == 1) ? vc * vc : vc;
            h0 = bf16_rne(val);
        }
        {
            float v = row[p * 2 + 1];
            int miss = f32_missing_bits(__float_as_uint(v));
            float vc = miss ? 0.f : v;
            float val = (sel == 0) ? (miss ? 0.f : 1.f) : (sel == 1) ? vc * vc : vc;
            h1 = bf16_rne(val);
        }
        w[p] = (u32)h0 | ((u32)h1 << 16);
    }
    frags[idx] = make_uint4(w[0], w[1], w[2], w[3]);
}

#define MF(A, B, C) __builtin_amdgcn_mfma_f32_16x16x32_bf16(                  \
        __builtin_bit_cast(bf16x8, (A)), (B), (C), 0, 0, 0)

#define LOADT(T, A0, A1, A2, A3, A4, A5) {                                    \
        size_t bo = (size_t)(T) * 384 + lane;                                 \
        A0 = frags[bo];       A1 = frags[bo + 64];                            \
        A2 = frags[bo + 128]; A3 = frags[bo + 192];                           \
        A4 = frags[bo + 256]; A5 = frags[bo + 320]; }

// ---- kernel A: QA=32 MFMA keys (two column sets) -> global workspace --------
__global__ __launch_bounds__(256) void knn_keys(
        const float* __restrict__ X,
        const uint4* __restrict__ frags,
        u16* __restrict__ keys,                   // [chunkQ][NF]
        int cq0) {
    __shared__ __align__(16) float s_xv[QA][D];   // 8 KB
    __shared__ u64 s_xmask[QA];

    const int tid = threadIdx.x;
    const int qb0 = blockIdx.x * QA;              // local query base

#pragma unroll
    for (int rr = 0; rr < 8; ++rr) {
        int qq = rr * 4 + (tid >> 6);
        int d  = tid & 63;
        float xf = X[(size_t)(cq0 + qb0 + qq) * D + d];
        int obs = !f32_missing_bits(__float_as_uint(xf));
        s_xv[qq][d] = obs ? xf : 0.f;
        u64 bal = __ballot(obs != 0);
        if (d == 0) s_xmask[qq] = bal;
    }
    __syncthreads();

    const int lane = tid & 63;
    const int qcol = lane & 15;
    const int krow = (lane >> 4) & 3;
    bf16x8 aXX0, aXX1, aOX0, aOX1, aM0, aM1;      // column set A: queries qb0+qcol
    bf16x8 bXX0, bXX1, bOX0, bOX1, bM0, bM1;      // column set B: queries qb0+16+qcol
#define BUILD_B(QIDX, XX0, XX1, OX0, OX1, M0, M1) {                           \
        const float* xr_ = s_xv[QIDX];                                        \
        u64 xm_ = s_xmask[QIDX];                                              \
        _Pragma("unroll")                                                     \
        for (int e = 0; e < 8; ++e) {                                         \
            int j0_ = krow * 8 + e;                                           \
            float x0_ = xr_[j0_];                                             \
            XX0[e] = (short)bf16_rne(x0_ * x0_);                              \
            OX0[e] = (short)(((xm_ >> j0_) & 1ull) ? 0x3F80 : 0);             \
            M0[e]  = (short)bf16_rne(-2.f * x0_);                             \
            int j1_ = 32 + krow * 8 + e;                                      \
            float x1_ = xr_[j1_];                                             \
            XX1[e] = (short)bf16_rne(x1_ * x1_);                              \
            OX1[e] = (short)(((xm_ >> j1_) & 1ull) ? 0x3F80 : 0);             \
            M1[e]  = (short)bf16_rne(-2.f * x1_);                             \
        } }
    BUILD_B(qcol,      aXX0, aXX1, aOX0, aOX1, aM0, aM1)
    BUILD_B(16 + qcol, bXX0, bXX1, bOX0, bOX1, bM0, bM1)
#undef BUILD_B

    const int wv = tid >> 6;
    int t = wv * 128;
    uint4 c0, c1, c2, c3, c4, c5;
    uint4 n0 = {}, n1 = {}, n2 = {}, n3 = {}, n4 = {}, n5 = {};
    LOADT(t, c0, c1, c2, c3, c4, c5);
#pragma unroll 1
    for (int tt = 0; tt < 128; ++tt) {
        bool hasn = (tt + 1 < 128);
        if (hasn) LOADT(t + 1, n0, n1, n2, n3, n4, n5);
        f32x4 sA = {0.f,0.f,0.f,0.f}, pA = {0.f,0.f,0.f,0.f};
        f32x4 sB = {0.f,0.f,0.f,0.f}, pB = {0.f,0.f,0.f,0.f};
        sA = MF(c0, aXX0, sA); sA = MF(c1, aXX1, sA);
        sA = MF(c2, aOX0, sA); sA = MF(c3, aOX1, sA);
        sA = MF(c4, aM0,  sA); sA = MF(c5, aM1,  sA);
        pA = MF(c0, aOX0, pA); pA = MF(c1, aOX1, pA);
        sB = MF(c0, bXX0, sB); sB = MF(c1, bXX1, sB);
        sB = MF(c2, bOX0, sB); sB = MF(c3, bOX1, sB);
        sB = MF(c4, bM0,  sB); sB = MF(c5, bM1,  sB);
        pB = MF(c0, bOX0, pB); pB = MF(c1, bOX1, pB);
#define MKKEY(P, S, r) (((P)[r] > 0.5f)                                       \
            ? __float_as_uint(__fdividef(fmaxf((S)[r], 0.f), (P)[r]))         \
            : FLTMAX_BITS)
        {
            u32 b0 = MKKEY(pA, sA, 0), b1 = MKKEY(pA, sA, 1);
            u32 b2 = MKKEY(pA, sA, 2), b3 = MKKEY(pA, sA, 3);
            size_t off = (size_t)(qb0 + qcol) * NF + (size_t)t * 16 + krow * 4;
            *(uint2*)(keys + off) = make_uint2((b0 >> 16) | (b1 & 0xFFFF0000u),
                                               (b2 >> 16) | (b3 & 0xFFFF0000u));
        }
        {
            u32 b0 = MKKEY(pB, sB, 0), b1 = MKKEY(pB, sB, 1);
            u32 b2 = MKKEY(pB, sB, 2), b3 = MKKEY(pB, sB, 3);
            size_t off = (size_t)(qb0 + 16 + qcol) * NF + (size_t)t * 16 + krow * 4;
            *(uint2*)(keys + off) = make_uint2((b0 >> 16) | (b1 & 0xFFFF0000u),
                                               (b2 >> 16) | (b3 & 0xFFFF0000u));
        }
#undef MKKEY
        if (hasn) { c0 = n0; c1 = n1; c2 = n2; c3 = n3; c4 = n4; c5 = n5; }
        ++t;
    }
}

// ---- kernel B: one wave/query; keys in regs; rank-sorted exact top-K --------
__global__ __launch_bounds__(64) void knn_sel(
        const float* __restrict__ X,
        const float* __restrict__ fit,
        const u16* __restrict__ keys,             // [chunkQ][NF]
        const int* __restrict__ pk,
        float* __restrict__ out,
        int cq0) {
    __shared__ __align__(16) float s_cv[TCAP * 64];   // 16 KB
    __shared__ __align__(16) float s_xv[D];
    __shared__ u32    s_ci[TCAP];
    __shared__ double s_kd[TCAP];
    __shared__ u32    s_ord[TCAP];
    __shared__ u32    s_cnt;

    const int lane = threadIdx.x;
    const int ql = blockIdx.x;
    const int q  = cq0 + ql;

    float xf = X[(size_t)q * D + lane];
    int obs = !f32_missing_bits(__float_as_uint(xf));
    s_xv[lane] = obs ? xf : 0.f;
    const u64 xm = __ballot(obs != 0);
    const u32 xmlo = (u32)xm, xmhi = (u32)(xm >> 32);

    // ---- keys -> 16 statically-indexed uint4 regs; track per-lane min ----
    uint4 kr[16];
    u32 mymin = 0xFFFFu;
    {
        const uint4* kg = (const uint4*)(keys + (size_t)ql * NF);
#pragma unroll
        for (int i = 0; i < 16; ++i) {
            kr[i] = kg[lane + (i << 6)];
#define MIN16S(W) { u32 a_ = (W) & 0xFFFFu, b_ = (W) >> 16;                   \
                    mymin = a_ < mymin ? a_ : mymin;                          \
                    mymin = b_ < mymin ? b_ : mymin; }
            MIN16S(kr[i].x) MIN16S(kr[i].y) MIN16S(kr[i].z) MIN16S(kr[i].w)
#undef MIN16S
        }
    }
    u32 lo0 = mymin, hi0 = mymin;      // bracket: [min, max-of-lane-mins]
#pragma unroll
    for (int o = 32; o; o >>= 1) {
        u32 a = (u32)__shfl_xor((int)lo0, o, 64); lo0 = a < lo0 ? a : lo0;
        u32 b = (u32)__shfl_xor((int)hi0, o, 64); hi0 = b > hi0 ? b : hi0;
    }

    int K = *pk;
    if (K < 1 || K > 64) {             // robustness if scalar arrived as float
        float kf = __int_as_float(K);
        K = (kf >= 1.f && kf <= 64.f) ? (int)kf : 5;
    }
    if (K > TCAP) K = TCAP;

    // -- 2a: 32nd-smallest u16 key via bracketed binary search (from regs) --
    u32 blo = lo0, bhi = hi0;
#pragma unroll 1
    while (blo < bhi) {
        u32 mid = (blo + bhi) >> 1;
        int c = 0;
#pragma unroll
        for (int i = 0; i < 16; ++i) {
#define CNTLE(W) { c += (((W) & 0xFFFFu) <= mid) + (((W) >> 16) <= mid); }
            CNTLE(kr[i].x) CNTLE(kr[i].y) CNTLE(kr[i].z) CNTLE(kr[i].w)
#undef CNTLE
        }
#pragma unroll
        for (int o = 32; o; o >>= 1) c += __shfl_xor(c, o, 64);
        if ((u32)c >= (u32)RANK) bhi = mid; else blo = mid + 1;
    }
    const u32 thr16 = blo;

    // -- 2a': collection from regs (set is order-independent) --
    if (lane == 0) s_cnt = 0;
    int nb = 0, nt2 = 0;
#pragma unroll
    for (int i = 0; i < 16; ++i) {
#define CNT2(W) { u32 k0_ = (W) & 0xFFFFu, k1_ = (W) >> 16;                   \
                  nb  += (k0_ < thr16)  + (k1_ < thr16);                      \
                  nt2 += (k0_ == thr16) + (k1_ == thr16); }
        CNT2(kr[i].x) CNT2(kr[i].y) CNT2(kr[i].z) CNT2(kr[i].w)
#undef CNT2
    }
    int tb = nb, tt2 = nt2;
#pragma unroll
    for (int o = 32; o; o >>= 1) {
        tb  += __shfl_xor(tb, o, 64);
        tt2 += __shfl_xor(tt2, o, 64);
    }
    const int nTot = tb + tt2;         // >= RANK
    if (nTot <= TCAP) {
#pragma unroll
        for (int i = 0; i < 16; ++i) {
            int f8 = (lane + (i << 6)) * 8;
#define APP(W, FB) { u32 k0_ = (W) & 0xFFFFu, k1_ = (W) >> 16;                \
        if (k0_ <= thr16) { u32 p_ = atomicAdd(&s_cnt, 1u); s_ci[p_] = (u32)(FB); } \
        if (k1_ <= thr16) { u32 p_ = atomicAdd(&s_cnt, 1u); s_ci[p_] = (u32)((FB) + 1); } }
            APP(kr[i].x, f8 + 0) APP(kr[i].y, f8 + 2)
            APP(kr[i].z, f8 + 4) APP(kr[i].w, f8 + 6)
#undef APP
        }
        if (lane >= nTot) s_ci[lane] = IDX_INVALID;
    } else {
        // rare overflow: all below, then ties ascending (smallest donor idx)
        if (lane == 0) {
            const u16* krow = keys + (size_t)ql * NF;
            int n = 0;
            for (int f = 0; f < NF; ++f)
                if ((u32)krow[f] < thr16) s_ci[n++] = (u32)f;
            for (int f = 0; f < NF && n < TCAP; ++f)
                if ((u32)krow[f] == thr16) s_ci[n++] = (u32)f;
            for (; n < TCAP; ++n) s_ci[n] = IDX_INVALID;
        }
    }

    // -- 2c: stage candidates, XOR-swizzled (conflict-free both axes) --
    u32 myci = s_ci[lane];
#pragma unroll 8
    for (int r = 0; r < TCAP; ++r) {
        u32 ci = __shfl((int)myci, r, 64);
        float v = (ci != IDX_INVALID) ? fit[(size_t)ci * D + lane]
                                      : __uint_as_float(NANF_BITS);
        s_cv[(r << 6) + (lane ^ (r & 31))] = v;
    }

    // -- 2b: exact fp64 re-key from staged values --
    double mykd;
    {
        double ss = 0.0; int pr2 = 0;
#pragma unroll 8
        for (int j = 0; j < D; ++j) {
            float yf = s_cv[(lane << 6) + (j ^ (lane & 31))];
            int vmiss = f32_missing_bits(__float_as_uint(yf));
            u32 xbit = (j < 32) ? ((xmlo >> j) & 1u) : ((xmhi >> (j - 32)) & 1u);
            int ok = (int)xbit & (vmiss ^ 1);
            double dd = ok ? ((double)s_xv[j] - (double)yf) : 0.0;
            ss = fma(dd, dd, ss);
            pr2 += ok;
        }
        mykd = (myci != IDX_INVALID && pr2 > 0) ? (ss / (double)pr2) : 1.0e300;
        s_kd[lane] = mykd;
    }

    // -- rank candidates by (kd, ci, lane); s_ord = sorted order --
    {
        int rank = 0;
#pragma unroll 1
        for (int j = 0; j < 64; ++j) {
            double kdj = __shfl(mykd, j, 64);
            u32 cij = (u32)__shfl((int)myci, j, 64);
            int less = (kdj < mykd) |
                       ((kdj == mykd) & ((cij < myci) |
                                         ((cij == myci) & (j < lane))));
            rank += less;
        }
        s_ord[rank] = (u32)lane;
    }

    // -- 2d: walk sorted candidates, first K column-valid (exact top-K) --
    {
        const int d = lane;
        u32 xobs = (d < 32) ? ((xmlo >> d) & 1u) : ((xmhi >> (d - 32)) & 1u);
        float res;
        if (xobs) {
            res = s_xv[d];
        } else {
            float sum = 0.f; int cnt = 0;
#pragma unroll 1
            for (int s2 = 0; s2 < TCAP; ++s2) {
                u32 r = s_ord[s2];
                u32 ci = s_ci[r];
                if (ci == IDX_INVALID) break;        // invalids sort last
                if (s_kd[r] >= 1.0e300) break;       // ascending => all done
                float v = s_cv[(r << 6) + (d ^ (r & 31))];
                if (f32_missing_bits(__float_as_uint(v))) continue;
                sum += v;
                if (++cnt == K) break;
            }
            if (cnt > 0) {
                res = sum / (float)cnt;
            } else {
                float cs = 0.f; int cc = 0;          // essentially-never fallback
                for (int f = 0; f < NF; ++f) {
                    float yf = fit[(size_t)f * D + d];
                    if (!f32_missing_bits(__float_as_uint(yf))) { cs += yf; cc++; }
                }
                res = cc > 0 ? cs / (float)cc : 0.f;
            }
            u32 rb = __float_as_uint(res);
            if (((rb >> 23) & 0xFFu) == 0xFFu) res = 0.f;   // integer guard
        }
        out[(size_t)q * D + d] = res;
    }
}

// ---- mid fallback: proven R19 single-kernel (verbatim) ----------------------
__global__ __launch_bounds__(256) void knn_mfma(
        const float* __restrict__ X,
        const float* __restrict__ fit,
        const uint4* __restrict__ frags,
        const int* __restrict__ pk,
        float* __restrict__ out) {
    __shared__ __align__(16) u16 s_k16[QB * PADW];
    __shared__ __align__(16) float s_xv[QB][D];
    __shared__ u64    s_xmask[QB];
    __shared__ u32    s_ci[4][TCAP];
    __shared__ double s_kd[4][TCAP];
    __shared__ u32    s_cnt[4];

    const int tid = threadIdx.x;
    const int q0 = blockIdx.x * QB;

#pragma unroll
    for (int rr = 0; rr < 2; ++rr) {
        int qq = rr * 4 + (tid >> 6);
        int d  = tid & 63;
        float xf = X[(size_t)(q0 + qq) * D + d];
        int obs = !f32_missing_bits(__float_as_uint(xf));
        s_xv[qq][d] = obs ? xf : 0.f;
        u64 bal = __ballot(obs != 0);
        if (d == 0) s_xmask[qq] = bal;
    }
    __syncthreads();

    const int lane = tid & 63;
    const int qcol = lane & 15;
    const int krow = (lane >> 4) & 3;
    bf16x8 bXX0 = (bf16x8)(short)0, bXX1 = (bf16x8)(short)0;
    bf16x8 bOX0 = (bf16x8)(short)0, bOX1 = (bf16x8)(short)0;
    bf16x8 bM0  = (bf16x8)(short)0, bM1  = (bf16x8)(short)0;
    if (qcol < QB) {
        const float* xr = s_xv[qcol];
        u64 xm = s_xmask[qcol];
#pragma unroll
        for (int e = 0; e < 8; ++e) {
            {
                int j = krow * 8 + e;
                float x = xr[j];
                bXX0[e] = (short)bf16_rne(x * x);
                bOX0[e] = (short)(((xm >> j) & 1ull) ? 0x3F80 : 0);
                bM0[e]  = (short)bf16_rne(-2.f * x);
            }
            {
                int j = 32 + krow * 8 + e;
                float x = xr[j];
                bXX1[e] = (short)bf16_rne(x * x);
                bOX1[e] = (short)(((xm >> j) & 1ull) ? 0x3F80 : 0);
                bM1[e]  = (short)bf16_rne(-2.f * x);
            }
        }
    }

    {
        const int wv = tid >> 6;
        int t = wv * 128;
        uint4 c0, c1, c2, c3, c4, c5;
        uint4 n0 = {}, n1 = {}, n2 = {}, n3 = {}, n4 = {}, n5 = {};
        LOADT(t, c0, c1, c2, c3, c4, c5);
#pragma unroll 1
        for (int tt = 0; tt < 128; ++tt) {
            bool hasn = (tt + 1 < 128);
            if (hasn) LOADT(t + 1, n0, n1, n2, n3, n4, n5);
            f32x4 accS = {0.f, 0.f, 0.f, 0.f};
            f32x4 accP = {0.f, 0.f, 0.f, 0.f};
            accS = MF(c0, bXX0, accS);
            accS = MF(c1, bXX1, accS);
            accS = MF(c2, bOX0, accS);
            accS = MF(c3, bOX1, accS);
            accS = MF(c4, bM0,  accS);
            accS = MF(c5, bM1,  accS);
            accP = MF(c0, bOX0, accP);
            accP = MF(c1, bOX1, accP);
            if (qcol < QB) {
#define MKKEY(r) ((accP[r] > 0.5f)                                            \
                    ? __float_as_uint(__fdividef(fmaxf(accS[r], 0.f), accP[r]))\
                    : FLTMAX_BITS)
                u32 b0 = MKKEY(0), b1 = MKKEY(1), b2 = MKKEY(2), b3 = MKKEY(3);
#undef MKKEY
                u32 lo = (b0 >> 16) | (b1 & 0xFFFF0000u);
                u32 hi = (b2 >> 16) | (b3 & 0xFFFF0000u);
                u32 off = (u32)qcol * PADW + (u32)t * 16 + (u32)krow * 4;
                *(uint2*)(&s_k16[off]) = make_uint2(lo, hi);
            }
            if (hasn) { c0 = n0; c1 = n1; c2 = n2; c3 = n3; c4 = n4; c5 = n5; }
            ++t;
        }
    }
    __syncthreads();

    int K = *pk;
    if (K < 1 || K > 64) {
        float kf = __int_as_float(K);
        K = (kf >= 1.f && kf <= 64.f) ? (int)kf : 5;
    }
    if (K > TCAP) K = TCAP;

    const int wv = tid >> 6;
#pragma unroll 1
    for (int rr = 0; rr < 2; ++rr) {
        const int qq = wv + rr * 4;
        const int q = q0 + qq;
        u16* kq = s_k16 + (size_t)qq * PADW;
        const u32* kq32 = (const u32*)kq;
        const u64 xm = s_xmask[qq];
        const u32 xmlo = (u32)xm, xmhi = (u32)(xm >> 32);

        u32 blo = 0, bhi = 65535;
#pragma unroll 1
        while (blo < bhi) {
            u32 mid = (blo + bhi) >> 1;
            int c = 0;
#pragma unroll 8
            for (int i = 0; i < 64; ++i) {
                u32 w2 = kq32[lane + (i << 6)];
                c += ((w2 & 0xFFFFu) <= mid) + ((w2 >> 16) <= mid);
            }
#pragma unroll
            for (int o = 32; o; o >>= 1) c += __shfl_xor(c, o, 64);
            if ((u32)c >= (u32)RANK) bhi = mid; else blo = mid + 1;
        }
        const u32 thr16 = blo;

        if (lane == 0) s_cnt[wv] = 0;
        int nb = 0, nt2 = 0;
#pragma unroll 8
        for (int i = 0; i < 64; ++i) {
            u32 w2 = kq32[lane + (i << 6)];
            u32 k0 = w2 & 0xFFFFu, k1 = w2 >> 16;
            nb  += (k0 < thr16)  + (k1 < thr16);
            nt2 += (k0 == thr16) + (k1 == thr16);
        }
        int tb = nb, tt2 = nt2;
#pragma unroll
        for (int o = 32; o; o >>= 1) {
            tb  += __shfl_xor(tb, o, 64);
            tt2 += __shfl_xor(tt2, o, 64);
        }
        const int nTot = tb + tt2;
        if (nTot <= TCAP) {
#pragma unroll 4
            for (int i = 0; i < 64; ++i) {
                u32 w2 = kq32[lane + (i << 6)];
                u32 k0 = w2 & 0xFFFFu, k1 = w2 >> 16;
                int f0 = (lane + (i << 6)) * 2;
                if (k0 <= thr16) { u32 p = atomicAdd(&s_cnt[wv], 1u); s_ci[wv][p] = (u32)f0; }
                if (k1 <= thr16) { u32 p = atomicAdd(&s_cnt[wv], 1u); s_ci[wv][p] = (u32)(f0 + 1); }
            }
            if (lane >= nTot) s_ci[wv][lane] = IDX_INVALID;
        } else {
            if (lane == 0) {
                int n = 0;
                for (int f = 0; f < NF; ++f)
                    if ((u32)kq[f] < thr16) s_ci[wv][n++] = (u32)f;
                for (int f = 0; f < NF && n < TCAP; ++f)
                    if ((u32)kq[f] == thr16) s_ci[wv][n++] = (u32)f;
                for (; n < TCAP; ++n) s_ci[wv][n] = IDX_INVALID;
            }
        }

        float* cv = (float*)kq;
        u32 myci = s_ci[wv][lane];
#pragma unroll 8
        for (int r = 0; r < TCAP; ++r) {
            u32 ci = __shfl((int)myci, r, 64);
            float v = (ci != IDX_INVALID) ? fit[(size_t)ci * D + lane]
                                          : __uint_as_float(NANF_BITS);
            cv[(r << 6) + (lane ^ (r & 31))] = v;
        }

        {
            double ss = 0.0; int pr2 = 0;
#pragma unroll 8
            for (int j = 0; j < D; ++j) {
                float yf = cv[(lane << 6) + (j ^ (lane & 31))];
                int vmiss = f32_missing_bits(__float_as_uint(yf));
                u32 xbit = (j < 32) ? ((xmlo >> j) & 1u) : ((xmhi >> (j - 32)) & 1u);
                int ok = (int)xbit & (vmiss ^ 1);
                double dd = ok ? ((double)s_xv[qq][j] - (double)yf) : 0.0;
                ss = fma(dd, dd, ss);
                pr2 += ok;
            }
            double kd = (myci != IDX_INVALID && pr2 > 0) ? (ss / (double)pr2)
                                                         : 1.0e300;
            s_kd[wv][lane] = kd;
        }

        {
            const int d = lane;
            u32 xobs = (d < 32) ? ((xmlo >> d) & 1u) : ((xmhi >> (d - 32)) & 1u);
            float res;
            if (xobs) {
                res = s_xv[qq][d];
            } else {
                u64 used = 0; float sum = 0.f; int cnt = 0;
                for (int s = 0; s < K; ++s) {
                    int best = -1; double bk = 0.0; u32 bi = 0;
                    for (int r = 0; r < TCAP; ++r) {
                        if ((used >> r) & 1ull) continue;
                        u32 ci = s_ci[wv][r];
                        if (ci == IDX_INVALID) continue;
                        float v = cv[(r << 6) + (d ^ (r & 31))];
                        if (f32_missing_bits(__float_as_uint(v))) continue;
                        double kd = s_kd[wv][r];
                        if (kd >= 1.0e300) continue;
                        if (best < 0 || kd < bk || (kd == bk && ci < bi)) {
                            best = r; bk = kd; bi = ci;
                        }
                    }
                    if (best < 0) break;
                    used |= 1ull << best;
                    sum += cv[(best << 6) + (d ^ (best & 31))];
                    cnt++;
                }
                if (cnt > 0) {
                    res = sum / (float)cnt;
                } else {
                    float cs = 0.f; int cc = 0;
                    for (int f = 0; f < NF; ++f) {
                        float yf = fit[(size_t)f * D + d];
                        if (!f32_missing_bits(__float_as_uint(yf))) { cs += yf; cc++; }
                    }
                    res = cc > 0 ? cs / (float)cc : 0.f;
                }
                u32 rb = __float_as_uint(res);
                if (((rb >> 23) & 0xFFu) == 0xFFu) res = 0.f;
            }
            out[(size_t)q * D + d] = res;
        }
    }
}

// ---- last fallback: proven R15 kernel ---------------------------------------
__global__ __launch_bounds__(256) void knn_fb(
        const float* __restrict__ X,
        const float* __restrict__ fit,
        const int* __restrict__ pk,
        float* __restrict__ out) {
    __shared__ __align__(16) unsigned char s_pool[16384];
    __shared__ u32   s_hist[256];
    __shared__ u32   s_blw[256];
    __shared__ u32   s_tie[256];
    __shared__ __align__(16) float s_xv[D];
    __shared__ u64   s_xmask;
    __shared__ u32   s_ci[TCAP];
    __shared__ double s_kd[TCAP];
    __shared__ u32   s_sel0, s_below0, s_sel1;

    u16*   s_k16 = (u16*)s_pool;
    float* s_cv  = (float*)s_pool;
    const int tid = threadIdx.x;
    const int q = blockIdx.x;

    if (tid < 64) {
        float xf = X[(size_t)q * D + tid];
        int obs = !f32_missing_bits(__float_as_uint(xf));
        s_xv[tid] = obs ? xf : 0.f;
        u64 bal = __ballot(obs != 0);
        if (tid == 0) s_xmask = bal;
    }
    __syncthreads();

    const u64 xm = s_xmask;
    const u32 xmlo = (u32)xm, xmhi = (u32)(xm >> 32);
    const float4* xv4 = (const float4*)s_xv;
    const float4* fitc = (const float4*)fit;

    for (int i = 0; i < 32; ++i) {
        int f = tid + (i << 8);
        const float4* rp = fitc + (size_t)f * 16;
        float ssd = 0.f; int pres = 0;
#pragma unroll
        for (int m = 0; m < 16; ++m) {
            float4 w = rp[m];
            float4 xc = xv4[m];
            u32 mb = (m < 8) ? (xmlo >> ((m & 7) * 4)) : (xmhi >> ((m & 7) * 4));
            float wv[4] = { w.x, w.y, w.z, w.w };
            float xw[4] = { xc.x, xc.y, xc.z, xc.w };
#pragma unroll
            for (int u = 0; u < 4; ++u) {
                int ok = (int)((mb >> u) & 1u)
                       & (f32_missing_bits(__float_as_uint(wv[u])) ^ 1);
                float t = ok ? wv[u] : xw[u];
                float dm = xw[u] - t;
                ssd = fmaf(dm, dm, ssd);
                pres += ok;
            }
        }
        float kk = (pres > 0) ? (ssd / (float)pres) : __uint_as_float(FLTMAX_BITS);
        s_k16[f] = (u16)(__float_as_uint(kk) >> 16);
    }
    __syncthreads();

    int K = *pk;
    if (K < 1 || K > 64) {
        float kf = __int_as_float(K);
        K = (kf >= 1.f && kf <= 64.f) ? (int)kf : 5;
    }
    if (K > TCAP) K = TCAP;

    s_hist[tid] = 0;
    __syncthreads();
    for (int i = 0; i < 32; ++i) {
        u32 k16 = (u32)s_k16[tid + (i << 8)];
        atomicAdd(&s_hist[k16 >> 8], 1u);
    }
    __syncthreads();
    if (tid == 0) {
        u32 run = 0, below = 0, sel = 255;
        for (int b = 0; b < 256; ++b) {
            u32 c = s_hist[b];
            if (run + c >= (u32)RANK) { sel = (u32)b; below = run; break; }
            run += c;
        }
        s_sel0 = sel; s_below0 = below;
    }
    __syncthreads();
    const u32 sel0 = s_sel0;
    const u32 need1 = (u32)RANK - s_below0;
    __syncthreads();
    s_hist[tid] = 0;
    __syncthreads();
    for (int i = 0; i < 32; ++i) {
        u32 k16 = (u32)s_k16[tid + (i << 8)];
        if ((k16 >> 8) == sel0) atomicAdd(&s_hist[k16 & 0xFFu], 1u);
    }
    __syncthreads();
    if (tid == 0) {
        u32 run = 0, sel = 255;
        for (int b = 0; b < 256; ++b) {
            u32 c = s_hist[b];
            if (run + c >= need1) { sel = (u32)b; break; }
            run += c;
        }
        s_sel1 = sel;
    }
    __syncthreads();
    const u32 thr16 = (sel0 << 8) | s_sel1;

    {
        u32 bb = 0, tb = 0;
        for (int i = 0; i < 32; ++i) {
            u32 k16 = (u32)s_k16[tid + (i << 8)];
            bb |= (k16 < thr16)  ? (1u << i) : 0u;
            tb |= (k16 == thr16) ? (1u << i) : 0u;
        }
        s_blw[tid] = bb; s_tie[tid] = tb;
    }
    __syncthreads();
    if (tid == 0) {
        int n = 0;
        for (int t = 0; t < 256 && n < TCAP; ++t) {
            u32 w = s_blw[t];
            while (w && n < TCAP) {
                int i = __ffs(w) - 1; w &= w - 1;
                s_ci[n++] = (u32)(i * 256 + t);
            }
        }
        u32 tf[TCAP]; int nt = 0;
        for (int t = 0; t < 256 && nt < TCAP; ++t) {
            u32 w = s_tie[t];
            while (w && nt < TCAP) {
                int i = __ffs(w) - 1; w &= w - 1;
                tf[nt++] = (u32)(i * 256 + t);
            }
        }
        int cap = TCAP - n;
        if (nt <= cap) {
            for (int r = 0; r < nt; ++r) s_ci[n++] = tf[r];
        } else {
            for (int j = 0; j < cap; ++j) {
                int bp = -1; u32 bi = IDX_INVALID;
                for (int r = 0; r < nt; ++r)
                    if (tf[r] < bi) { bi = tf[r]; bp = r; }
                tf[bp] = IDX_INVALID;
                s_ci[n++] = bi;
            }
        }
        for (; n < TCAP; ++n) s_ci[n] = IDX_INVALID;
    }
    __syncthreads();

#pragma unroll
    for (int t = 0; t < (TCAP * 64) / 256; ++t) {
        int idx = tid + t * 256;
        int r = idx >> 6, d2 = idx & 63;
        u32 ci = s_ci[r];
        s_cv[idx] = (ci != IDX_INVALID) ? fit[(size_t)ci * D + d2]
                                        : __uint_as_float(NANF_BITS);
    }

    if (tid < TCAP) {
        u32 ci = s_ci[tid];
        double kd = 1.0e300;
        if (ci != IDX_INVALID) {
            const float* row = fit + (size_t)ci * D;
            double ss = 0.0; int pr = 0;
            for (int j = 0; j < D; ++j) {
                float yf = row[j];
                int vmiss = f32_missing_bits(__float_as_uint(yf));
                u32 xbit = (j < 32) ? ((xmlo >> j) & 1u) : ((xmhi >> (j - 32)) & 1u);
                int ok = (int)xbit & (vmiss ^ 1);
                double dd = ok ? ((double)s_xv[j] - (double)yf) : 0.0;
                ss = fma(dd, dd, ss);
                pr += ok;
            }
            kd = (pr > 0) ? (ss / (double)pr) : 1.0e300;
        }
        s_kd[tid] = kd;
    }
    __syncthreads();

    if (tid < 64) {
        const int d = tid;
        u32 xobs = (d < 32) ? ((xmlo >> d) & 1u) : ((xmhi >> (d - 32)) & 1u);
        float res;
        if (xobs) {
            res = s_xv[d];
        } else {
            u64 used = 0; float sum = 0.f; int cnt = 0;
            for (int s = 0; s < K; ++s) {
                int best = -1; double bk = 0.0; u32 bi = 0;
                for (int r = 0; r < TCAP; ++r) {
                    if ((used >> r) & 1ull) continue;
                    u32 ci = s_ci[r];
                    if (ci == IDX_INVALID) continue;
                    float v = s_cv[r * 64 + d];
                    if (f32_missing_bits(__float_as_uint(v))) continue;
                    double kd = s_kd[r];
                    if (kd >= 1.0e300) continue;
                    if (best < 0 || kd < bk || (kd == bk && ci < bi)) {
                        best = r; bk = kd; bi = ci;
                    }
                }
                if (best < 0) break;
                used |= 1ull << best;
                sum += s_cv[best * 64 + d];
                cnt++;
            }
            if (cnt > 0) {
                res = sum / (float)cnt;
            } else {
                float cs = 0.f; int cc = 0;
                for (int f = 0; f < NF; ++f) {
                    float yf = fit[(size_t)f * D + d];
                    if (!f32_missing_bits(__float_as_uint(yf))) { cs += yf; cc++; }
                }
                res = cc > 0 ? cs / (float)cc : 0.f;
            }
            u32 rb = __float_as_uint(res);
            if (((rb >> 23) & 0xFFu) == 0xFFu) res = 0.f;
        }
        out[(size_t)q * D + d] = res;
    }
}

// ---- launch ------------------------------------------------------------------
extern "C" void kernel_launch(void* const* d_in, const int* in_sizes, int n_in,
                              void* d_out, int out_size, void* d_ws, size_t ws_size,
                              hipStream_t stream) {
    const void* pX = d_in[0];
    const void* pF = (n_in > 1) ? d_in[1] : d_in[0];
    const void* pK = (n_in > 2) ? d_in[2] : d_in[0];
    for (int i = 0; i < n_in; ++i) {
        if (in_sizes[i] == NQ * D)      pX = d_in[i];
        else if (in_sizes[i] == NF * D) pF = d_in[i];
        else if (in_sizes[i] == 1)      pK = d_in[i];
    }
    const float* X   = (const float*)pX;
    const float* fit = (const float*)pF;
    const int*   pk  = (const int*)pK;
    float* out = (float*)d_out;

    const size_t perQ = (size_t)NF * sizeof(u16);          // 16 KB per query
    if (ws_size >= FRAG_BYTES + 2048 * perQ) {
        uint4* frags = (uint4*)d_ws;
        u16*   keys  = (u16*)((char*)d_ws + FRAG_BYTES);
        size_t avail = ws_size - FRAG_BYTES;
        int chunkQ = (int)(avail / perQ);
        if (chunkQ > NQ) chunkQ = NQ;
        chunkQ &= ~(QA - 1);                                // multiple of QA
        prep_frags<<<(NTILES * 384) / 256, 256, 0, stream>>>(fit, frags);
        for (int cq0 = 0; cq0 < NQ; cq0 += chunkQ) {
            int cur = NQ - cq0 < chunkQ ? NQ - cq0 : chunkQ;
            knn_keys<<<cur / QA, 256, 0, stream>>>(X, frags, keys, cq0);
            knn_sel<<<cur, 64, 0, stream>>>(X, fit, keys, pk, out, cq0);
        }
    } else if (ws_size >= FRAG_BYTES) {
        uint4* frags = (uint4*)d_ws;
        prep_frags<<<(NTILES * 384) / 256, 256, 0, stream>>>(fit, frags);
        knn_mfma<<<NQ / QB, 256, 0, stream>>>(X, fit, frags, pk, out);
    } else {
        knn_fb<<<NQ, 256, 0, stream>>>(X, fit, pk, out);
    }
}

// Round 8
// 580.945 us; speedup vs baseline: 61.2932x; 1.1005x over previous
//
#include <hip/hip_runtime.h>

// R22: kill the 16KB LDS staging in knn_sel. R21 (639us) = ~2x321us knn_sel;
// occupancy pinned at 24.5% by LDS_Block_Size 17,920 (s_cv staging) -> 8
// single-wave blocks/CU. But fit is 2MB = L2-resident: staging saves nothing.
// (1) 2b re-keys from the lane's own candidate row via 16 float4 L2 loads
//     (same values, same fp64 fma order j=0..63 => bit-identical kd);
//     2d reads fit[ci*D+d] per sorted step (all lanes same row, col=lane =>
//     coalesced 256B L2 hits; same NaN-skip semantics). LDS 17.9KB -> 2.7KB.
// (2) 128-thread blocks = 2 independent waves (2 queries), per-wave LDS
//     slices, zero barriers -> occupancy cap moves to VGPR (~5 waves/SIMD).
// Threshold/collection/rank-sort/top-K semantics unchanged => same output.
// knn_keys (QA=32 dual-column MFMA) and fallbacks unchanged (proven).

#define NQ 16384
#define NF 8192
#define D  64
#define TCAP 64
#define RANK 32
#define QB 8            // R19 fallback kernel
#define QA 32           // kernel-A queries per block (two 16-col MFMA sets)
#define PADW 8208
#define NTILES 512      // NF/16
#define FRAG_BYTES ((size_t)NTILES * 384 * 16)   // 3 MB

typedef unsigned short u16;
typedef unsigned int u32;
typedef unsigned long long u64;
typedef __attribute__((ext_vector_type(8))) short bf16x8;
typedef __attribute__((ext_vector_type(4))) float f32x4;

#define IDX_INVALID 0xFFFFFFFFu
#define NANF_BITS   0x7FC00000u
#define FLTMAX_BITS 0x7F7FFFFFu

__device__ __forceinline__ int f32_missing_bits(u32 b) {
    return ((b >> 23) & 0xFFu) == 0xFFu;      // NaN/inf => missing
}
__device__ __forceinline__ u16 bf16_rne(float f) {
    u32 b = __float_as_uint(f);
    return (u16)((b + 0x7FFFu + ((b >> 16) & 1u)) >> 16);
}

// ---- prep: donor-side MFMA A-fragments into ws (unchanged, proven) ----------
__global__ __launch_bounds__(256) void prep_frags(const float* __restrict__ fit,
                                                  uint4* __restrict__ frags) {
    int idx  = blockIdx.x * 256 + threadIdx.x;    // 0 .. NTILES*384-1
    int lane = idx & 63;
    int kk   = (idx >> 6) & 1;
    int sel  = (idx >> 7) % 3;
    int t    = (idx >> 7) / 3;
    int donor = t * 16 + (lane & 15);
    int j0 = kk * 32 + ((lane >> 4) & 3) * 8;
    const float* row = fit + (size_t)donor * D + j0;
    u32 w[4];
#pragma unroll
    for (int p = 0; p < 4; ++p) {
        u16 h0, h1;
        {
            float v = row[p * 2];
            int miss = f32_missing_bits(__float_as_uint(v));
            float vc = miss ? 0.f : v;
            float val = (sel == 0) ? (miss ? 0.f : 1.f) : (sel == 1) ? vc * vc : vc;
            h0 = bf16_rne(val);
        }
        {
            float v = row[p * 2 + 1];
            int miss = f32_missing_bits(__float_as_uint(v));
            float vc = miss ? 0.f : v;
            float val = (sel == 0) ? (miss ? 0.f : 1.f) : (sel == 1) ? vc * vc : vc;
            h1 = bf16_rne(val);
        }
        w[p] = (u32)h0 | ((u32)h1 << 16);
    }
    frags[idx] = make_uint4(w[0], w[1], w[2], w[3]);
}

#define MF(A, B, C) __builtin_amdgcn_mfma_f32_16x16x32_bf16(                  \
        __builtin_bit_cast(bf16x8, (A)), (B), (C), 0, 0, 0)

#define LOADT(T, A0, A1, A2, A3, A4, A5) {                                    \
        size_t bo = (size_t)(T) * 384 + lane;                                 \
        A0 = frags[bo];       A1 = frags[bo + 64];                            \
        A2 = frags[bo + 128]; A3 = frags[bo + 192];                           \
        A4 = frags[bo + 256]; A5 = frags[bo + 320]; }

// ---- kernel A: QA=32 MFMA keys (two column sets) -> global workspace --------
__global__ __launch_bounds__(256) void knn_keys(
        const float* __restrict__ X,
        const uint4* __restrict__ frags,
        u16* __restrict__ keys,                   // [chunkQ][NF]
        int cq0) {
    __shared__ __align__(16) float s_xv[QA][D];   // 8 KB
    __shared__ u64 s_xmask[QA];

    const int tid = threadIdx.x;
    const int qb0 = blockIdx.x * QA;              // local query base

#pragma unroll
    for (int rr = 0; rr < 8; ++rr) {
        int qq = rr * 4 + (tid >> 6);
        int d  = tid & 63;
        float xf = X[(size_t)(cq0 + qb0 + qq) * D + d];
        int obs = !f32_missing_bits(__float_as_uint(xf));
        s_xv[qq][d] = obs ? xf : 0.f;
        u64 bal = __ballot(obs != 0);
        if (d == 0) s_xmask[qq] = bal;
    }
    __syncthreads();

    const int lane = tid & 63;
    const int qcol = lane & 15;
    const int krow = (lane >> 4) & 3;
    bf16x8 aXX0, aXX1, aOX0, aOX1, aM0, aM1;      // column set A: queries qb0+qcol
    bf16x8 bXX0, bXX1, bOX0, bOX1, bM0, bM1;      // column set B: queries qb0+16+qcol
#define BUILD_B(QIDX, XX0, XX1, OX0, OX1, M0, M1) {                           \
        const float* xr_ = s_xv[QIDX];                                        \
        u64 xm_ = s_xmask[QIDX];                                              \
        _Pragma("unroll")                                                     \
        for (int e = 0; e < 8; ++e) {                                         \
            int j0_ = krow * 8 + e;                                           \
            float x0_ = xr_[j0_];                                             \
            XX0[e] = (short)bf16_rne(x0_ * x0_);                              \
            OX0[e] = (short)(((xm_ >> j0_) & 1ull) ? 0x3F80 : 0);             \
            M0[e]  = (short)bf16_rne(-2.f * x0_);                             \
            int j1_ = 32 + krow * 8 + e;                                      \
            float x1_ = xr_[j1_];                                             \
            XX1[e] = (short)bf16_rne(x1_ * x1_);                              \
            OX1[e] = (short)(((xm_ >> j1_) & 1ull) ? 0x3F80 : 0);             \
            M1[e]  = (short)bf16_rne(-2.f * x1_);                             \
        } }
    BUILD_B(qcol,      aXX0, aXX1, aOX0, aOX1, aM0, aM1)
    BUILD_B(16 + qcol, bXX0, bXX1, bOX0, bOX1, bM0, bM1)
#undef BUILD_B

    const int wv = tid >> 6;
    int t = wv * 128;
    uint4 c0, c1, c2, c3, c4, c5;
    uint4 n0 = {}, n1 = {}, n2 = {}, n3 = {}, n4 = {}, n5 = {};
    LOADT(t, c0, c1, c2, c3, c4, c5);
#pragma unroll 1
    for (int tt = 0; tt < 128; ++tt) {
        bool hasn = (tt + 1 < 128);
        if (hasn) LOADT(t + 1, n0, n1, n2, n3, n4, n5);
        f32x4 sA = {0.f,0.f,0.f,0.f}, pA = {0.f,0.f,0.f,0.f};
        f32x4 sB = {0.f,0.f,0.f,0.f}, pB = {0.f,0.f,0.f,0.f};
        sA = MF(c0, aXX0, sA); sA = MF(c1, aXX1, sA);
        sA = MF(c2, aOX0, sA); sA = MF(c3, aOX1, sA);
        sA = MF(c4, aM0,  sA); sA = MF(c5, aM1,  sA);
        pA = MF(c0, aOX0, pA); pA = MF(c1, aOX1, pA);
        sB = MF(c0, bXX0, sB); sB = MF(c1, bXX1, sB);
        sB = MF(c2, bOX0, sB); sB = MF(c3, bOX1, sB);
        sB = MF(c4, bM0,  sB); sB = MF(c5, bM1,  sB);
        pB = MF(c0, bOX0, pB); pB = MF(c1, bOX1, pB);
#define MKKEY(P, S, r) (((P)[r] > 0.5f)                                       \
            ? __float_as_uint(__fdividef(fmaxf((S)[r], 0.f), (P)[r]))         \
            : FLTMAX_BITS)
        {
            u32 b0 = MKKEY(pA, sA, 0), b1 = MKKEY(pA, sA, 1);
            u32 b2 = MKKEY(pA, sA, 2), b3 = MKKEY(pA, sA, 3);
            size_t off = (size_t)(qb0 + qcol) * NF + (size_t)t * 16 + krow * 4;
            *(uint2*)(keys + off) = make_uint2((b0 >> 16) | (b1 & 0xFFFF0000u),
                                               (b2 >> 16) | (b3 & 0xFFFF0000u));
        }
        {
            u32 b0 = MKKEY(pB, sB, 0), b1 = MKKEY(pB, sB, 1);
            u32 b2 = MKKEY(pB, sB, 2), b3 = MKKEY(pB, sB, 3);
            size_t off = (size_t)(qb0 + 16 + qcol) * NF + (size_t)t * 16 + krow * 4;
            *(uint2*)(keys + off) = make_uint2((b0 >> 16) | (b1 & 0xFFFF0000u),
                                               (b2 >> 16) | (b3 & 0xFFFF0000u));
        }
#undef MKKEY
        if (hasn) { c0 = n0; c1 = n1; c2 = n2; c3 = n3; c4 = n4; c5 = n5; }
        ++t;
    }
}

// ---- kernel B: 2 waves/block, 1 query/wave; no staging; LDS ~2.7KB ----------
__global__ __launch_bounds__(128) void knn_sel(
        const float* __restrict__ X,
        const float* __restrict__ fit,
        const u16* __restrict__ keys,             // [chunkQ][NF]
        const int* __restrict__ pk,
        float* __restrict__ out,
        int cq0) {
    __shared__ __align__(16) float s_xv[2][D];
    __shared__ u32    s_ci[2][TCAP];
    __shared__ double s_kd[2][TCAP];
    __shared__ u32    s_ord[2][TCAP];
    __shared__ u32    s_cnt[2];

    const int lane = threadIdx.x & 63;
    const int wv   = threadIdx.x >> 6;
    const int ql = blockIdx.x * 2 + wv;           // local query
    const int q  = cq0 + ql;                      // global query

    float xf = X[(size_t)q * D + lane];
    int obs = !f32_missing_bits(__float_as_uint(xf));
    s_xv[wv][lane] = obs ? xf : 0.f;
    const u64 xm = __ballot(obs != 0);
    const u32 xmlo = (u32)xm, xmhi = (u32)(xm >> 32);

    // ---- keys -> 16 statically-indexed uint4 regs; track per-lane min ----
    uint4 kr[16];
    u32 mymin = 0xFFFFu;
    {
        const uint4* kg = (const uint4*)(keys + (size_t)ql * NF);
#pragma unroll
        for (int i = 0; i < 16; ++i) {
            kr[i] = kg[lane + (i << 6)];
#define MIN16S(W) { u32 a_ = (W) & 0xFFFFu, b_ = (W) >> 16;                   \
                    mymin = a_ < mymin ? a_ : mymin;                          \
                    mymin = b_ < mymin ? b_ : mymin; }
            MIN16S(kr[i].x) MIN16S(kr[i].y) MIN16S(kr[i].z) MIN16S(kr[i].w)
#undef MIN16S
        }
    }
    u32 lo0 = mymin, hi0 = mymin;      // bracket: [min, max-of-lane-mins]
#pragma unroll
    for (int o = 32; o; o >>= 1) {
        u32 a = (u32)__shfl_xor((int)lo0, o, 64); lo0 = a < lo0 ? a : lo0;
        u32 b = (u32)__shfl_xor((int)hi0, o, 64); hi0 = b > hi0 ? b : hi0;
    }

    int K = *pk;
    if (K < 1 || K > 64) {             // robustness if scalar arrived as float
        float kf = __int_as_float(K);
        K = (kf >= 1.f && kf <= 64.f) ? (int)kf : 5;
    }
    if (K > TCAP) K = TCAP;

    // -- 2a: 32nd-smallest u16 key via bracketed binary search (from regs) --
    u32 blo = lo0, bhi = hi0;
#pragma unroll 1
    while (blo < bhi) {
        u32 mid = (blo + bhi) >> 1;
        int c = 0;
#pragma unroll
        for (int i = 0; i < 16; ++i) {
#define CNTLE(W) { c += (((W) & 0xFFFFu) <= mid) + (((W) >> 16) <= mid); }
            CNTLE(kr[i].x) CNTLE(kr[i].y) CNTLE(kr[i].z) CNTLE(kr[i].w)
#undef CNTLE
        }
#pragma unroll
        for (int o = 32; o; o >>= 1) c += __shfl_xor(c, o, 64);
        if ((u32)c >= (u32)RANK) bhi = mid; else blo = mid + 1;
    }
    const u32 thr16 = blo;

    // -- 2a': collection from regs (set is order-independent) --
    if (lane == 0) s_cnt[wv] = 0;      // in-wave LDS order: safe
    int nb = 0, nt2 = 0;
#pragma unroll
    for (int i = 0; i < 16; ++i) {
#define CNT2(W) { u32 k0_ = (W) & 0xFFFFu, k1_ = (W) >> 16;                   \
                  nb  += (k0_ < thr16)  + (k1_ < thr16);                      \
                  nt2 += (k0_ == thr16) + (k1_ == thr16); }
        CNT2(kr[i].x) CNT2(kr[i].y) CNT2(kr[i].z) CNT2(kr[i].w)
#undef CNT2
    }
    int tb = nb, tt2 = nt2;
#pragma unroll
    for (int o = 32; o; o >>= 1) {
        tb  += __shfl_xor(tb, o, 64);
        tt2 += __shfl_xor(tt2, o, 64);
    }
    const int nTot = tb + tt2;         // >= RANK
    if (nTot <= TCAP) {
#pragma unroll
        for (int i = 0; i < 16; ++i) {
            int f8 = (lane + (i << 6)) * 8;
#define APP(W, FB) { u32 k0_ = (W) & 0xFFFFu, k1_ = (W) >> 16;                \
        if (k0_ <= thr16) { u32 p_ = atomicAdd(&s_cnt[wv], 1u); s_ci[wv][p_] = (u32)(FB); } \
        if (k1_ <= thr16) { u32 p_ = atomicAdd(&s_cnt[wv], 1u); s_ci[wv][p_] = (u32)((FB) + 1); } }
            APP(kr[i].x, f8 + 0) APP(kr[i].y, f8 + 2)
            APP(kr[i].z, f8 + 4) APP(kr[i].w, f8 + 6)
#undef APP
        }
        if (lane >= nTot) s_ci[wv][lane] = IDX_INVALID;
    } else {
        // rare overflow: all below, then ties ascending (smallest donor idx)
        if (lane == 0) {
            const u16* krow = keys + (size_t)ql * NF;
            int n = 0;
            for (int f = 0; f < NF; ++f)
                if ((u32)krow[f] < thr16) s_ci[wv][n++] = (u32)f;
            for (int f = 0; f < NF && n < TCAP; ++f)
                if ((u32)krow[f] == thr16) s_ci[wv][n++] = (u32)f;
            for (; n < TCAP; ++n) s_ci[wv][n] = IDX_INVALID;
        }
    }

    // -- 2b: exact fp64 re-key; lane reads its own candidate row (L2-hot) --
    u32 myci = s_ci[wv][lane];
    double mykd = 1.0e300;
    if (myci != IDX_INVALID) {
        const float4* row4 = (const float4*)(fit + (size_t)myci * D);
        double ss = 0.0; int pr2 = 0;
#pragma unroll
        for (int g = 0; g < 16; ++g) {
            float4 w4 = row4[g];
            float wv4[4] = { w4.x, w4.y, w4.z, w4.w };
#pragma unroll
            for (int u = 0; u < 4; ++u) {
                int j = g * 4 + u;                 // ascending: same fma order
                int vmiss = f32_missing_bits(__float_as_uint(wv4[u]));
                u32 xbit = (j < 32) ? ((xmlo >> j) & 1u) : ((xmhi >> (j - 32)) & 1u);
                int ok = (int)xbit & (vmiss ^ 1);
                double dd = ok ? ((double)s_xv[wv][j] - (double)wv4[u]) : 0.0;
                ss = fma(dd, dd, ss);
                pr2 += ok;
            }
        }
        mykd = (pr2 > 0) ? (ss / (double)pr2) : 1.0e300;
    }
    s_kd[wv][lane] = mykd;

    // -- rank candidates by (kd, ci, lane); s_ord = sorted order --
    {
        int rank = 0;
#pragma unroll 1
        for (int j = 0; j < 64; ++j) {
            double kdj = __shfl(mykd, j, 64);
            u32 cij = (u32)__shfl((int)myci, j, 64);
            int less = (kdj < mykd) |
                       ((kdj == mykd) & ((cij < myci) |
                                         ((cij == myci) & (j < lane))));
            rank += less;
        }
        s_ord[wv][rank] = (u32)lane;
    }

    // -- 2d: walk sorted candidates; read donor values from L2-hot fit --
    {
        const int d = lane;
        u32 xobs = (d < 32) ? ((xmlo >> d) & 1u) : ((xmhi >> (d - 32)) & 1u);
        float res;
        if (xobs) {
            res = s_xv[wv][d];
        } else {
            float sum = 0.f; int cnt = 0;
#pragma unroll 1
            for (int s2 = 0; s2 < TCAP; ++s2) {
                u32 r = s_ord[wv][s2];
                u32 ci = s_ci[wv][r];
                if (ci == IDX_INVALID) break;        // invalids sort last
                if (s_kd[wv][r] >= 1.0e300) break;   // ascending => all done
                float v = fit[(size_t)ci * D + d];   // coalesced row, L2 hit
                if (f32_missing_bits(__float_as_uint(v))) continue;
                sum += v;
                if (++cnt == K) break;
            }
            if (cnt > 0) {
                res = sum / (float)cnt;
            } else {
                float cs = 0.f; int cc = 0;          // essentially-never fallback
                for (int f = 0; f < NF; ++f) {
                    float yf = fit[(size_t)f * D + d];
                    if (!f32_missing_bits(__float_as_uint(yf))) { cs += yf; cc++; }
                }
                res = cc > 0 ? cs / (float)cc : 0.f;
            }
            u32 rb = __float_as_uint(res);
            if (((rb >> 23) & 0xFFu) == 0xFFu) res = 0.f;   // integer guard
        }
        out[(size_t)q * D + d] = res;
    }
}

// ---- mid fallback: proven R19 single-kernel (verbatim) ----------------------
__global__ __launch_bounds__(256) void knn_mfma(
        const float* __restrict__ X,
        const float* __restrict__ fit,
        const uint4* __restrict__ frags,
        const int* __restrict__ pk,
        float* __restrict__ out) {
    __shared__ __align__(16) u16 s_k16[QB * PADW];
    __shared__ __align__(16) float s_xv[QB][D];
    __shared__ u64    s_xmask[QB];
    __shared__ u32    s_ci[4][TCAP];
    __shared__ double s_kd[4][TCAP];
    __shared__ u32    s_cnt[4];

    const int tid = threadIdx.x;
    const int q0 = blockIdx.x * QB;

#pragma unroll
    for (int rr = 0; rr < 2; ++rr) {
        int qq = rr * 4 + (tid >> 6);
        int d  = tid & 63;
        float xf = X[(size_t)(q0 + qq) * D + d];
        int obs = !f32_missing_bits(__float_as_uint(xf));
        s_xv[qq][d] = obs ? xf : 0.f;
        u64 bal = __ballot(obs != 0);
        if (d == 0) s_xmask[qq] = bal;
    }
    __syncthreads();

    const int lane = tid & 63;
    const int qcol = lane & 15;
    const int krow = (lane >> 4) & 3;
    bf16x8 bXX0 = (bf16x8)(short)0, bXX1 = (bf16x8)(short)0;
    bf16x8 bOX0 = (bf16x8)(short)0, bOX1 = (bf16x8)(short)0;
    bf16x8 bM0  = (bf16x8)(short)0, bM1  = (bf16x8)(short)0;
    if (qcol < QB) {
        const float* xr = s_xv[qcol];
        u64 xm = s_xmask[qcol];
#pragma unroll
        for (int e = 0; e < 8; ++e) {
            {
                int j = krow * 8 + e;
                float x = xr[j];
                bXX0[e] = (short)bf16_rne(x * x);
                bOX0[e] = (short)(((xm >> j) & 1ull) ? 0x3F80 : 0);
                bM0[e]  = (short)bf16_rne(-2.f * x);
            }
            {
                int j = 32 + krow * 8 + e;
                float x = xr[j];
                bXX1[e] = (short)bf16_rne(x * x);
                bOX1[e] = (short)(((xm >> j) & 1ull) ? 0x3F80 : 0);
                bM1[e]  = (short)bf16_rne(-2.f * x);
            }
        }
    }

    {
        const int wv = tid >> 6;
        int t = wv * 128;
        uint4 c0, c1, c2, c3, c4, c5;
        uint4 n0 = {}, n1 = {}, n2 = {}, n3 = {}, n4 = {}, n5 = {};
        LOADT(t, c0, c1, c2, c3, c4, c5);
#pragma unroll 1
        for (int tt = 0; tt < 128; ++tt) {
            bool hasn = (tt + 1 < 128);
            if (hasn) LOADT(t + 1, n0, n1, n2, n3, n4, n5);
            f32x4 accS = {0.f, 0.f, 0.f, 0.f};
            f32x4 accP = {0.f, 0.f, 0.f, 0.f};
            accS = MF(c0, bXX0, accS);
            accS = MF(c1, bXX1, accS);
            accS = MF(c2, bOX0, accS);
            accS = MF(c3, bOX1, accS);
            accS = MF(c4, bM0,  accS);
            accS = MF(c5, bM1,  accS);
            accP = MF(c0, bOX0, accP);
            accP = MF(c1, bOX1, accP);
            if (qcol < QB) {
#define MKKEY(r) ((accP[r] > 0.5f)                                            \
                    ? __float_as_uint(__fdividef(fmaxf(accS[r], 0.f), accP[r]))\
                    : FLTMAX_BITS)
                u32 b0 = MKKEY(0), b1 = MKKEY(1), b2 = MKKEY(2), b3 = MKKEY(3);
#undef MKKEY
                u32 lo = (b0 >> 16) | (b1 & 0xFFFF0000u);
                u32 hi = (b2 >> 16) | (b3 & 0xFFFF0000u);
                u32 off = (u32)qcol * PADW + (u32)t * 16 + (u32)krow * 4;
                *(uint2*)(&s_k16[off]) = make_uint2(lo, hi);
            }
            if (hasn) { c0 = n0; c1 = n1; c2 = n2; c3 = n3; c4 = n4; c5 = n5; }
            ++t;
        }
    }
    __syncthreads();

    int K = *pk;
    if (K < 1 || K > 64) {
        float kf = __int_as_float(K);
        K = (kf >= 1.f && kf <= 64.f) ? (int)kf : 5;
    }
    if (K > TCAP) K = TCAP;

    const int wv = tid >> 6;
#pragma unroll 1
    for (int rr = 0; rr < 2; ++rr) {
        const int qq = wv + rr * 4;
        const int q = q0 + qq;
        u16* kq = s_k16 + (size_t)qq * PADW;
        const u32* kq32 = (const u32*)kq;
        const u64 xm = s_xmask[qq];
        const u32 xmlo = (u32)xm, xmhi = (u32)(xm >> 32);

        u32 blo = 0, bhi = 65535;
#pragma unroll 1
        while (blo < bhi) {
            u32 mid = (blo + bhi) >> 1;
            int c = 0;
#pragma unroll 8
            for (int i = 0; i < 64; ++i) {
                u32 w2 = kq32[lane + (i << 6)];
                c += ((w2 & 0xFFFFu) <= mid) + ((w2 >> 16) <= mid);
            }
#pragma unroll
            for (int o = 32; o; o >>= 1) c += __shfl_xor(c, o, 64);
            if ((u32)c >= (u32)RANK) bhi = mid; else blo = mid + 1;
        }
        const u32 thr16 = blo;

        if (lane == 0) s_cnt[wv] = 0;
        int nb = 0, nt2 = 0;
#pragma unroll 8
        for (int i = 0; i < 64; ++i) {
            u32 w2 = kq32[lane + (i << 6)];
            u32 k0 = w2 & 0xFFFFu, k1 = w2 >> 16;
            nb  += (k0 < thr16)  + (k1 < thr16);
            nt2 += (k0 == thr16) + (k1 == thr16);
        }
        int tb = nb, tt2 = nt2;
#pragma unroll
        for (int o = 32; o; o >>= 1) {
            tb  += __shfl_xor(tb, o, 64);
            tt2 += __shfl_xor(tt2, o, 64);
        }
        const int nTot = tb + tt2;
        if (nTot <= TCAP) {
#pragma unroll 4
            for (int i = 0; i < 64; ++i) {
                u32 w2 = kq32[lane + (i << 6)];
                u32 k0 = w2 & 0xFFFFu, k1 = w2 >> 16;
                int f0 = (lane + (i << 6)) * 2;
                if (k0 <= thr16) { u32 p = atomicAdd(&s_cnt[wv], 1u); s_ci[wv][p] = (u32)f0; }
                if (k1 <= thr16) { u32 p = atomicAdd(&s_cnt[wv], 1u); s_ci[wv][p] = (u32)(f0 + 1); }
            }
            if (lane >= nTot) s_ci[wv][lane] = IDX_INVALID;
        } else {
            if (lane == 0) {
                int n = 0;
                for (int f = 0; f < NF; ++f)
                    if ((u32)kq[f] < thr16) s_ci[wv][n++] = (u32)f;
                for (int f = 0; f < NF && n < TCAP; ++f)
                    if ((u32)kq[f] == thr16) s_ci[wv][n++] = (u32)f;
                for (; n < TCAP; ++n) s_ci[wv][n] = IDX_INVALID;
            }
        }

        float* cv = (float*)kq;
        u32 myci = s_ci[wv][lane];
#pragma unroll 8
        for (int r = 0; r < TCAP; ++r) {
            u32 ci = __shfl((int)myci, r, 64);
            float v = (ci != IDX_INVALID) ? fit[(size_t)ci * D + lane]
                                          : __uint_as_float(NANF_BITS);
            cv[(r << 6) + (lane ^ (r & 31))] = v;
        }

        {
            double ss = 0.0; int pr2 = 0;
#pragma unroll 8
            for (int j = 0; j < D; ++j) {
                float yf = cv[(lane << 6) + (j ^ (lane & 31))];
                int vmiss = f32_missing_bits(__float_as_uint(yf));
                u32 xbit = (j < 32) ? ((xmlo >> j) & 1u) : ((xmhi >> (j - 32)) & 1u);
                int ok = (int)xbit & (vmiss ^ 1);
                double dd = ok ? ((double)s_xv[qq][j] - (double)yf) : 0.0;
                ss = fma(dd, dd, ss);
                pr2 += ok;
            }
            double kd = (myci != IDX_INVALID && pr2 > 0) ? (ss / (double)pr2)
                                                         : 1.0e300;
            s_kd[wv][lane] = kd;
        }

        {
            const int d = lane;
            u32 xobs = (d < 32) ? ((xmlo >> d) & 1u) : ((xmhi >> (d - 32)) & 1u);
            float res;
            if (xobs) {
                res = s_xv[qq][d];
            } else {
                u64 used = 0; float sum = 0.f; int cnt = 0;
                for (int s = 0; s < K; ++s) {
                    int best = -1; double bk = 0.0; u32 bi = 0;
                    for (int r = 0; r < TCAP; ++r) {
                        if ((used >> r) & 1ull) continue;
                        u32 ci = s_ci[wv][r];
                        if (ci == IDX_INVALID) continue;
                        float v = cv[(r << 6) + (d ^ (r & 31))];
                        if (f32_missing_bits(__float_as_uint(v))) continue;
                        double kd = s_kd[wv][r];
                        if (kd >= 1.0e300) continue;
                        if (best < 0 || kd < bk || (kd == bk && ci < bi)) {
                            best = r; bk = kd; bi = ci;
                        }
                    }
                    if (best < 0) break;
                    used |= 1ull << best;
                    sum += cv[(best << 6) + (d ^ (best & 31))];
                    cnt++;
                }
                if (cnt > 0) {
                    res = sum / (float)cnt;
                } else {
                    float cs = 0.f; int cc = 0;
                    for (int f = 0; f < NF; ++f) {
                        float yf = fit[(size_t)f * D + d];
                        if (!f32_missing_bits(__float_as_uint(yf))) { cs += yf; cc++; }
                    }
                    res = cc > 0 ? cs / (float)cc : 0.f;
                }
                u32 rb = __float_as_uint(res);
                if (((rb >> 23) & 0xFFu) == 0xFFu) res = 0.f;
            }
            out[(size_t)q * D + d] = res;
        }
    }
}

// ---- last fallback: proven R15 kernel ---------------------------------------
__global__ __launch_bounds__(256) void knn_fb(
        const float* __restrict__ X,
        const float* __restrict__ fit,
        const int* __restrict__ pk,
        float* __restrict__ out) {
    __shared__ __align__(16) unsigned char s_pool[16384];
    __shared__ u32   s_hist[256];
    __shared__ u32   s_blw[256];
    __shared__ u32   s_tie[256];
    __shared__ __align__(16) float s_xv[D];
    __shared__ u64   s_xmask;
    __shared__ u32   s_ci[TCAP];
    __shared__ double s_kd[TCAP];
    __shared__ u32   s_sel0, s_below0, s_sel1;

    u16*   s_k16 = (u16*)s_pool;
    float* s_cv  = (float*)s_pool;
    const int tid = threadIdx.x;
    const int q = blockIdx.x;

    if (tid < 64) {
        float xf = X[(size_t)q * D + tid];
        int obs = !f32_missing_bits(__float_as_uint(xf));
        s_xv[tid] = obs ? xf : 0.f;
        u64 bal = __ballot(obs != 0);
        if (tid == 0) s_xmask = bal;
    }
    __syncthreads();

    const u64 xm = s_xmask;
    const u32 xmlo = (u32)xm, xmhi = (u32)(xm >> 32);
    const float4* xv4 = (const float4*)s_xv;
    const float4* fitc = (const float4*)fit;

    for (int i = 0; i < 32; ++i) {
        int f = tid + (i << 8);
        const float4* rp = fitc + (size_t)f * 16;
        float ssd = 0.f; int pres = 0;
#pragma unroll
        for (int m = 0; m < 16; ++m) {
            float4 w = rp[m];
            float4 xc = xv4[m];
            u32 mb = (m < 8) ? (xmlo >> ((m & 7) * 4)) : (xmhi >> ((m & 7) * 4));
            float wv[4] = { w.x, w.y, w.z, w.w };
            float xw[4] = { xc.x, xc.y, xc.z, xc.w };
#pragma unroll
            for (int u = 0; u < 4; ++u) {
                int ok = (int)((mb >> u) & 1u)
                       & (f32_missing_bits(__float_as_uint(wv[u])) ^ 1);
                float t = ok ? wv[u] : xw[u];
                float dm = xw[u] - t;
                ssd = fmaf(dm, dm, ssd);
                pres += ok;
            }
        }
        float kk = (pres > 0) ? (ssd / (float)pres) : __uint_as_float(FLTMAX_BITS);
        s_k16[f] = (u16)(__float_as_uint(kk) >> 16);
    }
    __syncthreads();

    int K = *pk;
    if (K < 1 || K > 64) {
        float kf = __int_as_float(K);
        K = (kf >= 1.f && kf <= 64.f) ? (int)kf : 5;
    }
    if (K > TCAP) K = TCAP;

    s_hist[tid] = 0;
    __syncthreads();
    for (int i = 0; i < 32; ++i) {
        u32 k16 = (u32)s_k16[tid + (i << 8)];
        atomicAdd(&s_hist[k16 >> 8], 1u);
    }
    __syncthreads();
    if (tid == 0) {
        u32 run = 0, below = 0, sel = 255;
        for (int b = 0; b < 256; ++b) {
            u32 c = s_hist[b];
            if (run + c >= (u32)RANK) { sel = (u32)b; below = run; break; }
            run += c;
        }
        s_sel0 = sel; s_below0 = below;
    }
    __syncthreads();
    const u32 sel0 = s_sel0;
    const u32 need1 = (u32)RANK - s_below0;
    __syncthreads();
    s_hist[tid] = 0;
    __syncthreads();
    for (int i = 0; i < 32; ++i) {
        u32 k16 = (u32)s_k16[tid + (i << 8)];
        if ((k16 >> 8) == sel0) atomicAdd(&s_hist[k16 & 0xFFu], 1u);
    }
    __syncthreads();
    if (tid == 0) {
        u32 run = 0, sel = 255;
        for (int b = 0; b < 256; ++b) {
            u32 c = s_hist[b];
            if (run + c >= need1) { sel = (u32)b; break; }
            run += c;
        }
        s_sel1 = sel;
    }
    __syncthreads();
    const u32 thr16 = (sel0 << 8) | s_sel1;

    {
        u32 bb = 0, tb = 0;
        for (int i = 0; i < 32; ++i) {
            u32 k16 = (u32)s_k16[tid + (i << 8)];
            bb |= (k16 < thr16)  ? (1u << i) : 0u;
            tb |= (k16 == thr16) ? (1u << i) : 0u;
        }
        s_blw[tid] = bb; s_tie[tid] = tb;
    }
    __syncthreads();
    if (tid == 0) {
        int n = 0;
        for (int t = 0; t < 256 && n < TCAP; ++t) {
            u32 w = s_blw[t];
            while (w && n < TCAP) {
                int i = __ffs(w) - 1; w &= w - 1;
                s_ci[n++] = (u32)(i * 256 + t);
            }
        }
        u32 tf[TCAP]; int nt = 0;
        for (int t = 0; t < 256 && nt < TCAP; ++t) {
            u32 w = s_tie[t];
            while (w && nt < TCAP) {
                int i = __ffs(w) - 1; w &= w - 1;
                tf[nt++] = (u32)(i * 256 + t);
            }
        }
        int cap = TCAP - n;
        if (nt <= cap) {
            for (int r = 0; r < nt; ++r) s_ci[n++] = tf[r];
        } else {
            for (int j = 0; j < cap; ++j) {
                int bp = -1; u32 bi = IDX_INVALID;
                for (int r = 0; r < nt; ++r)
                    if (tf[r] < bi) { bi = tf[r]; bp = r; }
                tf[bp] = IDX_INVALID;
                s_ci[n++] = bi;
            }
        }
        for (; n < TCAP; ++n) s_ci[n] = IDX_INVALID;
    }
    __syncthreads();

#pragma unroll
    for (int t = 0; t < (TCAP * 64) / 256; ++t) {
        int idx = tid + t * 256;
        int r = idx >> 6, d2 = idx & 63;
        u32 ci = s_ci[r];
        s_cv[idx] = (ci != IDX_INVALID) ? fit[(size_t)ci * D + d2]
                                        : __uint_as_float(NANF_BITS);
    }

    if (tid < TCAP) {
        u32 ci = s_ci[tid];
        double kd = 1.0e300;
        if (ci != IDX_INVALID) {
            const float* row = fit + (size_t)ci * D;
            double ss = 0.0; int pr = 0;
            for (int j = 0; j < D; ++j) {
                float yf = row[j];
                int vmiss = f32_missing_bits(__float_as_uint(yf));
                u32 xbit = (j < 32) ? ((xmlo >> j) & 1u) : ((xmhi >> (j - 32)) & 1u);
                int ok = (int)xbit & (vmiss ^ 1);
                double dd = ok ? ((double)s_xv[j] - (double)yf) : 0.0;
                ss = fma(dd, dd, ss);
                pr += ok;
            }
            kd = (pr > 0) ? (ss / (double)pr) : 1.0e300;
        }
        s_kd[tid] = kd;
    }
    __syncthreads();

    if (tid < 64) {
        const int d = tid;
        u32 xobs = (d < 32) ? ((xmlo >> d) & 1u) : ((xmhi >> (d - 32)) & 1u);
        float res;
        if (xobs) {
            res = s_xv[d];
        } else {
            u64 used = 0; float sum = 0.f; int cnt = 0;
            for (int s = 0; s < K; ++s) {
                int best = -1; double bk = 0.0; u32 bi = 0;
                for (int r = 0; r < TCAP; ++r) {
                    if ((used >> r) & 1ull) continue;
                    u32 ci = s_ci[r];
                    if (ci == IDX_INVALID) continue;
                    float v = s_cv[r * 64 + d];
                    if (f32_missing_bits(__float_as_uint(v))) continue;
                    double kd = s_kd[r];
                    if (kd >= 1.0e300) continue;
                    if (best < 0 || kd < bk || (kd == bk && ci < bi)) {
                        best = r; bk = kd; bi = ci;
                    }
                }
                if (best < 0) break;
                used |= 1ull << best;
                sum += s_cv[best * 64 + d];
                cnt++;
            }
            if (cnt > 0) {
                res = sum / (float)cnt;
            } else {
                float cs = 0.f; int cc = 0;
                for (int f = 0; f < NF; ++f) {
                    float yf = fit[(size_t)f * D + d];
                    if (!f32_missing_bits(__float_as_uint(yf))) { cs += yf; cc++; }
                }
                res = cc > 0 ? cs / (float)cc : 0.f;
            }
            u32 rb = __float_as_uint(res);
            if (((rb >> 23) & 0xFFu) == 0xFFu) res = 0.f;
        }
        out[(size_t)q * D + d] = res;
    }
}

// ---- launch ------------------------------------------------------------------
extern "C" void kernel_launch(void* const* d_in, const int* in_sizes, int n_in,
                              void* d_out, int out_size, void* d_ws, size_t ws_size,
                              hipStream_t stream) {
    const void* pX = d_in[0];
    const void* pF = (n_in > 1) ? d_in[1] : d_in[0];
    const void* pK = (n_in > 2) ? d_in[2] : d_in[0];
    for (int i = 0; i < n_in; ++i) {
        if (in_sizes[i] == NQ * D)      pX = d_in[i];
        else if (in_sizes[i] == NF * D) pF = d_in[i];
        else if (in_sizes[i] == 1)      pK = d_in[i];
    }
    const float* X   = (const float*)pX;
    const float* fit = (const float*)pF;
    const int*   pk  = (const int*)pK;
    float* out = (float*)d_out;

    const size_t perQ = (size_t)NF * sizeof(u16);          // 16 KB per query
    if (ws_size >= FRAG_BYTES + 2048 * perQ) {
        uint4* frags = (uint4*)d_ws;
        u16*   keys  = (u16*)((char*)d_ws + FRAG_BYTES);
        size_t avail = ws_size - FRAG_BYTES;
        int chunkQ = (int)(avail / perQ);
        if (chunkQ > NQ) chunkQ = NQ;
        chunkQ &= ~(QA - 1);                                // multiple of QA
        prep_frags<<<(NTILES * 384) / 256, 256, 0, stream>>>(fit, frags);
        for (int cq0 = 0; cq0 < NQ; cq0 += chunkQ) {
            int cur = NQ - cq0 < chunkQ ? NQ - cq0 : chunkQ;
            knn_keys<<<cur / QA, 256, 0, stream>>>(X, frags, keys, cq0);
            knn_sel<<<cur / 2, 128, 0, stream>>>(X, fit, keys, pk, out, cq0);
        }
    } else if (ws_size >= FRAG_BYTES) {
        uint4* frags = (uint4*)d_ws;
        prep_frags<<<(NTILES * 384) / 256, 256, 0, stream>>>(fit, frags);
        knn_mfma<<<NQ / QB, 256, 0, stream>>>(X, fit, frags, pk, out);
    } else {
        knn_fb<<<NQ, 256, 0, stream>>>(X, fit, pk, out);
    }
}

// Round 9
// 573.547 us; speedup vs baseline: 62.0838x; 1.0129x over previous
//
#include <hip/hip_runtime.h>

// R23: group-min pruning. R22 (581us): knn_sel FETCH 155MB/chunk at 634GB/s
// == dispatch duration -> bound by streaming 256MB of keys from HBM at 8%
// peak (low-MLP latency-limited). Prune: kernel A also writes per-query
// per-32-donor-group MIN key (256 u16/query). Kernel B: UB = 32nd-smallest
// group-min; PROOF: thr16 <= UB (32 groups w/ smallest mins each hold a key
// <= UB), and min_g > UB => no key <= thr16 in g. So only surviving groups
// (min<=UB, typically ~33) are read: ~2KB/query vs 16KB. Exact thr search +
// collection over surviving keys == global result => identical output.
// Fast path (ns<=64): 32 keys/lane in 16 regs. Rare ns>64: transient
// re-reads (no static VGPR cost). nTot>64 overflow: lane-0 global scan
// (unchanged). 2b fp64 re-key / rank-sort / 2d: R22 verbatim.
// Fallbacks: two-kernel needs ws >= 3MB + 2048*(16.5KB); else R19; else R15.

#define NQ 16384
#define NF 8192
#define D  64
#define TCAP 64
#define RANK 32
#define QB 8            // R19 fallback kernel
#define QA 32           // kernel-A queries per block (two 16-col MFMA sets)
#define NG 256          // donor groups per query (32 donors each)
#define PADW 8208
#define NTILES 512      // NF/16
#define FRAG_BYTES ((size_t)NTILES * 384 * 16)   // 3 MB

typedef unsigned short u16;
typedef unsigned int u32;
typedef unsigned long long u64;
typedef __attribute__((ext_vector_type(8))) short bf16x8;
typedef __attribute__((ext_vector_type(4))) float f32x4;

#define IDX_INVALID 0xFFFFFFFFu
#define NANF_BITS   0x7FC00000u
#define FLTMAX_BITS 0x7F7FFFFFu

__device__ __forceinline__ int f32_missing_bits(u32 b) {
    return ((b >> 23) & 0xFFu) == 0xFFu;      // NaN/inf => missing
}
__device__ __forceinline__ u16 bf16_rne(float f) {
    u32 b = __float_as_uint(f);
    return (u16)((b + 0x7FFFu + ((b >> 16) & 1u)) >> 16);
}
__device__ __forceinline__ u32 umin2(u32 a, u32 b) { return a < b ? a : b; }

// ---- prep: donor-side MFMA A-fragments into ws (unchanged, proven) ----------
__global__ __launch_bounds__(256) void prep_frags(const float* __restrict__ fit,
                                                  uint4* __restrict__ frags) {
    int idx  = blockIdx.x * 256 + threadIdx.x;    // 0 .. NTILES*384-1
    int lane = idx & 63;
    int kk   = (idx >> 6) & 1;
    int sel  = (idx >> 7) % 3;
    int t    = (idx >> 7) / 3;
    int donor = t * 16 + (lane & 15);
    int j0 = kk * 32 + ((lane >> 4) & 3) * 8;
    const float* row = fit + (size_t)donor * D + j0;
    u32 w[4];
#pragma unroll
    for (int p = 0; p < 4; ++p) {
        u16 h0, h1;
        {
            float v = row[p * 2];
            int miss = f32_missing_bits(__float_as_uint(v));
            float vc = miss ? 0.f : v;
            float val = (sel == 0) ? (miss ? 0.f : 1.f) : (sel == 1) ? vc * vc : vc;
            h0 = bf16_rne(val);
        }
        {
            float v = row[p * 2 + 1];
            int miss = f32_missing_bits(__float_as_uint(v));
            float vc = miss ? 0.f : v;
            float val = (sel == 0) ? (miss ? 0.f : 1.f) : (sel == 1) ? vc * vc : vc;
            h1 = bf16_rne(val);
        }
        w[p] = (u32)h0 | ((u32)h1 << 16);
    }
    frags[idx] = make_uint4(w[0], w[1], w[2], w[3]);
}

#define MF(A, B, C) __builtin_amdgcn_mfma_f32_16x16x32_bf16(                  \
        __builtin_bit_cast(bf16x8, (A)), (B), (C), 0, 0, 0)

#define LOADT(T, A0, A1, A2, A3, A4, A5) {                                    \
        size_t bo = (size_t)(T) * 384 + lane;                                 \
        A0 = frags[bo];       A1 = frags[bo + 64];                            \
        A2 = frags[bo + 128]; A3 = frags[bo + 192];                           \
        A4 = frags[bo + 256]; A5 = frags[bo + 320]; }

// ---- kernel A: QA=32 MFMA keys + per-group mins -> workspace ----------------
__global__ __launch_bounds__(256) void knn_keys(
        const float* __restrict__ X,
        const uint4* __restrict__ frags,
        u16* __restrict__ keys,                   // [chunkQ][NF]
        u16* __restrict__ mins,                   // [chunkQ][NG]
        int cq0) {
    __shared__ __align__(16) float s_xv[QA][D];   // 8 KB
    __shared__ u64 s_xmask[QA];

    const int tid = threadIdx.x;
    const int qb0 = blockIdx.x * QA;              // local query base

#pragma unroll
    for (int rr = 0; rr < 8; ++rr) {
        int qq = rr * 4 + (tid >> 6);
        int d  = tid & 63;
        float xf = X[(size_t)(cq0 + qb0 + qq) * D + d];
        int obs = !f32_missing_bits(__float_as_uint(xf));
        s_xv[qq][d] = obs ? xf : 0.f;
        u64 bal = __ballot(obs != 0);
        if (d == 0) s_xmask[qq] = bal;
    }
    __syncthreads();

    const int lane = tid & 63;
    const int qcol = lane & 15;
    const int krow = (lane >> 4) & 3;
    bf16x8 aXX0, aXX1, aOX0, aOX1, aM0, aM1;      // set A: queries qb0+qcol
    bf16x8 bXX0, bXX1, bOX0, bOX1, bM0, bM1;      // set B: queries qb0+16+qcol
#define BUILD_B(QIDX, XX0, XX1, OX0, OX1, M0, M1) {                           \
        const float* xr_ = s_xv[QIDX];                                        \
        u64 xm_ = s_xmask[QIDX];                                              \
        _Pragma("unroll")                                                     \
        for (int e = 0; e < 8; ++e) {                                         \
            int j0_ = krow * 8 + e;                                           \
            float x0_ = xr_[j0_];                                             \
            XX0[e] = (short)bf16_rne(x0_ * x0_);                              \
            OX0[e] = (short)(((xm_ >> j0_) & 1ull) ? 0x3F80 : 0);             \
            M0[e]  = (short)bf16_rne(-2.f * x0_);                             \
            int j1_ = 32 + krow * 8 + e;                                      \
            float x1_ = xr_[j1_];                                             \
            XX1[e] = (short)bf16_rne(x1_ * x1_);                              \
            OX1[e] = (short)(((xm_ >> j1_) & 1ull) ? 0x3F80 : 0);             \
            M1[e]  = (short)bf16_rne(-2.f * x1_);                             \
        } }
    BUILD_B(qcol,      aXX0, aXX1, aOX0, aOX1, aM0, aM1)
    BUILD_B(16 + qcol, bXX0, bXX1, bOX0, bOX1, bM0, bM1)
#undef BUILD_B

    const int wv = tid >> 6;
    int t = wv * 128;
    uint4 c0, c1, c2, c3, c4, c5;
    uint4 n0 = {}, n1 = {}, n2 = {}, n3 = {}, n4 = {}, n5 = {};
    LOADT(t, c0, c1, c2, c3, c4, c5);
    u32 gmA = 0xFFFFu, gmB = 0xFFFFu;             // running group (2-tile) mins
#pragma unroll 1
    for (int tt = 0; tt < 128; ++tt) {
        bool hasn = (tt + 1 < 128);
        if (hasn) LOADT(t + 1, n0, n1, n2, n3, n4, n5);
        f32x4 sA = {0.f,0.f,0.f,0.f}, pA = {0.f,0.f,0.f,0.f};
        f32x4 sB = {0.f,0.f,0.f,0.f}, pB = {0.f,0.f,0.f,0.f};
        sA = MF(c0, aXX0, sA); sA = MF(c1, aXX1, sA);
        sA = MF(c2, aOX0, sA); sA = MF(c3, aOX1, sA);
        sA = MF(c4, aM0,  sA); sA = MF(c5, aM1,  sA);
        pA = MF(c0, aOX0, pA); pA = MF(c1, aOX1, pA);
        sB = MF(c0, bXX0, sB); sB = MF(c1, bXX1, sB);
        sB = MF(c2, bOX0, sB); sB = MF(c3, bOX1, sB);
        sB = MF(c4, bM0,  sB); sB = MF(c5, bM1,  sB);
        pB = MF(c0, bOX0, pB); pB = MF(c1, bOX1, pB);
#define MKKEY(P, S, r) (((P)[r] > 0.5f)                                       \
            ? (__float_as_uint(__fdividef(fmaxf((S)[r], 0.f), (P)[r])) >> 16) \
            : (FLTMAX_BITS >> 16))
        u32 kA0 = MKKEY(pA, sA, 0), kA1 = MKKEY(pA, sA, 1);
        u32 kA2 = MKKEY(pA, sA, 2), kA3 = MKKEY(pA, sA, 3);
        u32 kB0 = MKKEY(pB, sB, 0), kB1 = MKKEY(pB, sB, 1);
        u32 kB2 = MKKEY(pB, sB, 2), kB3 = MKKEY(pB, sB, 3);
#undef MKKEY
        {
            size_t off = (size_t)(qb0 + qcol) * NF + (size_t)t * 16 + krow * 4;
            *(uint2*)(keys + off) = make_uint2(kA0 | (kA1 << 16), kA2 | (kA3 << 16));
        }
        {
            size_t off = (size_t)(qb0 + 16 + qcol) * NF + (size_t)t * 16 + krow * 4;
            *(uint2*)(keys + off) = make_uint2(kB0 | (kB1 << 16), kB2 | (kB3 << 16));
        }
        gmA = umin2(gmA, umin2(umin2(kA0, kA1), umin2(kA2, kA3)));
        gmB = umin2(gmB, umin2(umin2(kB0, kB1), umin2(kB2, kB3)));
        if (tt & 1) {                             // group of 2 tiles complete
            u32 vA = gmA, vB = gmB;               // reduce over krow lanes
            vA = umin2(vA, (u32)__shfl_xor((int)vA, 16, 64));
            vA = umin2(vA, (u32)__shfl_xor((int)vA, 32, 64));
            vB = umin2(vB, (u32)__shfl_xor((int)vB, 16, 64));
            vB = umin2(vB, (u32)__shfl_xor((int)vB, 32, 64));
            if (krow == 0) {
                int g = t >> 1;
                mins[(size_t)(qb0 + qcol) * NG + g]      = (u16)vA;
                mins[(size_t)(qb0 + 16 + qcol) * NG + g] = (u16)vB;
            }
            gmA = 0xFFFFu; gmB = 0xFFFFu;
        }
        if (hasn) { c0 = n0; c1 = n1; c2 = n2; c3 = n3; c4 = n4; c5 = n5; }
        ++t;
    }
}

// ---- kernel B: group-min pruned selection; 2 waves/block --------------------
__global__ __launch_bounds__(128) void knn_sel(
        const float* __restrict__ X,
        const float* __restrict__ fit,
        const u16* __restrict__ keys,             // [chunkQ][NF]
        const u16* __restrict__ mins,             // [chunkQ][NG]
        const int* __restrict__ pk,
        float* __restrict__ out,
        int cq0) {
    __shared__ __align__(16) float s_xv[2][D];
    __shared__ u32    s_sg[2][NG];                // surviving group list
    __shared__ u32    s_ci[2][TCAP];
    __shared__ double s_kd[2][TCAP];
    __shared__ u32    s_ord[2][TCAP];
    __shared__ u32    s_cnt[2];
    __shared__ u32    s_ns[2];

    const int lane = threadIdx.x & 63;
    const int wv   = threadIdx.x >> 6;
    const int ql = blockIdx.x * 2 + wv;           // local query
    const int q  = cq0 + ql;                      // global query

    float xf = X[(size_t)q * D + lane];
    int obs = !f32_missing_bits(__float_as_uint(xf));
    s_xv[wv][lane] = obs ? xf : 0.f;
    const u64 xm = __ballot(obs != 0);
    const u32 xmlo = (u32)xm, xmhi = (u32)(xm >> 32);

    // ---- group mins (4/lane) + [min, max-of-lane-mins] bracket ----
    uint2 mm = ((const uint2*)(mins + (size_t)ql * NG))[lane];
    const u32 m0 = mm.x & 0xFFFFu, m1 = mm.x >> 16;
    const u32 m2 = mm.y & 0xFFFFu, m3 = mm.y >> 16;
    u32 lmin = umin2(umin2(m0, m1), umin2(m2, m3));
    u32 lo0 = lmin, hi0 = lmin;
#pragma unroll
    for (int o = 32; o; o >>= 1) {
        u32 a = (u32)__shfl_xor((int)lo0, o, 64); lo0 = a < lo0 ? a : lo0;
        u32 b = (u32)__shfl_xor((int)hi0, o, 64); hi0 = b > hi0 ? b : hi0;
    }

    int K = *pk;
    if (K < 1 || K > 64) {             // robustness if scalar arrived as float
        float kf = __int_as_float(K);
        K = (kf >= 1.f && kf <= 64.f) ? (int)kf : 5;
    }
    if (K > TCAP) K = TCAP;

    // ---- UB = 32nd-smallest group-min (rank-32 of 256 values) ----
    u32 blo = lo0, bhi = hi0;
#pragma unroll 1
    while (blo < bhi) {
        u32 mid = (blo + bhi) >> 1;
        int c = (m0 <= mid) + (m1 <= mid) + (m2 <= mid) + (m3 <= mid);
#pragma unroll
        for (int o = 32; o; o >>= 1) c += __shfl_xor(c, o, 64);
        if ((u32)c >= (u32)RANK) bhi = mid; else blo = mid + 1;
    }
    const u32 UB = blo;                // thr16 <= UB (proof in header)

    // ---- survivors: groups with min <= UB ----
    if (lane == 0) s_ns[wv] = 0;
    {
        u32 gb = (u32)lane * 4;
        if (m0 <= UB) { u32 p = atomicAdd(&s_ns[wv], 1u); s_sg[wv][p] = gb; }
        if (m1 <= UB) { u32 p = atomicAdd(&s_ns[wv], 1u); s_sg[wv][p] = gb + 1; }
        if (m2 <= UB) { u32 p = atomicAdd(&s_ns[wv], 1u); s_sg[wv][p] = gb + 2; }
        if (m3 <= UB) { u32 p = atomicAdd(&s_ns[wv], 1u); s_sg[wv][p] = gb + 3; }
    }
    const int ns = (int)s_ns[wv];      // >= RANK by construction

    u32 thr16;
    const u16* krow_g = keys + (size_t)ql * NF;
    if (ns <= 64) {
        // ---- fast path: 1 surviving group per lane, 32 keys in 16 regs ----
        uint4 k0 = {~0u,~0u,~0u,~0u}, k1 = {~0u,~0u,~0u,~0u};
        uint4 k2 = {~0u,~0u,~0u,~0u}, k3 = {~0u,~0u,~0u,~0u};
        u32 sg = 0;
        if (lane < ns) {
            sg = s_sg[wv][lane];
            const uint4* kp = (const uint4*)(krow_g + (size_t)sg * 32);
            k0 = kp[0]; k1 = kp[1]; k2 = kp[2]; k3 = kp[3];
        }
        // exact thr16 = 32nd-smallest key, bracket [lo0, UB]
        blo = lo0; bhi = UB;
#pragma unroll 1
        while (blo < bhi) {
            u32 mid = (blo + bhi) >> 1;
            int c = 0;
#define CNTLE(W) { c += (((W) & 0xFFFFu) <= mid) + (((W) >> 16) <= mid); }
            CNTLE(k0.x) CNTLE(k0.y) CNTLE(k0.z) CNTLE(k0.w)
            CNTLE(k1.x) CNTLE(k1.y) CNTLE(k1.z) CNTLE(k1.w)
            CNTLE(k2.x) CNTLE(k2.y) CNTLE(k2.z) CNTLE(k2.w)
            CNTLE(k3.x) CNTLE(k3.y) CNTLE(k3.z) CNTLE(k3.w)
#undef CNTLE
#pragma unroll
            for (int o = 32; o; o >>= 1) c += __shfl_xor(c, o, 64);
            if ((u32)c >= (u32)RANK) bhi = mid; else blo = mid + 1;
        }
        thr16 = blo;

        // counts below / ties
        int nb = 0, nt2 = 0;
#define CNT2(W) { u32 a_ = (W) & 0xFFFFu, b_ = (W) >> 16;                     \
                  nb  += (a_ < thr16)  + (b_ < thr16);                        \
                  nt2 += (a_ == thr16) + (b_ == thr16); }
        CNT2(k0.x) CNT2(k0.y) CNT2(k0.z) CNT2(k0.w)
        CNT2(k1.x) CNT2(k1.y) CNT2(k1.z) CNT2(k1.w)
        CNT2(k2.x) CNT2(k2.y) CNT2(k2.z) CNT2(k2.w)
        CNT2(k3.x) CNT2(k3.y) CNT2(k3.z) CNT2(k3.w)
#undef CNT2
        int tb = nb, tt2 = nt2;
#pragma unroll
        for (int o = 32; o; o >>= 1) {
            tb  += __shfl_xor(tb, o, 64);
            tt2 += __shfl_xor(tt2, o, 64);
        }
        const int nTot = tb + tt2;     // >= RANK
        if (lane == 0) s_cnt[wv] = 0;
        if (nTot <= TCAP) {
            u32 fb = sg * 32;
#define APPK(W, KOFF) { u32 a_ = (W) & 0xFFFFu, b_ = (W) >> 16;               \
        if (a_ <= thr16) { u32 p_ = atomicAdd(&s_cnt[wv], 1u);                \
                           s_ci[wv][p_] = fb + (KOFF); }                      \
        if (b_ <= thr16) { u32 p_ = atomicAdd(&s_cnt[wv], 1u);                \
                           s_ci[wv][p_] = fb + (KOFF) + 1; } }
            APPK(k0.x, 0)  APPK(k0.y, 2)  APPK(k0.z, 4)  APPK(k0.w, 6)
            APPK(k1.x, 8)  APPK(k1.y, 10) APPK(k1.z, 12) APPK(k1.w, 14)
            APPK(k2.x, 16) APPK(k2.y, 18) APPK(k2.z, 20) APPK(k2.w, 22)
            APPK(k3.x, 24) APPK(k3.y, 26) APPK(k3.z, 28) APPK(k3.w, 30)
#undef APPK
            if (lane >= nTot) s_ci[wv][lane] = IDX_INVALID;
        } else {
            // rare overflow: all below, then ties ascending (smallest idx)
            if (lane == 0) {
                int n = 0;
                for (int f = 0; f < NF; ++f)
                    if ((u32)krow_g[f] < thr16) s_ci[wv][n++] = (u32)f;
                for (int f = 0; f < NF && n < TCAP; ++f)
                    if ((u32)krow_g[f] == thr16) s_ci[wv][n++] = (u32)f;
                for (; n < TCAP; ++n) s_ci[wv][n] = IDX_INVALID;
            }
        }
    } else {
        // ---- rare: many tied groups; transient re-reads (no reg cost) ----
        blo = lo0; bhi = UB;
#pragma unroll 1
        while (blo < bhi) {
            u32 mid = (blo + bhi) >> 1;
            int c = 0;
            for (int r = lane; r < ns; r += 64) {
                const u32* kp = (const u32*)(krow_g + (size_t)s_sg[wv][r] * 32);
                for (int w2 = 0; w2 < 16; ++w2) {
                    u32 x = kp[w2];
                    c += ((x & 0xFFFFu) <= mid) + ((x >> 16) <= mid);
                }
            }
#pragma unroll
            for (int o = 32; o; o >>= 1) c += __shfl_xor(c, o, 64);
            if ((u32)c >= (u32)RANK) bhi = mid; else blo = mid + 1;
        }
        thr16 = blo;
        int nb = 0, nt2 = 0;
        for (int r = lane; r < ns; r += 64) {
            const u32* kp = (const u32*)(krow_g + (size_t)s_sg[wv][r] * 32);
            for (int w2 = 0; w2 < 16; ++w2) {
                u32 x = kp[w2];
                u32 a_ = x & 0xFFFFu, b_ = x >> 16;
                nb  += (a_ < thr16)  + (b_ < thr16);
                nt2 += (a_ == thr16) + (b_ == thr16);
            }
        }
        int tb = nb, tt2 = nt2;
#pragma unroll
        for (int o = 32; o; o >>= 1) {
            tb  += __shfl_xor(tb, o, 64);
            tt2 += __shfl_xor(tt2, o, 64);
        }
        const int nTot = tb + tt2;
        if (lane == 0) s_cnt[wv] = 0;
        if (nTot <= TCAP) {
            for (int r = lane; r < ns; r += 64) {
                u32 sg2 = s_sg[wv][r];
                const u32* kp = (const u32*)(krow_g + (size_t)sg2 * 32);
                for (int w2 = 0; w2 < 16; ++w2) {
                    u32 x = kp[w2];
                    u32 a_ = x & 0xFFFFu, b_ = x >> 16;
                    if (a_ <= thr16) { u32 p_ = atomicAdd(&s_cnt[wv], 1u);
                                       s_ci[wv][p_] = sg2 * 32 + w2 * 2; }
                    if (b_ <= thr16) { u32 p_ = atomicAdd(&s_cnt[wv], 1u);
                                       s_ci[wv][p_] = sg2 * 32 + w2 * 2 + 1; }
                }
            }
            if (lane >= nTot) s_ci[wv][lane] = IDX_INVALID;
        } else {
            if (lane == 0) {
                int n = 0;
                for (int f = 0; f < NF; ++f)
                    if ((u32)krow_g[f] < thr16) s_ci[wv][n++] = (u32)f;
                for (int f = 0; f < NF && n < TCAP; ++f)
                    if ((u32)krow_g[f] == thr16) s_ci[wv][n++] = (u32)f;
                for (; n < TCAP; ++n) s_ci[wv][n] = IDX_INVALID;
            }
        }
    }

    // -- 2b: exact fp64 re-key; lane reads its own candidate row (L2-hot) --
    u32 myci = s_ci[wv][lane];
    double mykd = 1.0e300;
    if (myci != IDX_INVALID) {
        const float4* row4 = (const float4*)(fit + (size_t)myci * D);
        double ss = 0.0; int pr2 = 0;
#pragma unroll
        for (int g = 0; g < 16; ++g) {
            float4 w4 = row4[g];
            float wv4[4] = { w4.x, w4.y, w4.z, w4.w };
#pragma unroll
            for (int u = 0; u < 4; ++u) {
                int j = g * 4 + u;                 // ascending: same fma order
                int vmiss = f32_missing_bits(__float_as_uint(wv4[u]));
                u32 xbit = (j < 32) ? ((xmlo >> j) & 1u) : ((xmhi >> (j - 32)) & 1u);
                int ok = (int)xbit & (vmiss ^ 1);
                double dd = ok ? ((double)s_xv[wv][j] - (double)wv4[u]) : 0.0;
                ss = fma(dd, dd, ss);
                pr2 += ok;
            }
        }
        mykd = (pr2 > 0) ? (ss / (double)pr2) : 1.0e300;
    }
    s_kd[wv][lane] = mykd;

    // -- rank candidates by (kd, ci, lane); s_ord = sorted order --
    {
        int rank = 0;
#pragma unroll 1
        for (int j = 0; j < 64; ++j) {
            double kdj = __shfl(mykd, j, 64);
            u32 cij = (u32)__shfl((int)myci, j, 64);
            int less = (kdj < mykd) |
                       ((kdj == mykd) & ((cij < myci) |
                                         ((cij == myci) & (j < lane))));
            rank += less;
        }
        s_ord[wv][rank] = (u32)lane;
    }

    // -- 2d: walk sorted candidates; read donor values from L2-hot fit --
    {
        const int d = lane;
        u32 xobs = (d < 32) ? ((xmlo >> d) & 1u) : ((xmhi >> (d - 32)) & 1u);
        float res;
        if (xobs) {
            res = s_xv[wv][d];
        } else {
            float sum = 0.f; int cnt = 0;
#pragma unroll 1
            for (int s2 = 0; s2 < TCAP; ++s2) {
                u32 r = s_ord[wv][s2];
                u32 ci = s_ci[wv][r];
                if (ci == IDX_INVALID) break;        // invalids sort last
                if (s_kd[wv][r] >= 1.0e300) break;   // ascending => all done
                float v = fit[(size_t)ci * D + d];   // coalesced row, L2 hit
                if (f32_missing_bits(__float_as_uint(v))) continue;
                sum += v;
                if (++cnt == K) break;
            }
            if (cnt > 0) {
                res = sum / (float)cnt;
            } else {
                float cs = 0.f; int cc = 0;          // essentially-never fallback
                for (int f = 0; f < NF; ++f) {
                    float yf = fit[(size_t)f * D + d];
                    if (!f32_missing_bits(__float_as_uint(yf))) { cs += yf; cc++; }
                }
                res = cc > 0 ? cs / (float)cc : 0.f;
            }
            u32 rb = __float_as_uint(res);
            if (((rb >> 23) & 0xFFu) == 0xFFu) res = 0.f;   // integer guard
        }
        out[(size_t)q * D + d] = res;
    }
}

// ---- mid fallback: proven R19 single-kernel (verbatim) ----------------------
__global__ __launch_bounds__(256) void knn_mfma(
        const float* __restrict__ X,
        const float* __restrict__ fit,
        const uint4* __restrict__ frags,
        const int* __restrict__ pk,
        float* __restrict__ out) {
    __shared__ __align__(16) u16 s_k16[QB * PADW];
    __shared__ __align__(16) float s_xv[QB][D];
    __shared__ u64    s_xmask[QB];
    __shared__ u32    s_ci[4][TCAP];
    __shared__ double s_kd[4][TCAP];
    __shared__ u32    s_cnt[4];

    const int tid = threadIdx.x;
    const int q0 = blockIdx.x * QB;

#pragma unroll
    for (int rr = 0; rr < 2; ++rr) {
        int qq = rr * 4 + (tid >> 6);
        int d  = tid & 63;
        float xf = X[(size_t)(q0 + qq) * D + d];
        int obs = !f32_missing_bits(__float_as_uint(xf));
        s_xv[qq][d] = obs ? xf : 0.f;
        u64 bal = __ballot(obs != 0);
        if (d == 0) s_xmask[qq] = bal;
    }
    __syncthreads();

    const int lane = tid & 63;
    const int qcol = lane & 15;
    const int krow = (lane >> 4) & 3;
    bf16x8 bXX0 = (bf16x8)(short)0, bXX1 = (bf16x8)(short)0;
    bf16x8 bOX0 = (bf16x8)(short)0, bOX1 = (bf16x8)(short)0;
    bf16x8 bM0  = (bf16x8)(short)0, bM1  = (bf16x8)(short)0;
    if (qcol < QB) {
        const float* xr = s_xv[qcol];
        u64 xm = s_xmask[qcol];
#pragma unroll
        for (int e = 0; e < 8; ++e) {
            {
                int j = krow * 8 + e;
                float x = xr[j];
                bXX0[e] = (short)bf16_rne(x * x);
                bOX0[e] = (short)(((xm >> j) & 1ull) ? 0x3F80 : 0);
                bM0[e]  = (short)bf16_rne(-2.f * x);
            }
            {
                int j = 32 + krow * 8 + e;
                float x = xr[j];
                bXX1[e] = (short)bf16_rne(x * x);
                bOX1[e] = (short)(((xm >> j) & 1ull) ? 0x3F80 : 0);
                bM1[e]  = (short)bf16_rne(-2.f * x);
            }
        }
    }

    {
        const int wv = tid >> 6;
        int t = wv * 128;
        uint4 c0, c1, c2, c3, c4, c5;
        uint4 n0 = {}, n1 = {}, n2 = {}, n3 = {}, n4 = {}, n5 = {};
        LOADT(t, c0, c1, c2, c3, c4, c5);
#pragma unroll 1
        for (int tt = 0; tt < 128; ++tt) {
            bool hasn = (tt + 1 < 128);
            if (hasn) LOADT(t + 1, n0, n1, n2, n3, n4, n5);
            f32x4 accS = {0.f, 0.f, 0.f, 0.f};
            f32x4 accP = {0.f, 0.f, 0.f, 0.f};
            accS = MF(c0, bXX0, accS);
            accS = MF(c1, bXX1, accS);
            accS = MF(c2, bOX0, accS);
            accS = MF(c3, bOX1, accS);
            accS = MF(c4, bM0,  accS);
            accS = MF(c5, bM1,  accS);
            accP = MF(c0, bOX0, accP);
            accP = MF(c1, bOX1, accP);
            if (qcol < QB) {
#define MKKEY(r) ((accP[r] > 0.5f)                                            \
                    ? __float_as_uint(__fdividef(fmaxf(accS[r], 0.f), accP[r]))\
                    : FLTMAX_BITS)
                u32 b0 = MKKEY(0), b1 = MKKEY(1), b2 = MKKEY(2), b3 = MKKEY(3);
#undef MKKEY
                u32 lo = (b0 >> 16) | (b1 & 0xFFFF0000u);
                u32 hi = (b2 >> 16) | (b3 & 0xFFFF0000u);
                u32 off = (u32)qcol * PADW + (u32)t * 16 + (u32)krow * 4;
                *(uint2*)(&s_k16[off]) = make_uint2(lo, hi);
            }
            if (hasn) { c0 = n0; c1 = n1; c2 = n2; c3 = n3; c4 = n4; c5 = n5; }
            ++t;
        }
    }
    __syncthreads();

    int K = *pk;
    if (K < 1 || K > 64) {
        float kf = __int_as_float(K);
        K = (kf >= 1.f && kf <= 64.f) ? (int)kf : 5;
    }
    if (K > TCAP) K = TCAP;

    const int wv = tid >> 6;
#pragma unroll 1
    for (int rr = 0; rr < 2; ++rr) {
        const int qq = wv + rr * 4;
        const int q = q0 + qq;
        u16* kq = s_k16 + (size_t)qq * PADW;
        const u32* kq32 = (const u32*)kq;
        const u64 xm = s_xmask[qq];
        const u32 xmlo = (u32)xm, xmhi = (u32)(xm >> 32);

        u32 blo = 0, bhi = 65535;
#pragma unroll 1
        while (blo < bhi) {
            u32 mid = (blo + bhi) >> 1;
            int c = 0;
#pragma unroll 8
            for (int i = 0; i < 64; ++i) {
                u32 w2 = kq32[lane + (i << 6)];
                c += ((w2 & 0xFFFFu) <= mid) + ((w2 >> 16) <= mid);
            }
#pragma unroll
            for (int o = 32; o; o >>= 1) c += __shfl_xor(c, o, 64);
            if ((u32)c >= (u32)RANK) bhi = mid; else blo = mid + 1;
        }
        const u32 thr16 = blo;

        if (lane == 0) s_cnt[wv] = 0;
        int nb = 0, nt2 = 0;
#pragma unroll 8
        for (int i = 0; i < 64; ++i) {
            u32 w2 = kq32[lane + (i << 6)];
            u32 k0 = w2 & 0xFFFFu, k1 = w2 >> 16;
            nb  += (k0 < thr16)  + (k1 < thr16);
            nt2 += (k0 == thr16) + (k1 == thr16);
        }
        int tb = nb, tt2 = nt2;
#pragma unroll
        for (int o = 32; o; o >>= 1) {
            tb  += __shfl_xor(tb, o, 64);
            tt2 += __shfl_xor(tt2, o, 64);
        }
        const int nTot = tb + tt2;
        if (nTot <= TCAP) {
#pragma unroll 4
            for (int i = 0; i < 64; ++i) {
                u32 w2 = kq32[lane + (i << 6)];
                u32 k0 = w2 & 0xFFFFu, k1 = w2 >> 16;
                int f0 = (lane + (i << 6)) * 2;
                if (k0 <= thr16) { u32 p = atomicAdd(&s_cnt[wv], 1u); s_ci[wv][p] = (u32)f0; }
                if (k1 <= thr16) { u32 p = atomicAdd(&s_cnt[wv], 1u); s_ci[wv][p] = (u32)(f0 + 1); }
            }
            if (lane >= nTot) s_ci[wv][lane] = IDX_INVALID;
        } else {
            if (lane == 0) {
                int n = 0;
                for (int f = 0; f < NF; ++f)
                    if ((u32)kq[f] < thr16) s_ci[wv][n++] = (u32)f;
                for (int f = 0; f < NF && n < TCAP; ++f)
                    if ((u32)kq[f] == thr16) s_ci[wv][n++] = (u32)f;
                for (; n < TCAP; ++n) s_ci[wv][n] = IDX_INVALID;
            }
        }

        float* cv = (float*)kq;
        u32 myci = s_ci[wv][lane];
#pragma unroll 8
        for (int r = 0; r < TCAP; ++r) {
            u32 ci = __shfl((int)myci, r, 64);
            float v = (ci != IDX_INVALID) ? fit[(size_t)ci * D + lane]
                                          : __uint_as_float(NANF_BITS);
            cv[(r << 6) + (lane ^ (r & 31))] = v;
        }

        {
            double ss = 0.0; int pr2 = 0;
#pragma unroll 8
            for (int j = 0; j < D; ++j) {
                float yf = cv[(lane << 6) + (j ^ (lane & 31))];
                int vmiss = f32_missing_bits(__float_as_uint(yf));
                u32 xbit = (j < 32) ? ((xmlo >> j) & 1u) : ((xmhi >> (j - 32)) & 1u);
                int ok = (int)xbit & (vmiss ^ 1);
                double dd = ok ? ((double)s_xv[qq][j] - (double)yf) : 0.0;
                ss = fma(dd, dd, ss);
                pr2 += ok;
            }
            double kd = (myci != IDX_INVALID && pr2 > 0) ? (ss / (double)pr2)
                                                         : 1.0e300;
            s_kd[wv][lane] = kd;
        }

        {
            const int d = lane;
            u32 xobs = (d < 32) ? ((xmlo >> d) & 1u) : ((xmhi >> (d - 32)) & 1u);
            float res;
            if (xobs) {
                res = s_xv[qq][d];
            } else {
                u64 used = 0; float sum = 0.f; int cnt = 0;
                for (int s = 0; s < K; ++s) {
                    int best = -1; double bk = 0.0; u32 bi = 0;
                    for (int r = 0; r < TCAP; ++r) {
                        if ((used >> r) & 1ull) continue;
                        u32 ci = s_ci[wv][r];
                        if (ci == IDX_INVALID) continue;
                        float v = cv[(r << 6) + (d ^ (r & 31))];
                        if (f32_missing_bits(__float_as_uint(v))) continue;
                        double kd = s_kd[wv][r];
                        if (kd >= 1.0e300) continue;
                        if (best < 0 || kd < bk || (kd == bk && ci < bi)) {
                            best = r; bk = kd; bi = ci;
                        }
                    }
                    if (best < 0) break;
                    used |= 1ull << best;
                    sum += cv[(best << 6) + (d ^ (best & 31))];
                    cnt++;
                }
                if (cnt > 0) {
                    res = sum / (float)cnt;
                } else {
                    float cs = 0.f; int cc = 0;
                    for (int f = 0; f < NF; ++f) {
                        float yf = fit[(size_t)f * D + d];
                        if (!f32_missing_bits(__float_as_uint(yf))) { cs += yf; cc++; }
                    }
                    res = cc > 0 ? cs / (float)cc : 0.f;
                }
                u32 rb = __float_as_uint(res);
                if (((rb >> 23) & 0xFFu) == 0xFFu) res = 0.f;
            }
            out[(size_t)q * D + d] = res;
        }
    }
}

// ---- last fallback: proven R15 kernel ---------------------------------------
__global__ __launch_bounds__(256) void knn_fb(
        const float* __restrict__ X,
        const float* __restrict__ fit,
        const int* __restrict__ pk,
        float* __restrict__ out) {
    __shared__ __align__(16) unsigned char s_pool[16384];
    __shared__ u32   s_hist[256];
    __shared__ u32   s_blw[256];
    __shared__ u32   s_tie[256];
    __shared__ __align__(16) float s_xv[D];
    __shared__ u64   s_xmask;
    __shared__ u32   s_ci[TCAP];
    __shared__ double s_kd[TCAP];
    __shared__ u32   s_sel0, s_below0, s_sel1;

    u16*   s_k16 = (u16*)s_pool;
    float* s_cv  = (float*)s_pool;
    const int tid = threadIdx.x;
    const int q = blockIdx.x;

    if (tid < 64) {
        float xf = X[(size_t)q * D + tid];
        int obs = !f32_missing_bits(__float_as_uint(xf));
        s_xv[tid] = obs ? xf : 0.f;
        u64 bal = __ballot(obs != 0);
        if (tid == 0) s_xmask = bal;
    }
    __syncthreads();

    const u64 xm = s_xmask;
    const u32 xmlo = (u32)xm, xmhi = (u32)(xm >> 32);
    const float4* xv4 = (const float4*)s_xv;
    const float4* fitc = (const float4*)fit;

    for (int i = 0; i < 32; ++i) {
        int f = tid + (i << 8);
        const float4* rp = fitc + (size_t)f * 16;
        float ssd = 0.f; int pres = 0;
#pragma unroll
        for (int m = 0; m < 16; ++m) {
            float4 w = rp[m];
            float4 xc = xv4[m];
            u32 mb = (m < 8) ? (xmlo >> ((m & 7) * 4)) : (xmhi >> ((m & 7) * 4));
            float wv[4] = { w.x, w.y, w.z, w.w };
            float xw[4] = { xc.x, xc.y, xc.z, xc.w };
#pragma unroll
            for (int u = 0; u < 4; ++u) {
                int ok = (int)((mb >> u) & 1u)
                       & (f32_missing_bits(__float_as_uint(wv[u])) ^ 1);
                float t = ok ? wv[u] : xw[u];
                float dm = xw[u] - t;
                ssd = fmaf(dm, dm, ssd);
                pres += ok;
            }
        }
        float kk = (pres > 0) ? (ssd / (float)pres) : __uint_as_float(FLTMAX_BITS);
        s_k16[f] = (u16)(__float_as_uint(kk) >> 16);
    }
    __syncthreads();

    int K = *pk;
    if (K < 1 || K > 64) {
        float kf = __int_as_float(K);
        K = (kf >= 1.f && kf <= 64.f) ? (int)kf : 5;
    }
    if (K > TCAP) K = TCAP;

    s_hist[tid] = 0;
    __syncthreads();
    for (int i = 0; i < 32; ++i) {
        u32 k16 = (u32)s_k16[tid + (i << 8)];
        atomicAdd(&s_hist[k16 >> 8], 1u);
    }
    __syncthreads();
    if (tid == 0) {
        u32 run = 0, below = 0, sel = 255;
        for (int b = 0; b < 256; ++b) {
            u32 c = s_hist[b];
            if (run + c >= (u32)RANK) { sel = (u32)b; below = run; break; }
            run += c;
        }
        s_sel0 = sel; s_below0 = below;
    }
    __syncthreads();
    const u32 sel0 = s_sel0;
    const u32 need1 = (u32)RANK - s_below0;
    __syncthreads();
    s_hist[tid] = 0;
    __syncthreads();
    for (int i = 0; i < 32; ++i) {
        u32 k16 = (u32)s_k16[tid + (i << 8)];
        if ((k16 >> 8) == sel0) atomicAdd(&s_hist[k16 & 0xFFu], 1u);
    }
    __syncthreads();
    if (tid == 0) {
        u32 run = 0, sel = 255;
        for (int b = 0; b < 256; ++b) {
            u32 c = s_hist[b];
            if (run + c >= need1) { sel = (u32)b; break; }
            run += c;
        }
        s_sel1 = sel;
    }
    __syncthreads();
    const u32 thr16 = (sel0 << 8) | s_sel1;

    {
        u32 bb = 0, tb = 0;
        for (int i = 0; i < 32; ++i) {
            u32 k16 = (u32)s_k16[tid + (i << 8)];
            bb |= (k16 < thr16)  ? (1u << i) : 0u;
            tb |= (k16 == thr16) ? (1u << i) : 0u;
        }
        s_blw[tid] = bb; s_tie[tid] = tb;
    }
    __syncthreads();
    if (tid == 0) {
        int n = 0;
        for (int t = 0; t < 256 && n < TCAP; ++t) {
            u32 w = s_blw[t];
            while (w && n < TCAP) {
                int i = __ffs(w) - 1; w &= w - 1;
                s_ci[n++] = (u32)(i * 256 + t);
            }
        }
        u32 tf[TCAP]; int nt = 0;
        for (int t = 0; t < 256 && nt < TCAP; ++t) {
            u32 w = s_tie[t];
            while (w && nt < TCAP) {
                int i = __ffs(w) - 1; w &= w - 1;
                tf[nt++] = (u32)(i * 256 + t);
            }
        }
        int cap = TCAP - n;
        if (nt <= cap) {
            for (int r = 0; r < nt; ++r) s_ci[n++] = tf[r];
        } else {
            for (int j = 0; j < cap; ++j) {
                int bp = -1; u32 bi = IDX_INVALID;
                for (int r = 0; r < nt; ++r)
                    if (tf[r] < bi) { bi = tf[r]; bp = r; }
                tf[bp] = IDX_INVALID;
                s_ci[n++] = bi;
            }
        }
        for (; n < TCAP; ++n) s_ci[n] = IDX_INVALID;
    }
    __syncthreads();

#pragma unroll
    for (int t = 0; t < (TCAP * 64) / 256; ++t) {
        int idx = tid + t * 256;
        int r = idx >> 6, d2 = idx & 63;
        u32 ci = s_ci[r];
        s_cv[idx] = (ci != IDX_INVALID) ? fit[(size_t)ci * D + d2]
                                        : __uint_as_float(NANF_BITS);
    }

    if (tid < TCAP) {
        u32 ci = s_ci[tid];
        double kd = 1.0e300;
        if (ci != IDX_INVALID) {
            const float* row = fit + (size_t)ci * D;
            double ss = 0.0; int pr = 0;
            for (int j = 0; j < D; ++j) {
                float yf = row[j];
                int vmiss = f32_missing_bits(__float_as_uint(yf));
                u32 xbit = (j < 32) ? ((xmlo >> j) & 1u) : ((xmhi >> (j - 32)) & 1u);
                int ok = (int)xbit & (vmiss ^ 1);
                double dd = ok ? ((double)s_xv[j] - (double)yf) : 0.0;
                ss = fma(dd, dd, ss);
                pr += ok;
            }
            kd = (pr > 0) ? (ss / (double)pr) : 1.0e300;
        }
        s_kd[tid] = kd;
    }
    __syncthreads();

    if (tid < 64) {
        const int d = tid;
        u32 xobs = (d < 32) ? ((xmlo >> d) & 1u) : ((xmhi >> (d - 32)) & 1u);
        float res;
        if (xobs) {
            res = s_xv[d];
        } else {
            u64 used = 0; float sum = 0.f; int cnt = 0;
            for (int s = 0; s < K; ++s) {
                int best = -1; double bk = 0.0; u32 bi = 0;
                for (int r = 0; r < TCAP; ++r) {
                    if ((used >> r) & 1ull) continue;
                    u32 ci = s_ci[r];
                    if (ci == IDX_INVALID) continue;
                    float v = s_cv[r * 64 + d];
                    if (f32_missing_bits(__float_as_uint(v))) continue;
                    double kd = s_kd[r];
                    if (kd >= 1.0e300) continue;
                    if (best < 0 || kd < bk || (kd == bk && ci < bi)) {
                        best = r; bk = kd; bi = ci;
                    }
                }
                if (best < 0) break;
                used |= 1ull << best;
                sum += s_cv[best * 64 + d];
                cnt++;
            }
            if (cnt > 0) {
                res = sum / (float)cnt;
            } else {
                float cs = 0.f; int cc = 0;
                for (int f = 0; f < NF; ++f) {
                    float yf = fit[(size_t)f * D + d];
                    if (!f32_missing_bits(__float_as_uint(yf))) { cs += yf; cc++; }
                }
                res = cc > 0 ? cs / (float)cc : 0.f;
            }
            u32 rb = __float_as_uint(res);
            if (((rb >> 23) & 0xFFu) == 0xFFu) res = 0.f;
        }
        out[(size_t)q * D + d] = res;
    }
}

// ---- launch ------------------------------------------------------------------
extern "C" void kernel_launch(void* const* d_in, const int* in_sizes, int n_in,
                              void* d_out, int out_size, void* d_ws, size_t ws_size,
                              hipStream_t stream) {
    const void* pX = d_in[0];
    const void* pF = (n_in > 1) ? d_in[1] : d_in[0];
    const void* pK = (n_in > 2) ? d_in[2] : d_in[0];
    for (int i = 0; i < n_in; ++i) {
        if (in_sizes[i] == NQ * D)      pX = d_in[i];
        else if (in_sizes[i] == NF * D) pF = d_in[i];
        else if (in_sizes[i] == 1)      pK = d_in[i];
    }
    const float* X   = (const float*)pX;
    const float* fit = (const float*)pF;
    const int*   pk  = (const int*)pK;
    float* out = (float*)d_out;

    const size_t perQ = (size_t)NF * 2 + (size_t)NG * 2;   // keys 16KB + mins 512B
    if (ws_size >= FRAG_BYTES + 2048 * perQ) {
        uint4* frags = (uint4*)d_ws;
        size_t avail = ws_size - FRAG_BYTES;
        int chunkQ = (int)(avail / perQ);
        if (chunkQ > NQ) chunkQ = NQ;
        chunkQ &= ~(QA - 1);                                // multiple of QA
        u16* mins = (u16*)((char*)d_ws + FRAG_BYTES);
        u16* keys = (u16*)((char*)d_ws + FRAG_BYTES + (size_t)chunkQ * NG * 2);
        prep_frags<<<(NTILES * 384) / 256, 256, 0, stream>>>(fit, frags);
        for (int cq0 = 0; cq0 < NQ; cq0 += chunkQ) {
            int cur = NQ - cq0 < chunkQ ? NQ - cq0 : chunkQ;
            knn_keys<<<cur / QA, 256, 0, stream>>>(X, frags, keys, mins, cq0);
            knn_sel<<<cur / 2, 128, 0, stream>>>(X, fit, keys, mins, pk, out, cq0);
        }
    } else if (ws_size >= FRAG_BYTES) {
        uint4* frags = (uint4*)d_ws;
        prep_frags<<<(NTILES * 384) / 256, 256, 0, stream>>>(fit, frags);
        knn_mfma<<<NQ / QB, 256, 0, stream>>>(X, fit, frags, pk, out);
    } else {
        knn_fb<<<NQ, 256, 0, stream>>>(X, fit, pk, out);
    }
}